// Round 1
// baseline (892.919 us; speedup 1.0000x reference)
//
#include <hip/hip_runtime.h>
#include <math.h>

#define NN 50000
#define NE 800000
#define IND 256
#define OUTD 128
#define HIDD 64

// ---------- helpers: ordered-uint encoding of float for atomicMax ----------
static __device__ __forceinline__ unsigned enc_f(float f) {
  unsigned u = __float_as_uint(f);
  return (u & 0x80000000u) ? ~u : (u | 0x80000000u);
}
static __device__ __forceinline__ float dec_f(unsigned u) {
  unsigned b = (u & 0x80000000u) ? (u ^ 0x80000000u) : ~u;
  return __uint_as_float(b);
}

// ---------- K0: zero x_new (output region) + init reduction scalars ----------
__global__ __launch_bounds__(256) void k_zero(float* __restrict__ xnew,
                                              unsigned* __restrict__ umax,
                                              float* __restrict__ sumexp) {
  int i = blockIdx.x * 256 + threadIdx.x;           // 6250*256 = 1,600,000 float4s
  float4 z = make_float4(0.f, 0.f, 0.f, 0.f);
  ((float4*)xnew)[i] = z;
  if (i == 0) { *umax = 0x007FFFFFu /* enc(-inf) */; *sumexp = 0.f; }
}

// ---------- K1: Wh = x @ W  (f32 vector GEMM, BM=64 BN=128 BK=32) ----------
__global__ __launch_bounds__(256) void k_gemm(const float* __restrict__ x,
                                              const float* __restrict__ W,
                                              float* __restrict__ Wh) {
  __shared__ float xs[32][64];    // [k][m]
  __shared__ float ws[32][128];   // [k][n]
  const int tid = threadIdx.x;
  const int bm = blockIdx.x * 64;
  const int ty = tid >> 4;        // 0..15 -> rows ty*4..ty*4+3
  const int tx = tid & 15;        // cols tx*8..tx*8+7
  float acc[4][8];
#pragma unroll
  for (int i = 0; i < 4; i++)
#pragma unroll
    for (int j = 0; j < 8; j++) acc[i][j] = 0.f;

  for (int k0 = 0; k0 < IND; k0 += 32) {
    // x tile: 64 rows x 32 k = 512 float4, 2 per thread (transposed store)
#pragma unroll
    for (int i = 0; i < 2; i++) {
      int f = tid + i * 256;
      int r = f >> 3;
      int kq = (f & 7) * 4;
      int row = bm + r; if (row >= NN) row = NN - 1;   // clamp (writes guarded)
      const float4 v = *(const float4*)&x[(long)row * IND + k0 + kq];
      xs[kq + 0][r] = v.x; xs[kq + 1][r] = v.y;
      xs[kq + 2][r] = v.z; xs[kq + 3][r] = v.w;
    }
    // W tile: 32 k x 128 cols = 1024 float4, 4 per thread (linear store)
#pragma unroll
    for (int i = 0; i < 4; i++) {
      int f = tid + i * 256;
      int kr = f >> 5;
      int cq = (f & 31) * 4;
      *(float4*)&ws[kr][cq] = *(const float4*)&W[(k0 + kr) * OUTD + cq];
    }
    __syncthreads();
#pragma unroll
    for (int kk = 0; kk < 32; kk++) {
      float4 xa = *(const float4*)&xs[kk][ty * 4];
      float4 wa = *(const float4*)&ws[kk][tx * 8];
      float4 wb = *(const float4*)&ws[kk][tx * 8 + 4];
      float xr[4] = {xa.x, xa.y, xa.z, xa.w};
      float wr[8] = {wa.x, wa.y, wa.z, wa.w, wb.x, wb.y, wb.z, wb.w};
#pragma unroll
      for (int i = 0; i < 4; i++)
#pragma unroll
        for (int j = 0; j < 8; j++)
          acc[i][j] = fmaf(xr[i], wr[j], acc[i][j]);
    }
    __syncthreads();
  }
#pragma unroll
  for (int i = 0; i < 4; i++) {
    int row = bm + ty * 4 + i;
    if (row < NN) {
      float4 o0 = make_float4(acc[i][0], acc[i][1], acc[i][2], acc[i][3]);
      float4 o1 = make_float4(acc[i][4], acc[i][5], acc[i][6], acc[i][7]);
      *(float4*)&Wh[(long)row * OUTD + tx * 8] = o0;
      *(float4*)&Wh[(long)row * OUTD + tx * 8 + 4] = o1;
    }
  }
}

// ---------- K2: s_src[n] = Wh[n]@a[:128], s_tgt[n] = Wh[n]@a[128:] ----------
__global__ __launch_bounds__(256) void k_s(const float* __restrict__ Wh,
                                           const float* __restrict__ a,
                                           float* __restrict__ s_src,
                                           float* __restrict__ s_tgt) {
  int wid = (blockIdx.x * 256 + threadIdx.x) >> 6;    // one wave per node
  int lane = threadIdx.x & 63;
  if (wid >= NN) return;
  float w0 = Wh[(long)wid * OUTD + lane];
  float w1 = Wh[(long)wid * OUTD + 64 + lane];
  float p1 = w0 * a[lane]       + w1 * a[64 + lane];
  float p2 = w0 * a[128 + lane] + w1 * a[192 + lane];
#pragma unroll
  for (int off = 32; off; off >>= 1) {
    p1 += __shfl_down(p1, off);
    p2 += __shfl_down(p2, off);
  }
  if (lane == 0) { s_src[wid] = p1; s_tgt[wid] = p2; }
}

// ---------- K3: scores + global max ----------
__global__ __launch_bounds__(256) void k_score(const int* __restrict__ ei,
                                               const float* __restrict__ s_src,
                                               const float* __restrict__ s_tgt,
                                               float* __restrict__ scores,
                                               unsigned* __restrict__ umax) {
  int e = blockIdx.x * 256 + threadIdx.x;             // grid covers NE exactly
  int s = ei[e];
  int t = ei[NE + e];
  float v = s_src[s] + s_tgt[t];
  float sc = v > 0.f ? v : 0.2f * v;                  // leaky_relu(0.2)
  scores[e] = sc;
  // block max
  float m = sc;
#pragma unroll
  for (int off = 32; off; off >>= 1) m = fmaxf(m, __shfl_down(m, off));
  __shared__ float red[4];
  int w = threadIdx.x >> 6, lane = threadIdx.x & 63;
  if (lane == 0) red[w] = m;
  __syncthreads();
  if (threadIdx.x == 0) {
    float bm = fmaxf(fmaxf(red[0], red[1]), fmaxf(red[2], red[3]));
    atomicMax(umax, enc_f(bm));
  }
}

// ---------- K4: sum of exp(score - max) ----------
__global__ __launch_bounds__(256) void k_sum(const float* __restrict__ scores,
                                             const unsigned* __restrict__ umax,
                                             float* __restrict__ sumexp) {
  int e = blockIdx.x * 256 + threadIdx.x;
  float m = dec_f(*umax);
  float v = expf(scores[e] - m);
#pragma unroll
  for (int off = 32; off; off >>= 1) v += __shfl_down(v, off);
  __shared__ float red[4];
  int w = threadIdx.x >> 6, lane = threadIdx.x & 63;
  if (lane == 0) red[w] = v;
  __syncthreads();
  if (threadIdx.x == 0)
    atomicAdd(sumexp, red[0] + red[1] + red[2] + red[3]);
}

// ---------- K5: scatter  x_new[tgt] += alpha * Wh[src]  ----------
__global__ __launch_bounds__(256) void k_scatter(const int* __restrict__ ei,
                                                 const float* __restrict__ scores,
                                                 const float* __restrict__ Wh,
                                                 const unsigned* __restrict__ umax,
                                                 const float* __restrict__ sumexp,
                                                 float* __restrict__ xnew) {
  int w = threadIdx.x >> 6;                 // wave in block
  int lane = threadIdx.x & 63;
  int e = blockIdx.x * 4 + w;               // 200000*4 = NE exactly
  float m = dec_f(*umax);
  float inv = 1.0f / *sumexp;
  float alpha = expf(scores[e] - m) * inv;
  int s = ei[e];
  int t = ei[NE + e];
  float2 v = *(const float2*)&Wh[(long)s * OUTD + lane * 2];
  float* dst = &xnew[(long)t * OUTD + lane * 2];
  atomicAdd(dst,     alpha * v.x);
  atomicAdd(dst + 1, alpha * v.y);
}

// ---------- K6: MLP head: h = relu(x_new@W1+b1); evidence = softplus(h@W2+b2)+1 ----------
__global__ __launch_bounds__(256) void k_mlp(const float* __restrict__ xnew,
                                             const float* __restrict__ W1,
                                             const float* __restrict__ b1,
                                             const float* __restrict__ W2,
                                             const float* __restrict__ b2,
                                             float* __restrict__ evid) {
  __shared__ float xs[4][128];
  __shared__ float hs[4][64];
  int w = threadIdx.x >> 6, lane = threadIdx.x & 63;
  int n = blockIdx.x * 4 + w;               // 12500*4 = NN exactly
  xs[w][lane]      = xnew[(long)n * OUTD + lane];
  xs[w][64 + lane] = xnew[(long)n * OUTD + 64 + lane];
  __syncthreads();
  float h = b1[lane];
#pragma unroll 4
  for (int k = 0; k < OUTD; k++)
    h = fmaf(xs[w][k], W1[k * HIDD + lane], h);
  h = fmaxf(h, 0.f);
  hs[w][lane] = h;
  __syncthreads();
  if (lane < 3) {
    float ev = b2[lane];
    for (int k = 0; k < HIDD; k++)
      ev = fmaf(hs[w][k], W2[k * 3 + lane], ev);
    // softplus(x) = log1p(exp(x)) (stable), then +1
    float sp = ev > 20.f ? ev : log1pf(expf(ev));
    evid[(long)n * 3 + lane] = sp + 1.0f;
  }
}

extern "C" void kernel_launch(void* const* d_in, const int* in_sizes, int n_in,
                              void* d_out, int out_size, void* d_ws, size_t ws_size,
                              hipStream_t stream) {
  const float* x   = (const float*)d_in[0];
  const int*   ei  = (const int*)d_in[1];
  const float* W   = (const float*)d_in[2];
  const float* a   = (const float*)d_in[3];
  const float* W1  = (const float*)d_in[4];
  const float* b1  = (const float*)d_in[5];
  const float* W2  = (const float*)d_in[6];
  const float* b2  = (const float*)d_in[7];

  float* xnew = (float*)d_out;                       // [NN*OUTD]
  float* evid = (float*)d_out + (size_t)NN * OUTD;   // [NN*3]

  float* wsf    = (float*)d_ws;
  float* Wh     = wsf;                               // 6,400,000 f
  float* s_src  = wsf + 6400000;                     // 50,000 f
  float* s_tgt  = wsf + 6450000;                     // 50,000 f
  float* scores = wsf + 6500000;                     // 800,000 f
  unsigned* umax = (unsigned*)(wsf + 7300000);
  float* sumexp  = wsf + 7300001;

  k_zero<<<6250, 256, 0, stream>>>(xnew, umax, sumexp);
  k_gemm<<<(NN + 63) / 64, 256, 0, stream>>>(x, W, Wh);
  k_s<<<12500, 256, 0, stream>>>(Wh, a, s_src, s_tgt);
  k_score<<<NE / 256, 256, 0, stream>>>(ei, s_src, s_tgt, scores, umax);
  k_sum<<<NE / 256, 256, 0, stream>>>(scores, umax, sumexp);
  k_scatter<<<NE / 4, 256, 0, stream>>>(ei, scores, Wh, umax, sumexp, xnew);
  k_mlp<<<NN / 4, 256, 0, stream>>>(xnew, W1, b1, W2, b2, evid);
}

// Round 2
// 511.614 us; speedup vs baseline: 1.7453x; 1.7453x over previous
//
#include <hip/hip_runtime.h>
#include <math.h>

#define NN 50000
#define NE 800000
#define IND 256
#define OUTD 128
#define HIDD 64

// ---------- helpers: ordered-uint encoding of float for atomicMax ----------
static __device__ __forceinline__ unsigned enc_f(float f) {
  unsigned u = __float_as_uint(f);
  return (u & 0x80000000u) ? ~u : (u | 0x80000000u);
}
static __device__ __forceinline__ float dec_f(unsigned u) {
  unsigned b = (u & 0x80000000u) ? (u ^ 0x80000000u) : ~u;
  return __uint_as_float(b);
}

// ---------- K0: zero target-histogram + init reduction scalars ----------
__global__ __launch_bounds__(256) void k_zero(int* __restrict__ cnt,
                                              unsigned* __restrict__ umax,
                                              float* __restrict__ sumexp) {
  int i = blockIdx.x * 256 + threadIdx.x;     // 196*256 = 50176 >= NN
  if (i < NN) cnt[i] = 0;
  if (i == 0) { *umax = 0x007FFFFFu /* enc(-inf) */; *sumexp = 0.f; }
}

// ---------- K1: Wh = x @ W  (f32 vector GEMM, BM=64 BN=128 BK=32) ----------
__global__ __launch_bounds__(256) void k_gemm(const float* __restrict__ x,
                                              const float* __restrict__ W,
                                              float* __restrict__ Wh) {
  __shared__ float xs[32][64];    // [k][m]
  __shared__ float ws[32][128];   // [k][n]
  const int tid = threadIdx.x;
  const int bm = blockIdx.x * 64;
  const int ty = tid >> 4;        // 0..15 -> rows ty*4..ty*4+3
  const int tx = tid & 15;        // cols tx*8..tx*8+7
  float acc[4][8];
#pragma unroll
  for (int i = 0; i < 4; i++)
#pragma unroll
    for (int j = 0; j < 8; j++) acc[i][j] = 0.f;

  for (int k0 = 0; k0 < IND; k0 += 32) {
#pragma unroll
    for (int i = 0; i < 2; i++) {
      int f = tid + i * 256;
      int r = f >> 3;
      int kq = (f & 7) * 4;
      int row = bm + r; if (row >= NN) row = NN - 1;   // clamp (writes guarded)
      const float4 v = *(const float4*)&x[(long)row * IND + k0 + kq];
      xs[kq + 0][r] = v.x; xs[kq + 1][r] = v.y;
      xs[kq + 2][r] = v.z; xs[kq + 3][r] = v.w;
    }
#pragma unroll
    for (int i = 0; i < 4; i++) {
      int f = tid + i * 256;
      int kr = f >> 5;
      int cq = (f & 31) * 4;
      *(float4*)&ws[kr][cq] = *(const float4*)&W[(k0 + kr) * OUTD + cq];
    }
    __syncthreads();
#pragma unroll
    for (int kk = 0; kk < 32; kk++) {
      float4 xa = *(const float4*)&xs[kk][ty * 4];
      float4 wa = *(const float4*)&ws[kk][tx * 8];
      float4 wb = *(const float4*)&ws[kk][tx * 8 + 4];
      float xr[4] = {xa.x, xa.y, xa.z, xa.w};
      float wr[8] = {wa.x, wa.y, wa.z, wa.w, wb.x, wb.y, wb.z, wb.w};
#pragma unroll
      for (int i = 0; i < 4; i++)
#pragma unroll
        for (int j = 0; j < 8; j++)
          acc[i][j] = fmaf(xr[i], wr[j], acc[i][j]);
    }
    __syncthreads();
  }
#pragma unroll
  for (int i = 0; i < 4; i++) {
    int row = bm + ty * 4 + i;
    if (row < NN) {
      float4 o0 = make_float4(acc[i][0], acc[i][1], acc[i][2], acc[i][3]);
      float4 o1 = make_float4(acc[i][4], acc[i][5], acc[i][6], acc[i][7]);
      *(float4*)&Wh[(long)row * OUTD + tx * 8] = o0;
      *(float4*)&Wh[(long)row * OUTD + tx * 8 + 4] = o1;
    }
  }
}

// ---------- K2: s_src[n] = Wh[n]@a[:128], s_tgt[n] = Wh[n]@a[128:] ----------
__global__ __launch_bounds__(256) void k_s(const float* __restrict__ Wh,
                                           const float* __restrict__ a,
                                           float* __restrict__ s_src,
                                           float* __restrict__ s_tgt) {
  int wid = (blockIdx.x * 256 + threadIdx.x) >> 6;    // one wave per node
  int lane = threadIdx.x & 63;
  if (wid >= NN) return;
  float w0 = Wh[(long)wid * OUTD + lane];
  float w1 = Wh[(long)wid * OUTD + 64 + lane];
  float p1 = w0 * a[lane]       + w1 * a[64 + lane];
  float p2 = w0 * a[128 + lane] + w1 * a[192 + lane];
#pragma unroll
  for (int off = 32; off; off >>= 1) {
    p1 += __shfl_down(p1, off);
    p2 += __shfl_down(p2, off);
  }
  if (lane == 0) { s_src[wid] = p1; s_tgt[wid] = p2; }
}

// ---------- K3: scores + global max + target histogram ----------
__global__ __launch_bounds__(256) void k_score(const int* __restrict__ ei,
                                               const float* __restrict__ s_src,
                                               const float* __restrict__ s_tgt,
                                               float* __restrict__ scores,
                                               unsigned* __restrict__ umax,
                                               int* __restrict__ cnt) {
  int e = blockIdx.x * 256 + threadIdx.x;             // grid covers NE exactly
  int s = ei[e];
  int t = ei[NE + e];
  float v = s_src[s] + s_tgt[t];
  float sc = v > 0.f ? v : 0.2f * v;                  // leaky_relu(0.2)
  scores[e] = sc;
  atomicAdd(&cnt[t], 1);                              // histogram of targets
  // block max
  float m = sc;
#pragma unroll
  for (int off = 32; off; off >>= 1) m = fmaxf(m, __shfl_down(m, off));
  __shared__ float red[4];
  int w = threadIdx.x >> 6, lane = threadIdx.x & 63;
  if (lane == 0) red[w] = m;
  __syncthreads();
  if (threadIdx.x == 0) {
    float bm = fmaxf(fmaxf(red[0], red[1]), fmaxf(red[2], red[3]));
    atomicMax(umax, enc_f(bm));
  }
}

// ---------- K4: sum of exp(score - max) ----------
__global__ __launch_bounds__(256) void k_sum(const float* __restrict__ scores,
                                             const unsigned* __restrict__ umax,
                                             float* __restrict__ sumexp) {
  int e = blockIdx.x * 256 + threadIdx.x;
  float m = dec_f(*umax);
  float v = __expf(scores[e] - m);
#pragma unroll
  for (int off = 32; off; off >>= 1) v += __shfl_down(v, off);
  __shared__ float red[4];
  int w = threadIdx.x >> 6, lane = threadIdx.x & 63;
  if (lane == 0) red[w] = v;
  __syncthreads();
  if (threadIdx.x == 0)
    atomicAdd(sumexp, red[0] + red[1] + red[2] + red[3]);
}

// ---------- K5: exclusive prefix-sum of cnt -> offs, cursor (1 block) ----------
__global__ __launch_bounds__(1024) void k_scan(const int* __restrict__ cnt,
                                               int* __restrict__ offs,
                                               int* __restrict__ cursor) {
  __shared__ int sums[1024];
  const int tid = threadIdx.x;
  const int CH = 49;                                  // 1024*49 = 50176 >= NN
  int base = tid * CH;
  int s = 0;
  for (int i = 0; i < CH; i++) {
    int idx = base + i;
    if (idx < NN) s += cnt[idx];
  }
  sums[tid] = s;
  __syncthreads();
  for (int off = 1; off < 1024; off <<= 1) {          // Hillis-Steele inclusive
    int v = (tid >= off) ? sums[tid - off] : 0;
    __syncthreads();
    sums[tid] += v;
    __syncthreads();
  }
  int run = (tid == 0) ? 0 : sums[tid - 1];
  for (int i = 0; i < CH; i++) {
    int idx = base + i;
    if (idx < NN) {
      offs[idx] = run;
      cursor[idx] = run;
      run += cnt[idx];
    }
  }
}

// ---------- K6: bin edges by target: (src, alpha) into sorted slots ----------
__global__ __launch_bounds__(256) void k_bin(const int* __restrict__ ei,
                                             const float* __restrict__ scores,
                                             const unsigned* __restrict__ umax,
                                             const float* __restrict__ sumexp,
                                             int* __restrict__ cursor,
                                             int* __restrict__ ssrc,
                                             float* __restrict__ salpha) {
  int e = blockIdx.x * 256 + threadIdx.x;
  int t = ei[NE + e];
  float m = dec_f(*umax);
  float inv = 1.0f / *sumexp;
  int pos = atomicAdd(&cursor[t], 1);
  ssrc[pos] = ei[e];
  salpha[pos] = __expf(scores[e] - m) * inv;
}

// ---------- K7: gather-sum per target node (one wave per node) ----------
__global__ __launch_bounds__(256) void k_gather(const int* __restrict__ offs,
                                                const int* __restrict__ cnt,
                                                const int* __restrict__ ssrc,
                                                const float* __restrict__ salpha,
                                                const float* __restrict__ Wh,
                                                float* __restrict__ xnew) {
  int wid = (blockIdx.x * 256 + threadIdx.x) >> 6;    // 12500*4 = NN waves
  int lane = threadIdx.x & 63;
  int start = offs[wid];
  int n = cnt[wid];
  const float2* __restrict__ Wh2 = (const float2*)Wh;
  float2 acc = make_float2(0.f, 0.f);
  for (int i = 0; i < n; i++) {
    int s = ssrc[start + i];
    float al = salpha[start + i];
    float2 v = Wh2[(long)s * 64 + lane];
    acc.x = fmaf(al, v.x, acc.x);
    acc.y = fmaf(al, v.y, acc.y);
  }
  ((float2*)xnew)[(long)wid * 64 + lane] = acc;
}

// ---------- K8: MLP head ----------
__global__ __launch_bounds__(256) void k_mlp(const float* __restrict__ xnew,
                                             const float* __restrict__ W1,
                                             const float* __restrict__ b1,
                                             const float* __restrict__ W2,
                                             const float* __restrict__ b2,
                                             float* __restrict__ evid) {
  __shared__ float xs[4][128];
  __shared__ float hs[4][64];
  int w = threadIdx.x >> 6, lane = threadIdx.x & 63;
  int n = blockIdx.x * 4 + w;               // 12500*4 = NN exactly
  xs[w][lane]      = xnew[(long)n * OUTD + lane];
  xs[w][64 + lane] = xnew[(long)n * OUTD + 64 + lane];
  __syncthreads();
  float h = b1[lane];
#pragma unroll 4
  for (int k = 0; k < OUTD; k++)
    h = fmaf(xs[w][k], W1[k * HIDD + lane], h);
  h = fmaxf(h, 0.f);
  hs[w][lane] = h;
  __syncthreads();
  if (lane < 3) {
    float ev = b2[lane];
    for (int k = 0; k < HIDD; k++)
      ev = fmaf(hs[w][k], W2[k * 3 + lane], ev);
    float sp = ev > 20.f ? ev : log1pf(expf(ev));
    evid[(long)n * 3 + lane] = sp + 1.0f;
  }
}

extern "C" void kernel_launch(void* const* d_in, const int* in_sizes, int n_in,
                              void* d_out, int out_size, void* d_ws, size_t ws_size,
                              hipStream_t stream) {
  const float* x   = (const float*)d_in[0];
  const int*   ei  = (const int*)d_in[1];
  const float* W   = (const float*)d_in[2];
  const float* a   = (const float*)d_in[3];
  const float* W1  = (const float*)d_in[4];
  const float* b1  = (const float*)d_in[5];
  const float* W2  = (const float*)d_in[6];
  const float* b2  = (const float*)d_in[7];

  float* xnew = (float*)d_out;                       // [NN*OUTD]
  float* evid = (float*)d_out + (size_t)NN * OUTD;   // [NN*3]

  float* wsf = (float*)d_ws;
  float*    Wh     = wsf;                            // 6,400,000 f (25.6 MB)
  float*    s_src  = wsf + 6400000;                  //    50,000 f
  float*    s_tgt  = wsf + 6450000;                  //    50,000 f
  float*    scores = wsf + 6500000;                  //   800,000 f
  float*    salpha = wsf + 7300000;                  //   800,000 f
  unsigned* umax   = (unsigned*)(wsf + 8100000);
  float*    sumexp = wsf + 8100002;
  int*      cnt    = (int*)(wsf + 8100004);          //    50,000 i
  int*      offs   = (int*)(wsf + 8150004);          //    50,000 i
  int*      cursor = (int*)(wsf + 8200004);          //    50,000 i
  int*      ssrc   = (int*)(wsf + 8250004);          //   800,000 i  (end ~36.2 MB)

  k_zero<<<196, 256, 0, stream>>>(cnt, umax, sumexp);
  k_gemm<<<(NN + 63) / 64, 256, 0, stream>>>(x, W, Wh);
  k_s<<<12500, 256, 0, stream>>>(Wh, a, s_src, s_tgt);
  k_score<<<NE / 256, 256, 0, stream>>>(ei, s_src, s_tgt, scores, umax, cnt);
  k_sum<<<NE / 256, 256, 0, stream>>>(scores, umax, sumexp);
  k_scan<<<1, 1024, 0, stream>>>(cnt, offs, cursor);
  k_bin<<<NE / 256, 256, 0, stream>>>(ei, scores, umax, sumexp, cursor, ssrc, salpha);
  k_gather<<<NN / 4, 256, 0, stream>>>(offs, cnt, ssrc, salpha, Wh, xnew);
  k_mlp<<<NN / 4, 256, 0, stream>>>(xnew, W1, b1, W2, b2, evid);
}

// Round 3
// 394.666 us; speedup vs baseline: 2.2625x; 1.2963x over previous
//
#include <hip/hip_runtime.h>
#include <math.h>

#define NN 50000
#define NE 800000
#define IND 256
#define OUTD 128
#define HIDD 64
#define NBLK 196   // ceil(NN/256)

// ---------- helpers: ordered-uint encoding of float for atomicMax ----------
static __device__ __forceinline__ unsigned enc_f(float f) {
  unsigned u = __float_as_uint(f);
  return (u & 0x80000000u) ? ~u : (u | 0x80000000u);
}
static __device__ __forceinline__ float dec_f(unsigned u) {
  unsigned b = (u & 0x80000000u) ? (u ^ 0x80000000u) : ~u;
  return __uint_as_float(b);
}

// ---------- K0: zero target-histogram + init reduction scalars ----------
__global__ __launch_bounds__(256) void k_zero(int* __restrict__ cnt,
                                              unsigned* __restrict__ umax,
                                              float* __restrict__ sumexp) {
  int i = blockIdx.x * 256 + threadIdx.x;     // 196*256 = 50176 >= NN
  if (i < NN) cnt[i] = 0;
  if (i == 0) { *umax = 0x007FFFFFu /* enc(-inf) */; *sumexp = 0.f; }
}

// ---------- K1: Wh = x @ W  (f32 vector GEMM, BM=64 BN=128 BK=32) ----------
__global__ __launch_bounds__(256) void k_gemm(const float* __restrict__ x,
                                              const float* __restrict__ W,
                                              float* __restrict__ Wh) {
  __shared__ float xs[32][64];    // [k][m]
  __shared__ float ws[32][128];   // [k][n]
  const int tid = threadIdx.x;
  const int bm = blockIdx.x * 64;
  const int ty = tid >> 4;        // 0..15 -> rows ty*4..ty*4+3
  const int tx = tid & 15;        // cols tx*8..tx*8+7
  float acc[4][8];
#pragma unroll
  for (int i = 0; i < 4; i++)
#pragma unroll
    for (int j = 0; j < 8; j++) acc[i][j] = 0.f;

  for (int k0 = 0; k0 < IND; k0 += 32) {
#pragma unroll
    for (int i = 0; i < 2; i++) {
      int f = tid + i * 256;
      int r = f >> 3;
      int kq = (f & 7) * 4;
      int row = bm + r; if (row >= NN) row = NN - 1;   // clamp (writes guarded)
      const float4 v = *(const float4*)&x[(long)row * IND + k0 + kq];
      xs[kq + 0][r] = v.x; xs[kq + 1][r] = v.y;
      xs[kq + 2][r] = v.z; xs[kq + 3][r] = v.w;
    }
#pragma unroll
    for (int i = 0; i < 4; i++) {
      int f = tid + i * 256;
      int kr = f >> 5;
      int cq = (f & 31) * 4;
      *(float4*)&ws[kr][cq] = *(const float4*)&W[(k0 + kr) * OUTD + cq];
    }
    __syncthreads();
#pragma unroll
    for (int kk = 0; kk < 32; kk++) {
      float4 xa = *(const float4*)&xs[kk][ty * 4];
      float4 wa = *(const float4*)&ws[kk][tx * 8];
      float4 wb = *(const float4*)&ws[kk][tx * 8 + 4];
      float xr[4] = {xa.x, xa.y, xa.z, xa.w};
      float wr[8] = {wa.x, wa.y, wa.z, wa.w, wb.x, wb.y, wb.z, wb.w};
#pragma unroll
      for (int i = 0; i < 4; i++)
#pragma unroll
        for (int j = 0; j < 8; j++)
          acc[i][j] = fmaf(xr[i], wr[j], acc[i][j]);
    }
    __syncthreads();
  }
#pragma unroll
  for (int i = 0; i < 4; i++) {
    int row = bm + ty * 4 + i;
    if (row < NN) {
      float4 o0 = make_float4(acc[i][0], acc[i][1], acc[i][2], acc[i][3]);
      float4 o1 = make_float4(acc[i][4], acc[i][5], acc[i][6], acc[i][7]);
      *(float4*)&Wh[(long)row * OUTD + tx * 8] = o0;
      *(float4*)&Wh[(long)row * OUTD + tx * 8 + 4] = o1;
    }
  }
}

// ---------- K2: s_src[n] = Wh[n]@a[:128], s_tgt[n] = Wh[n]@a[128:] ----------
__global__ __launch_bounds__(256) void k_s(const float* __restrict__ Wh,
                                           const float* __restrict__ a,
                                           float* __restrict__ s_src,
                                           float* __restrict__ s_tgt) {
  int wid = (blockIdx.x * 256 + threadIdx.x) >> 6;    // one wave per node
  int lane = threadIdx.x & 63;
  if (wid >= NN) return;
  float w0 = Wh[(long)wid * OUTD + lane];
  float w1 = Wh[(long)wid * OUTD + 64 + lane];
  float p1 = w0 * a[lane]       + w1 * a[64 + lane];
  float p2 = w0 * a[128 + lane] + w1 * a[192 + lane];
#pragma unroll
  for (int off = 32; off; off >>= 1) {
    p1 += __shfl_down(p1, off);
    p2 += __shfl_down(p2, off);
  }
  if (lane == 0) { s_src[wid] = p1; s_tgt[wid] = p2; }
}

// ---------- K3: scores + global max + target histogram ----------
__global__ __launch_bounds__(256) void k_score(const int* __restrict__ ei,
                                               const float* __restrict__ s_src,
                                               const float* __restrict__ s_tgt,
                                               float* __restrict__ scores,
                                               unsigned* __restrict__ umax,
                                               int* __restrict__ cnt) {
  int e = blockIdx.x * 256 + threadIdx.x;             // grid covers NE exactly
  int s = ei[e];
  int t = ei[NE + e];
  float v = s_src[s] + s_tgt[t];
  float sc = v > 0.f ? v : 0.2f * v;                  // leaky_relu(0.2)
  scores[e] = sc;
  atomicAdd(&cnt[t], 1);                              // histogram of targets
  // block max
  float m = sc;
#pragma unroll
  for (int off = 32; off; off >>= 1) m = fmaxf(m, __shfl_down(m, off));
  __shared__ float red[4];
  int w = threadIdx.x >> 6, lane = threadIdx.x & 63;
  if (lane == 0) red[w] = m;
  __syncthreads();
  if (threadIdx.x == 0) {
    float bm = fmaxf(fmaxf(red[0], red[1]), fmaxf(red[2], red[3]));
    atomicMax(umax, enc_f(bm));
  }
}

// ---------- K4: sum of exp(score - max) ----------
__global__ __launch_bounds__(256) void k_sum(const float* __restrict__ scores,
                                             const unsigned* __restrict__ umax,
                                             float* __restrict__ sumexp) {
  int e = blockIdx.x * 256 + threadIdx.x;
  float m = dec_f(*umax);
  float v = __expf(scores[e] - m);
#pragma unroll
  for (int off = 32; off; off >>= 1) v += __shfl_down(v, off);
  __shared__ float red[4];
  int w = threadIdx.x >> 6, lane = threadIdx.x & 63;
  if (lane == 0) red[w] = v;
  __syncthreads();
  if (threadIdx.x == 0)
    atomicAdd(sumexp, red[0] + red[1] + red[2] + red[3]);
}

// ---------- K5a: per-block sums of cnt ----------
__global__ __launch_bounds__(256) void k_scan1(const int* __restrict__ cnt,
                                               int* __restrict__ bsum) {
  int i = blockIdx.x * 256 + threadIdx.x;
  int v = (i < NN) ? cnt[i] : 0;
#pragma unroll
  for (int off = 32; off; off >>= 1) v += __shfl_down(v, off);
  __shared__ int red[4];
  int w = threadIdx.x >> 6, lane = threadIdx.x & 63;
  if (lane == 0) red[w] = v;
  __syncthreads();
  if (threadIdx.x == 0)
    bsum[blockIdx.x] = red[0] + red[1] + red[2] + red[3];
}

// ---------- K5b: exclusive scan of 196 block sums (1 small block) ----------
__global__ __launch_bounds__(256) void k_scan2(int* __restrict__ bsum) {
  __shared__ int s[256];
  int tid = threadIdx.x;
  int v = (tid < NBLK) ? bsum[tid] : 0;
  s[tid] = v;
  __syncthreads();
  for (int off = 1; off < 256; off <<= 1) {
    int t = (tid >= off) ? s[tid - off] : 0;
    __syncthreads();
    s[tid] += t;
    __syncthreads();
  }
  int excl = (tid == 0) ? 0 : s[tid - 1];
  if (tid < NBLK) bsum[tid] = excl;
}

// ---------- K5c: block-local exclusive scan + base -> offs, cursor ----------
__global__ __launch_bounds__(256) void k_scan3(const int* __restrict__ cnt,
                                               const int* __restrict__ bsum,
                                               int* __restrict__ offs,
                                               int* __restrict__ cursor) {
  int i = blockIdx.x * 256 + threadIdx.x;
  int lane = threadIdx.x & 63;
  int w = threadIdx.x >> 6;
  int v = (i < NN) ? cnt[i] : 0;
  // wave-level inclusive scan
  int inc = v;
#pragma unroll
  for (int off = 1; off < 64; off <<= 1) {
    int t = __shfl_up(inc, off);
    if (lane >= off) inc += t;
  }
  __shared__ int wsum[4];
  if (lane == 63) wsum[w] = inc;
  __syncthreads();
  int woff = 0;
#pragma unroll
  for (int j = 0; j < 4; j++) woff += (j < w) ? wsum[j] : 0;
  int excl = bsum[blockIdx.x] + woff + inc - v;
  if (i < NN) { offs[i] = excl; cursor[i] = excl; }
}

// ---------- K6: bin edges by target: (src, alpha) into sorted slots ----------
__global__ __launch_bounds__(256) void k_bin(const int* __restrict__ ei,
                                             const float* __restrict__ scores,
                                             const unsigned* __restrict__ umax,
                                             const float* __restrict__ sumexp,
                                             int* __restrict__ cursor,
                                             int* __restrict__ ssrc,
                                             float* __restrict__ salpha) {
  int e = blockIdx.x * 256 + threadIdx.x;
  int t = ei[NE + e];
  float m = dec_f(*umax);
  float inv = 1.0f / *sumexp;
  int pos = atomicAdd(&cursor[t], 1);
  ssrc[pos] = ei[e];
  salpha[pos] = __expf(scores[e] - m) * inv;
}

// ---------- K7: gather-sum per target node (one wave per node) ----------
__global__ __launch_bounds__(256) void k_gather(const int* __restrict__ offs,
                                                const int* __restrict__ cnt,
                                                const int* __restrict__ ssrc,
                                                const float* __restrict__ salpha,
                                                const float* __restrict__ Wh,
                                                float* __restrict__ xnew) {
  int wid = (blockIdx.x * 256 + threadIdx.x) >> 6;    // 12500*4 = NN waves
  int lane = threadIdx.x & 63;
  int start = offs[wid];
  int n = cnt[wid];
  const float2* __restrict__ Wh2 = (const float2*)Wh;
  float2 acc = make_float2(0.f, 0.f);
  for (int i = 0; i < n; i++) {
    int s = ssrc[start + i];
    float al = salpha[start + i];
    float2 v = Wh2[(long)s * 64 + lane];
    acc.x = fmaf(al, v.x, acc.x);
    acc.y = fmaf(al, v.y, acc.y);
  }
  ((float2*)xnew)[(long)wid * 64 + lane] = acc;
}

// ---------- K8: MLP head ----------
__global__ __launch_bounds__(256) void k_mlp(const float* __restrict__ xnew,
                                             const float* __restrict__ W1,
                                             const float* __restrict__ b1,
                                             const float* __restrict__ W2,
                                             const float* __restrict__ b2,
                                             float* __restrict__ evid) {
  __shared__ float xs[4][128];
  __shared__ float hs[4][64];
  int w = threadIdx.x >> 6, lane = threadIdx.x & 63;
  int n = blockIdx.x * 4 + w;               // 12500*4 = NN exactly
  xs[w][lane]      = xnew[(long)n * OUTD + lane];
  xs[w][64 + lane] = xnew[(long)n * OUTD + 64 + lane];
  __syncthreads();
  float h = b1[lane];
#pragma unroll 4
  for (int k = 0; k < OUTD; k++)
    h = fmaf(xs[w][k], W1[k * HIDD + lane], h);
  h = fmaxf(h, 0.f);
  hs[w][lane] = h;
  __syncthreads();
  if (lane < 3) {
    float ev = b2[lane];
    for (int k = 0; k < HIDD; k++)
      ev = fmaf(hs[w][k], W2[k * 3 + lane], ev);
    float sp = ev > 20.f ? ev : log1pf(expf(ev));
    evid[(long)n * 3 + lane] = sp + 1.0f;
  }
}

extern "C" void kernel_launch(void* const* d_in, const int* in_sizes, int n_in,
                              void* d_out, int out_size, void* d_ws, size_t ws_size,
                              hipStream_t stream) {
  const float* x   = (const float*)d_in[0];
  const int*   ei  = (const int*)d_in[1];
  const float* W   = (const float*)d_in[2];
  const float* a   = (const float*)d_in[3];
  const float* W1  = (const float*)d_in[4];
  const float* b1  = (const float*)d_in[5];
  const float* W2  = (const float*)d_in[6];
  const float* b2  = (const float*)d_in[7];

  float* xnew = (float*)d_out;                       // [NN*OUTD]
  float* evid = (float*)d_out + (size_t)NN * OUTD;   // [NN*3]

  float* wsf = (float*)d_ws;
  float*    Wh     = wsf;                            // 6,400,000 f (25.6 MB)
  float*    s_src  = wsf + 6400000;                  //    50,000 f
  float*    s_tgt  = wsf + 6450000;                  //    50,000 f
  float*    scores = wsf + 6500000;                  //   800,000 f
  float*    salpha = wsf + 7300000;                  //   800,000 f
  unsigned* umax   = (unsigned*)(wsf + 8100000);
  float*    sumexp = wsf + 8100002;
  int*      cnt    = (int*)(wsf + 8100004);          //    50,000 i
  int*      offs   = (int*)(wsf + 8150004);          //    50,000 i
  int*      cursor = (int*)(wsf + 8200004);          //    50,000 i
  int*      ssrc   = (int*)(wsf + 8250004);          //   800,000 i
  int*      bsum   = (int*)(wsf + 9050004);          //       196 i (end ~36.2 MB)

  k_zero<<<196, 256, 0, stream>>>(cnt, umax, sumexp);
  k_gemm<<<(NN + 63) / 64, 256, 0, stream>>>(x, W, Wh);
  k_s<<<12500, 256, 0, stream>>>(Wh, a, s_src, s_tgt);
  k_score<<<NE / 256, 256, 0, stream>>>(ei, s_src, s_tgt, scores, umax, cnt);
  k_sum<<<NE / 256, 256, 0, stream>>>(scores, umax, sumexp);
  k_scan1<<<NBLK, 256, 0, stream>>>(cnt, bsum);
  k_scan2<<<1, 256, 0, stream>>>(bsum);
  k_scan3<<<NBLK, 256, 0, stream>>>(cnt, bsum, offs, cursor);
  k_bin<<<NE / 256, 256, 0, stream>>>(ei, scores, umax, sumexp, cursor, ssrc, salpha);
  k_gather<<<NN / 4, 256, 0, stream>>>(offs, cnt, ssrc, salpha, Wh, xnew);
  k_mlp<<<NN / 4, 256, 0, stream>>>(xnew, W1, b1, W2, b2, evid);
}

// Round 4
// 348.917 us; speedup vs baseline: 2.5591x; 1.1311x over previous
//
#include <hip/hip_runtime.h>
#include <math.h>

#define NN 50000
#define NE 800000
#define IND 256
#define OUTD 128
#define HIDD 64
#define NBLK 196   // ceil(NN/256)

// ---------- helpers: ordered-uint encoding of float for atomicMax ----------
static __device__ __forceinline__ unsigned enc_f(float f) {
  unsigned u = __float_as_uint(f);
  return (u & 0x80000000u) ? ~u : (u | 0x80000000u);
}
static __device__ __forceinline__ float dec_f(unsigned u) {
  unsigned b = (u & 0x80000000u) ? (u ^ 0x80000000u) : ~u;
  return __uint_as_float(b);
}

// ---------- K0: zero target-histogram + init reduction scalars ----------
__global__ __launch_bounds__(256) void k_zero(int* __restrict__ cnt,
                                              unsigned* __restrict__ umax,
                                              float* __restrict__ sumexp) {
  int i = blockIdx.x * 256 + threadIdx.x;     // 196*256 = 50176 >= NN
  if (i < NN) cnt[i] = 0;
  if (i == 0) { *umax = 0x007FFFFFu /* enc(-inf) */; *sumexp = 0.f; }
}

// ---------- K1: Wh = x @ W  (f32 vector GEMM, BM=64 BN=128 BK=32) ----------
__global__ __launch_bounds__(256) void k_gemm(const float* __restrict__ x,
                                              const float* __restrict__ W,
                                              float* __restrict__ Wh) {
  __shared__ float xs[32][64];    // [k][m]
  __shared__ float ws[32][128];   // [k][n]
  const int tid = threadIdx.x;
  const int bm = blockIdx.x * 64;
  const int ty = tid >> 4;        // 0..15 -> rows ty*4..ty*4+3
  const int tx = tid & 15;        // cols tx*8..tx*8+7
  float acc[4][8];
#pragma unroll
  for (int i = 0; i < 4; i++)
#pragma unroll
    for (int j = 0; j < 8; j++) acc[i][j] = 0.f;

  for (int k0 = 0; k0 < IND; k0 += 32) {
#pragma unroll
    for (int i = 0; i < 2; i++) {
      int f = tid + i * 256;
      int r = f >> 3;
      int kq = (f & 7) * 4;
      int row = bm + r; if (row >= NN) row = NN - 1;   // clamp (writes guarded)
      const float4 v = *(const float4*)&x[(long)row * IND + k0 + kq];
      xs[kq + 0][r] = v.x; xs[kq + 1][r] = v.y;
      xs[kq + 2][r] = v.z; xs[kq + 3][r] = v.w;
    }
#pragma unroll
    for (int i = 0; i < 4; i++) {
      int f = tid + i * 256;
      int kr = f >> 5;
      int cq = (f & 31) * 4;
      *(float4*)&ws[kr][cq] = *(const float4*)&W[(k0 + kr) * OUTD + cq];
    }
    __syncthreads();
#pragma unroll
    for (int kk = 0; kk < 32; kk++) {
      float4 xa = *(const float4*)&xs[kk][ty * 4];
      float4 wa = *(const float4*)&ws[kk][tx * 8];
      float4 wb = *(const float4*)&ws[kk][tx * 8 + 4];
      float xr[4] = {xa.x, xa.y, xa.z, xa.w};
      float wr[8] = {wa.x, wa.y, wa.z, wa.w, wb.x, wb.y, wb.z, wb.w};
#pragma unroll
      for (int i = 0; i < 4; i++)
#pragma unroll
        for (int j = 0; j < 8; j++)
          acc[i][j] = fmaf(xr[i], wr[j], acc[i][j]);
    }
    __syncthreads();
  }
#pragma unroll
  for (int i = 0; i < 4; i++) {
    int row = bm + ty * 4 + i;
    if (row < NN) {
      float4 o0 = make_float4(acc[i][0], acc[i][1], acc[i][2], acc[i][3]);
      float4 o1 = make_float4(acc[i][4], acc[i][5], acc[i][6], acc[i][7]);
      *(float4*)&Wh[(long)row * OUTD + tx * 8] = o0;
      *(float4*)&Wh[(long)row * OUTD + tx * 8 + 4] = o1;
    }
  }
}

// ---------- K2: s_src[n] = Wh[n]@a[:128], s_tgt[n] = Wh[n]@a[128:] ----------
__global__ __launch_bounds__(256) void k_s(const float* __restrict__ Wh,
                                           const float* __restrict__ a,
                                           float* __restrict__ s_src,
                                           float* __restrict__ s_tgt) {
  int wid = (blockIdx.x * 256 + threadIdx.x) >> 6;    // one wave per node
  int lane = threadIdx.x & 63;
  if (wid >= NN) return;
  float w0 = Wh[(long)wid * OUTD + lane];
  float w1 = Wh[(long)wid * OUTD + 64 + lane];
  float p1 = w0 * a[lane]       + w1 * a[64 + lane];
  float p2 = w0 * a[128 + lane] + w1 * a[192 + lane];
#pragma unroll
  for (int off = 32; off; off >>= 1) {
    p1 += __shfl_down(p1, off);
    p2 += __shfl_down(p2, off);
  }
  if (lane == 0) { s_src[wid] = p1; s_tgt[wid] = p2; }
}

// ---------- K3: scores + global max + target histogram ----------
__global__ __launch_bounds__(256) void k_score(const int* __restrict__ ei,
                                               const float* __restrict__ s_src,
                                               const float* __restrict__ s_tgt,
                                               float* __restrict__ scores,
                                               unsigned* __restrict__ umax,
                                               int* __restrict__ cnt) {
  int e = blockIdx.x * 256 + threadIdx.x;             // grid covers NE exactly
  int s = ei[e];
  int t = ei[NE + e];
  float v = s_src[s] + s_tgt[t];
  float sc = v > 0.f ? v : 0.2f * v;                  // leaky_relu(0.2)
  scores[e] = sc;
  atomicAdd(&cnt[t], 1);                              // histogram of targets
  // block max
  float m = sc;
#pragma unroll
  for (int off = 32; off; off >>= 1) m = fmaxf(m, __shfl_down(m, off));
  __shared__ float red[4];
  int w = threadIdx.x >> 6, lane = threadIdx.x & 63;
  if (lane == 0) red[w] = m;
  __syncthreads();
  if (threadIdx.x == 0) {
    float bm = fmaxf(fmaxf(red[0], red[1]), fmaxf(red[2], red[3]));
    atomicMax(umax, enc_f(bm));
  }
}

// ---------- K4: sum of exp(score - max) ----------
__global__ __launch_bounds__(256) void k_sum(const float* __restrict__ scores,
                                             const unsigned* __restrict__ umax,
                                             float* __restrict__ sumexp) {
  int e = blockIdx.x * 256 + threadIdx.x;
  float m = dec_f(*umax);
  float v = __expf(scores[e] - m);
#pragma unroll
  for (int off = 32; off; off >>= 1) v += __shfl_down(v, off);
  __shared__ float red[4];
  int w = threadIdx.x >> 6, lane = threadIdx.x & 63;
  if (lane == 0) red[w] = v;
  __syncthreads();
  if (threadIdx.x == 0)
    atomicAdd(sumexp, red[0] + red[1] + red[2] + red[3]);
}

// ---------- K5a: per-block sums of cnt ----------
__global__ __launch_bounds__(256) void k_scan1(const int* __restrict__ cnt,
                                               int* __restrict__ bsum) {
  int i = blockIdx.x * 256 + threadIdx.x;
  int v = (i < NN) ? cnt[i] : 0;
#pragma unroll
  for (int off = 32; off; off >>= 1) v += __shfl_down(v, off);
  __shared__ int red[4];
  int w = threadIdx.x >> 6, lane = threadIdx.x & 63;
  if (lane == 0) red[w] = v;
  __syncthreads();
  if (threadIdx.x == 0)
    bsum[blockIdx.x] = red[0] + red[1] + red[2] + red[3];
}

// ---------- K5b: exclusive scan of 196 block sums (1 small block) ----------
__global__ __launch_bounds__(256) void k_scan2(int* __restrict__ bsum) {
  __shared__ int s[256];
  int tid = threadIdx.x;
  int v = (tid < NBLK) ? bsum[tid] : 0;
  s[tid] = v;
  __syncthreads();
  for (int off = 1; off < 256; off <<= 1) {
    int t = (tid >= off) ? s[tid - off] : 0;
    __syncthreads();
    s[tid] += t;
    __syncthreads();
  }
  int excl = (tid == 0) ? 0 : s[tid - 1];
  if (tid < NBLK) bsum[tid] = excl;
}

// ---------- K5c: block-local exclusive scan + base -> offs, cursor ----------
__global__ __launch_bounds__(256) void k_scan3(const int* __restrict__ cnt,
                                               const int* __restrict__ bsum,
                                               int* __restrict__ offs,
                                               int* __restrict__ cursor) {
  int i = blockIdx.x * 256 + threadIdx.x;
  int lane = threadIdx.x & 63;
  int w = threadIdx.x >> 6;
  int v = (i < NN) ? cnt[i] : 0;
  // wave-level inclusive scan
  int inc = v;
#pragma unroll
  for (int off = 1; off < 64; off <<= 1) {
    int t = __shfl_up(inc, off);
    if (lane >= off) inc += t;
  }
  __shared__ int wsum[4];
  if (lane == 63) wsum[w] = inc;
  __syncthreads();
  int woff = 0;
#pragma unroll
  for (int j = 0; j < 4; j++) woff += (j < w) ? wsum[j] : 0;
  int excl = bsum[blockIdx.x] + woff + inc - v;
  if (i < NN) { offs[i] = excl; cursor[i] = excl; }
}

// ---------- K6: bin edges by target: (src, alpha) into sorted slots ----------
__global__ __launch_bounds__(256) void k_bin(const int* __restrict__ ei,
                                             const float* __restrict__ scores,
                                             const unsigned* __restrict__ umax,
                                             const float* __restrict__ sumexp,
                                             int* __restrict__ cursor,
                                             int* __restrict__ ssrc,
                                             float* __restrict__ salpha) {
  int e = blockIdx.x * 256 + threadIdx.x;
  int t = ei[NE + e];
  float m = dec_f(*umax);
  float inv = 1.0f / *sumexp;
  int pos = atomicAdd(&cursor[t], 1);
  ssrc[pos] = ei[e];
  salpha[pos] = __expf(scores[e] - m) * inv;
}

// ---------- K7: gather-sum per target node (one wave per node) ----------
__global__ __launch_bounds__(256) void k_gather(const int* __restrict__ offs,
                                                const int* __restrict__ cnt,
                                                const int* __restrict__ ssrc,
                                                const float* __restrict__ salpha,
                                                const float* __restrict__ Wh,
                                                float* __restrict__ xnew) {
  int wid = (blockIdx.x * 256 + threadIdx.x) >> 6;    // 12500*4 = NN waves
  int lane = threadIdx.x & 63;
  int start = offs[wid];
  int n = cnt[wid];
  const float2* __restrict__ Wh2 = (const float2*)Wh;
  float2 acc = make_float2(0.f, 0.f);
  for (int i = 0; i < n; i++) {
    int s = ssrc[start + i];
    float al = salpha[start + i];
    float2 v = Wh2[(long)s * 64 + lane];
    acc.x = fmaf(al, v.x, acc.x);
    acc.y = fmaf(al, v.y, acc.y);
  }
  ((float2*)xnew)[(long)wid * 64 + lane] = acc;
}

// ---------- K8: fused MLP head as register-tiled GEMM ----------
// 64 nodes/block, 256 thr. LDS: x-tile [64][132] (33KB) + W1 k-major [128][64]
// (32KB) = 66.5KB -> 2 blocks/CU. Thread (ty=t>>4, tx=t&15) owns acc[4 nodes][4 hid].
// Layer 2 fused: relu(acc+b1) -> per-class partials -> shfl_xor reduce over tx.
__global__ __launch_bounds__(256) void k_mlp(const float* __restrict__ xnew,
                                             const float* __restrict__ W1,
                                             const float* __restrict__ b1,
                                             const float* __restrict__ W2,
                                             const float* __restrict__ b2,
                                             float* __restrict__ evid) {
  __shared__ float xs[64][132];     // row stride 132 (528B, 16B-aligned)
  __shared__ float w1s[128][64];    // [k][hid]
  const int tid = threadIdx.x;
  const int nb = blockIdx.x * 64;
  const int ty = tid >> 4;          // 0..15 -> nodes ty*4..+3
  const int tx = tid & 15;          // 0..15 -> hid tx*4..+3

  // stage x tile: 64 rows x 128 = 2048 float4, 8/thread
#pragma unroll
  for (int i = 0; i < 8; i++) {
    int f = tid + i * 256;
    int n = f >> 5;
    int kq = (f & 31) * 4;
    int row = nb + n; if (row >= NN) row = NN - 1;
    *(float4*)&xs[n][kq] = *(const float4*)&xnew[(long)row * OUTD + kq];
  }
  // stage W1: 128 rows x 64 = 2048 float4, 8/thread
#pragma unroll
  for (int i = 0; i < 8; i++) {
    int f = tid + i * 256;
    int kr = f >> 4;
    int cq = (f & 15) * 4;
    *(float4*)&w1s[kr][cq] = *(const float4*)&W1[kr * HIDD + cq];
  }
  __syncthreads();

  float acc[4][4];
#pragma unroll
  for (int i = 0; i < 4; i++)
#pragma unroll
    for (int j = 0; j < 4; j++) acc[i][j] = 0.f;

#pragma unroll 2
  for (int k0 = 0; k0 < OUTD; k0 += 4) {
    float4 xv[4], wv[4];
#pragma unroll
    for (int i = 0; i < 4; i++) xv[i] = *(const float4*)&xs[ty * 4 + i][k0];
#pragma unroll
    for (int d = 0; d < 4; d++) wv[d] = *(const float4*)&w1s[k0 + d][tx * 4];
#pragma unroll
    for (int i = 0; i < 4; i++) {
      float xr[4] = {xv[i].x, xv[i].y, xv[i].z, xv[i].w};
#pragma unroll
      for (int d = 0; d < 4; d++) {
        float wr[4] = {wv[d].x, wv[d].y, wv[d].z, wv[d].w};
#pragma unroll
        for (int j = 0; j < 4; j++)
          acc[i][j] = fmaf(xr[d], wr[j], acc[i][j]);
      }
    }
  }

  // layer 2 fused in registers
  float b1r[4], w2r[4][3];
#pragma unroll
  for (int j = 0; j < 4; j++) {
    int jg = tx * 4 + j;
    b1r[j] = b1[jg];
    w2r[j][0] = W2[jg * 3 + 0];
    w2r[j][1] = W2[jg * 3 + 1];
    w2r[j][2] = W2[jg * 3 + 2];
  }
#pragma unroll
  for (int i = 0; i < 4; i++) {
    float p0 = 0.f, p1 = 0.f, p2 = 0.f;
#pragma unroll
    for (int j = 0; j < 4; j++) {
      float h = fmaxf(acc[i][j] + b1r[j], 0.f);
      p0 = fmaf(h, w2r[j][0], p0);
      p1 = fmaf(h, w2r[j][1], p1);
      p2 = fmaf(h, w2r[j][2], p2);
    }
#pragma unroll
    for (int m = 1; m < 16; m <<= 1) {
      p0 += __shfl_xor(p0, m);
      p1 += __shfl_xor(p1, m);
      p2 += __shfl_xor(p2, m);
    }
    if (tx == 0) {
      int n = nb + ty * 4 + i;
      if (n < NN) {
        float e0 = p0 + b2[0], e1 = p1 + b2[1], e2 = p2 + b2[2];
        float s0 = e0 > 20.f ? e0 : log1pf(expf(e0));
        float s1 = e1 > 20.f ? e1 : log1pf(expf(e1));
        float s2 = e2 > 20.f ? e2 : log1pf(expf(e2));
        evid[(long)n * 3 + 0] = s0 + 1.0f;
        evid[(long)n * 3 + 1] = s1 + 1.0f;
        evid[(long)n * 3 + 2] = s2 + 1.0f;
      }
    }
  }
}

extern "C" void kernel_launch(void* const* d_in, const int* in_sizes, int n_in,
                              void* d_out, int out_size, void* d_ws, size_t ws_size,
                              hipStream_t stream) {
  const float* x   = (const float*)d_in[0];
  const int*   ei  = (const int*)d_in[1];
  const float* W   = (const float*)d_in[2];
  const float* a   = (const float*)d_in[3];
  const float* W1  = (const float*)d_in[4];
  const float* b1  = (const float*)d_in[5];
  const float* W2  = (const float*)d_in[6];
  const float* b2  = (const float*)d_in[7];

  float* xnew = (float*)d_out;                       // [NN*OUTD]
  float* evid = (float*)d_out + (size_t)NN * OUTD;   // [NN*3]

  float* wsf = (float*)d_ws;
  float*    Wh     = wsf;                            // 6,400,000 f (25.6 MB)
  float*    s_src  = wsf + 6400000;                  //    50,000 f
  float*    s_tgt  = wsf + 6450000;                  //    50,000 f
  float*    scores = wsf + 6500000;                  //   800,000 f
  float*    salpha = wsf + 7300000;                  //   800,000 f
  unsigned* umax   = (unsigned*)(wsf + 8100000);
  float*    sumexp = wsf + 8100002;
  int*      cnt    = (int*)(wsf + 8100004);          //    50,000 i
  int*      offs   = (int*)(wsf + 8150004);          //    50,000 i
  int*      cursor = (int*)(wsf + 8200004);          //    50,000 i
  int*      ssrc   = (int*)(wsf + 8250004);          //   800,000 i
  int*      bsum   = (int*)(wsf + 9050004);          //       196 i (end ~36.2 MB)

  k_zero<<<196, 256, 0, stream>>>(cnt, umax, sumexp);
  k_gemm<<<(NN + 63) / 64, 256, 0, stream>>>(x, W, Wh);
  k_s<<<12500, 256, 0, stream>>>(Wh, a, s_src, s_tgt);
  k_score<<<NE / 256, 256, 0, stream>>>(ei, s_src, s_tgt, scores, umax, cnt);
  k_sum<<<NE / 256, 256, 0, stream>>>(scores, umax, sumexp);
  k_scan1<<<NBLK, 256, 0, stream>>>(cnt, bsum);
  k_scan2<<<1, 256, 0, stream>>>(bsum);
  k_scan3<<<NBLK, 256, 0, stream>>>(cnt, bsum, offs, cursor);
  k_bin<<<NE / 256, 256, 0, stream>>>(ei, scores, umax, sumexp, cursor, ssrc, salpha);
  k_gather<<<NN / 4, 256, 0, stream>>>(offs, cnt, ssrc, salpha, Wh, xnew);
  k_mlp<<<(NN + 63) / 64, 256, 0, stream>>>(xnew, W1, b1, W2, b2, evid);
}

// Round 5
// 295.781 us; speedup vs baseline: 3.0188x; 1.1796x over previous
//
#include <hip/hip_runtime.h>
#include <math.h>

#define NN 50000
#define NE 800000
#define IND 256
#define OUTD 128
#define HIDD 64
#define NBLK 196   // ceil(NN/256)

// ---------- helpers ----------
static __device__ __forceinline__ unsigned enc_f(float f) {
  unsigned u = __float_as_uint(f);
  return (u & 0x80000000u) ? ~u : (u | 0x80000000u);
}
static __device__ __forceinline__ float dec_f(unsigned u) {
  unsigned b = (u & 0x80000000u) ? (u ^ 0x80000000u) : ~u;
  return __uint_as_float(b);
}
static __device__ __forceinline__ unsigned f2bf(float f) {       // RNE f32->bf16 bits
  unsigned u = __float_as_uint(f);
  return (u + 0x7fffu + ((u >> 16) & 1u)) >> 16;
}
static __device__ __forceinline__ float bf2f(unsigned b) {
  return __uint_as_float(b << 16);
}

// ---------- K0: zero target-histogram + init reduction scalars ----------
__global__ __launch_bounds__(256) void k_zero(int* __restrict__ cnt,
                                              unsigned* __restrict__ umax,
                                              float* __restrict__ sumexp) {
  int i = blockIdx.x * 256 + threadIdx.x;     // 196*256 = 50176 >= NN
  if (i < NN) cnt[i] = 0;
  if (i == 0) { *umax = 0x007FFFFFu /* enc(-inf) */; *sumexp = 0.f; }
}

// ---------- K1: Wh16 = bf16(x @ W), fused s_src/s_tgt epilogue ----------
// BM=64 BN=128 BK=32. No f32 Wh is materialized: the gather uses bf16, and
// the attention projections are computed from the f32 accumulators here.
__global__ __launch_bounds__(256) void k_gemm(const float* __restrict__ x,
                                              const float* __restrict__ W,
                                              const float* __restrict__ a,
                                              unsigned* __restrict__ Whu,  // [NN*64] uint = 2 bf16
                                              float* __restrict__ s_src,
                                              float* __restrict__ s_tgt) {
  __shared__ float xs[32][64];    // [k][m]
  __shared__ float ws[32][128];   // [k][n]
  const int tid = threadIdx.x;
  const int bm = blockIdx.x * 64;
  const int ty = tid >> 4;        // 0..15 -> rows ty*4..ty*4+3
  const int tx = tid & 15;        // cols tx*8..tx*8+7
  float acc[4][8];
#pragma unroll
  for (int i = 0; i < 4; i++)
#pragma unroll
    for (int j = 0; j < 8; j++) acc[i][j] = 0.f;

  for (int k0 = 0; k0 < IND; k0 += 32) {
#pragma unroll
    for (int i = 0; i < 2; i++) {
      int f = tid + i * 256;
      int r = f >> 3;
      int kq = (f & 7) * 4;
      int row = bm + r; if (row >= NN) row = NN - 1;   // clamp (writes guarded)
      const float4 v = *(const float4*)&x[(long)row * IND + k0 + kq];
      xs[kq + 0][r] = v.x; xs[kq + 1][r] = v.y;
      xs[kq + 2][r] = v.z; xs[kq + 3][r] = v.w;
    }
#pragma unroll
    for (int i = 0; i < 4; i++) {
      int f = tid + i * 256;
      int kr = f >> 5;
      int cq = (f & 31) * 4;
      *(float4*)&ws[kr][cq] = *(const float4*)&W[(k0 + kr) * OUTD + cq];
    }
    __syncthreads();
#pragma unroll
    for (int kk = 0; kk < 32; kk++) {
      float4 xa = *(const float4*)&xs[kk][ty * 4];
      float4 wa = *(const float4*)&ws[kk][tx * 8];
      float4 wb = *(const float4*)&ws[kk][tx * 8 + 4];
      float xr[4] = {xa.x, xa.y, xa.z, xa.w};
      float wr[8] = {wa.x, wa.y, wa.z, wa.w, wb.x, wb.y, wb.z, wb.w};
#pragma unroll
      for (int i = 0; i < 4; i++)
#pragma unroll
        for (int j = 0; j < 8; j++)
          acc[i][j] = fmaf(xr[i], wr[j], acc[i][j]);
    }
    __syncthreads();
  }

  // bf16 store of the tile
#pragma unroll
  for (int i = 0; i < 4; i++) {
    int row = bm + ty * 4 + i;
    if (row < NN) {
      uint4 o;
      o.x = f2bf(acc[i][0]) | (f2bf(acc[i][1]) << 16);
      o.y = f2bf(acc[i][2]) | (f2bf(acc[i][3]) << 16);
      o.z = f2bf(acc[i][4]) | (f2bf(acc[i][5]) << 16);
      o.w = f2bf(acc[i][6]) | (f2bf(acc[i][7]) << 16);
      *(uint4*)&Whu[(long)row * 64 + tx * 4] = o;
    }
  }

  // fused attention projections: s_src = Wh@a[:128], s_tgt = Wh@a[128:]
  float a1r[8], a2r[8];
#pragma unroll
  for (int j = 0; j < 8; j++) {
    a1r[j] = a[tx * 8 + j];
    a2r[j] = a[128 + tx * 8 + j];
  }
#pragma unroll
  for (int i = 0; i < 4; i++) {
    float p1 = 0.f, p2 = 0.f;
#pragma unroll
    for (int j = 0; j < 8; j++) {
      p1 = fmaf(acc[i][j], a1r[j], p1);
      p2 = fmaf(acc[i][j], a2r[j], p2);
    }
#pragma unroll
    for (int msk = 1; msk < 16; msk <<= 1) {    // reduce over tx (16-lane groups)
      p1 += __shfl_xor(p1, msk);
      p2 += __shfl_xor(p2, msk);
    }
    int row = bm + ty * 4 + i;
    if (tx == 0 && row < NN) { s_src[row] = p1; s_tgt[row] = p2; }
  }
}

// ---------- K3: scores + global max + target histogram ----------
__global__ __launch_bounds__(256) void k_score(const int* __restrict__ ei,
                                               const float* __restrict__ s_src,
                                               const float* __restrict__ s_tgt,
                                               float* __restrict__ scores,
                                               unsigned* __restrict__ umax,
                                               int* __restrict__ cnt) {
  int e = blockIdx.x * 256 + threadIdx.x;             // grid covers NE exactly
  int s = ei[e];
  int t = ei[NE + e];
  float v = s_src[s] + s_tgt[t];
  float sc = v > 0.f ? v : 0.2f * v;                  // leaky_relu(0.2)
  scores[e] = sc;
  atomicAdd(&cnt[t], 1);                              // histogram of targets
  float m = sc;
#pragma unroll
  for (int off = 32; off; off >>= 1) m = fmaxf(m, __shfl_down(m, off));
  __shared__ float red[4];
  int w = threadIdx.x >> 6, lane = threadIdx.x & 63;
  if (lane == 0) red[w] = m;
  __syncthreads();
  if (threadIdx.x == 0) {
    float bm = fmaxf(fmaxf(red[0], red[1]), fmaxf(red[2], red[3]));
    atomicMax(umax, enc_f(bm));
  }
}

// ---------- K4: sum of exp(score - max) ----------
__global__ __launch_bounds__(256) void k_sum(const float* __restrict__ scores,
                                             const unsigned* __restrict__ umax,
                                             float* __restrict__ sumexp) {
  int e = blockIdx.x * 256 + threadIdx.x;
  float m = dec_f(*umax);
  float v = __expf(scores[e] - m);
#pragma unroll
  for (int off = 32; off; off >>= 1) v += __shfl_down(v, off);
  __shared__ float red[4];
  int w = threadIdx.x >> 6, lane = threadIdx.x & 63;
  if (lane == 0) red[w] = v;
  __syncthreads();
  if (threadIdx.x == 0)
    atomicAdd(sumexp, red[0] + red[1] + red[2] + red[3]);
}

// ---------- K5a: per-block sums of cnt ----------
__global__ __launch_bounds__(256) void k_scan1(const int* __restrict__ cnt,
                                               int* __restrict__ bsum) {
  int i = blockIdx.x * 256 + threadIdx.x;
  int v = (i < NN) ? cnt[i] : 0;
#pragma unroll
  for (int off = 32; off; off >>= 1) v += __shfl_down(v, off);
  __shared__ int red[4];
  int w = threadIdx.x >> 6, lane = threadIdx.x & 63;
  if (lane == 0) red[w] = v;
  __syncthreads();
  if (threadIdx.x == 0)
    bsum[blockIdx.x] = red[0] + red[1] + red[2] + red[3];
}

// ---------- K5b: exclusive scan of 196 block sums (1 small block) ----------
__global__ __launch_bounds__(256) void k_scan2(int* __restrict__ bsum) {
  __shared__ int s[256];
  int tid = threadIdx.x;
  int v = (tid < NBLK) ? bsum[tid] : 0;
  s[tid] = v;
  __syncthreads();
  for (int off = 1; off < 256; off <<= 1) {
    int t = (tid >= off) ? s[tid - off] : 0;
    __syncthreads();
    s[tid] += t;
    __syncthreads();
  }
  int excl = (tid == 0) ? 0 : s[tid - 1];
  if (tid < NBLK) bsum[tid] = excl;
}

// ---------- K5c: block-local exclusive scan + base -> offs, cursor ----------
__global__ __launch_bounds__(256) void k_scan3(const int* __restrict__ cnt,
                                               const int* __restrict__ bsum,
                                               int* __restrict__ offs,
                                               int* __restrict__ cursor) {
  int i = blockIdx.x * 256 + threadIdx.x;
  int lane = threadIdx.x & 63;
  int w = threadIdx.x >> 6;
  int v = (i < NN) ? cnt[i] : 0;
  int inc = v;
#pragma unroll
  for (int off = 1; off < 64; off <<= 1) {
    int t = __shfl_up(inc, off);
    if (lane >= off) inc += t;
  }
  __shared__ int wsum[4];
  if (lane == 63) wsum[w] = inc;
  __syncthreads();
  int woff = 0;
#pragma unroll
  for (int j = 0; j < 4; j++) woff += (j < w) ? wsum[j] : 0;
  int excl = bsum[blockIdx.x] + woff + inc - v;
  if (i < NN) { offs[i] = excl; cursor[i] = excl; }
}

// ---------- K6: bin edges by target: (src, alpha) records ----------
__global__ __launch_bounds__(256) void k_bin(const int* __restrict__ ei,
                                             const float* __restrict__ scores,
                                             const unsigned* __restrict__ umax,
                                             const float* __restrict__ sumexp,
                                             int* __restrict__ cursor,
                                             int2* __restrict__ recs) {
  int e = blockIdx.x * 256 + threadIdx.x;
  int t = ei[NE + e];
  float m = dec_f(*umax);
  float inv = 1.0f / *sumexp;
  int pos = atomicAdd(&cursor[t], 1);
  float al = __expf(scores[e] - m) * inv;
  recs[pos] = make_int2(ei[e], __float_as_int(al));
}

// ---------- K7: gather-sum per target node (one wave per node, bf16 rows) ----------
__global__ __launch_bounds__(256) void k_gather(const int* __restrict__ offs,
                                                const int* __restrict__ cnt,
                                                const int2* __restrict__ recs,
                                                const unsigned* __restrict__ Whu,
                                                float* __restrict__ xnew) {
  int wid = (blockIdx.x * 256 + threadIdx.x) >> 6;    // 12500*4 = NN waves
  int lane = threadIdx.x & 63;
  int start = offs[wid];
  int n = cnt[wid];
  float2 acc = make_float2(0.f, 0.f);
  for (int base = 0; base < n; base += 64) {
    int m = n - base; if (m > 64) m = 64;
    int li = lane < m ? lane : m - 1;
    int2 r = recs[start + base + li];                 // coalesced chunk load
    for (int i = 0; i < m; i += 4) {                  // 4 row-loads in flight
      int sj[4]; float aj[4];
#pragma unroll
      for (int j = 0; j < 4; j++) {
        int idx = i + j;
        sj[j] = __shfl(r.x, idx);
        float al = __int_as_float(__shfl(r.y, idx));
        aj[j] = (idx < m) ? al : 0.f;
      }
      unsigned v[4];
#pragma unroll
      for (int j = 0; j < 4; j++)
        v[j] = Whu[(long)sj[j] * 64 + lane];
#pragma unroll
      for (int j = 0; j < 4; j++) {
        acc.x = fmaf(aj[j], bf2f(v[j] & 0xffffu), acc.x);
        acc.y = fmaf(aj[j], bf2f(v[j] >> 16), acc.y);
      }
    }
  }
  ((float2*)xnew)[(long)wid * 64 + lane] = acc;
}

// ---------- K8: fused MLP head as register-tiled GEMM ----------
__global__ __launch_bounds__(256) void k_mlp(const float* __restrict__ xnew,
                                             const float* __restrict__ W1,
                                             const float* __restrict__ b1,
                                             const float* __restrict__ W2,
                                             const float* __restrict__ b2,
                                             float* __restrict__ evid) {
  __shared__ float xs[64][132];     // row stride 132 (528B, 16B-aligned)
  __shared__ float w1s[128][64];    // [k][hid]
  const int tid = threadIdx.x;
  const int nb = blockIdx.x * 64;
  const int ty = tid >> 4;          // 0..15 -> nodes ty*4..+3
  const int tx = tid & 15;          // 0..15 -> hid tx*4..+3

#pragma unroll
  for (int i = 0; i < 8; i++) {
    int f = tid + i * 256;
    int n = f >> 5;
    int kq = (f & 31) * 4;
    int row = nb + n; if (row >= NN) row = NN - 1;
    *(float4*)&xs[n][kq] = *(const float4*)&xnew[(long)row * OUTD + kq];
  }
#pragma unroll
  for (int i = 0; i < 8; i++) {
    int f = tid + i * 256;
    int kr = f >> 4;
    int cq = (f & 15) * 4;
    *(float4*)&w1s[kr][cq] = *(const float4*)&W1[kr * HIDD + cq];
  }
  __syncthreads();

  float acc[4][4];
#pragma unroll
  for (int i = 0; i < 4; i++)
#pragma unroll
    for (int j = 0; j < 4; j++) acc[i][j] = 0.f;

#pragma unroll 2
  for (int k0 = 0; k0 < OUTD; k0 += 4) {
    float4 xv[4], wv[4];
#pragma unroll
    for (int i = 0; i < 4; i++) xv[i] = *(const float4*)&xs[ty * 4 + i][k0];
#pragma unroll
    for (int d = 0; d < 4; d++) wv[d] = *(const float4*)&w1s[k0 + d][tx * 4];
#pragma unroll
    for (int i = 0; i < 4; i++) {
      float xr[4] = {xv[i].x, xv[i].y, xv[i].z, xv[i].w};
#pragma unroll
      for (int d = 0; d < 4; d++) {
        float wr[4] = {wv[d].x, wv[d].y, wv[d].z, wv[d].w};
#pragma unroll
        for (int j = 0; j < 4; j++)
          acc[i][j] = fmaf(xr[d], wr[j], acc[i][j]);
      }
    }
  }

  float b1r[4], w2r[4][3];
#pragma unroll
  for (int j = 0; j < 4; j++) {
    int jg = tx * 4 + j;
    b1r[j] = b1[jg];
    w2r[j][0] = W2[jg * 3 + 0];
    w2r[j][1] = W2[jg * 3 + 1];
    w2r[j][2] = W2[jg * 3 + 2];
  }
#pragma unroll
  for (int i = 0; i < 4; i++) {
    float p0 = 0.f, p1 = 0.f, p2 = 0.f;
#pragma unroll
    for (int j = 0; j < 4; j++) {
      float h = fmaxf(acc[i][j] + b1r[j], 0.f);
      p0 = fmaf(h, w2r[j][0], p0);
      p1 = fmaf(h, w2r[j][1], p1);
      p2 = fmaf(h, w2r[j][2], p2);
    }
#pragma unroll
    for (int m = 1; m < 16; m <<= 1) {
      p0 += __shfl_xor(p0, m);
      p1 += __shfl_xor(p1, m);
      p2 += __shfl_xor(p2, m);
    }
    if (tx == 0) {
      int n = nb + ty * 4 + i;
      if (n < NN) {
        float e0 = p0 + b2[0], e1 = p1 + b2[1], e2 = p2 + b2[2];
        float s0 = e0 > 20.f ? e0 : log1pf(expf(e0));
        float s1 = e1 > 20.f ? e1 : log1pf(expf(e1));
        float s2 = e2 > 20.f ? e2 : log1pf(expf(e2));
        evid[(long)n * 3 + 0] = s0 + 1.0f;
        evid[(long)n * 3 + 1] = s1 + 1.0f;
        evid[(long)n * 3 + 2] = s2 + 1.0f;
      }
    }
  }
}

extern "C" void kernel_launch(void* const* d_in, const int* in_sizes, int n_in,
                              void* d_out, int out_size, void* d_ws, size_t ws_size,
                              hipStream_t stream) {
  const float* x   = (const float*)d_in[0];
  const int*   ei  = (const int*)d_in[1];
  const float* W   = (const float*)d_in[2];
  const float* a   = (const float*)d_in[3];
  const float* W1  = (const float*)d_in[4];
  const float* b1  = (const float*)d_in[5];
  const float* W2  = (const float*)d_in[6];
  const float* b2  = (const float*)d_in[7];

  float* xnew = (float*)d_out;                       // [NN*OUTD]
  float* evid = (float*)d_out + (size_t)NN * OUTD;   // [NN*3]

  float* wsf = (float*)d_ws;
  unsigned* Whu    = (unsigned*)wsf;                 // 3,200,000 u32 (12.8 MB bf16 Wh)
  float*    s_src  = wsf + 3200000;                  //    50,000 f
  float*    s_tgt  = wsf + 3250000;                  //    50,000 f
  float*    scores = wsf + 3300000;                  //   800,000 f
  int2*     recs   = (int2*)(wsf + 4100000);         //   800,000 int2 (8B-aligned)
  unsigned* umax   = (unsigned*)(wsf + 5700000);
  float*    sumexp = wsf + 5700002;
  int*      cnt    = (int*)(wsf + 5700004);          //    50,000 i
  int*      offs   = (int*)(wsf + 5750004);          //    50,000 i
  int*      cursor = (int*)(wsf + 5800004);          //    50,000 i
  int*      bsum   = (int*)(wsf + 5850004);          //       196 i (end ~23.4 MB)

  k_zero<<<196, 256, 0, stream>>>(cnt, umax, sumexp);
  k_gemm<<<(NN + 63) / 64, 256, 0, stream>>>(x, W, a, Whu, s_src, s_tgt);
  k_score<<<NE / 256, 256, 0, stream>>>(ei, s_src, s_tgt, scores, umax, cnt);
  k_sum<<<NE / 256, 256, 0, stream>>>(scores, umax, sumexp);
  k_scan1<<<NBLK, 256, 0, stream>>>(cnt, bsum);
  k_scan2<<<1, 256, 0, stream>>>(bsum);
  k_scan3<<<NBLK, 256, 0, stream>>>(cnt, bsum, offs, cursor);
  k_bin<<<NE / 256, 256, 0, stream>>>(ei, scores, umax, sumexp, cursor, recs);
  k_gather<<<NN / 4, 256, 0, stream>>>(offs, cnt, recs, Whu, xnew);
  k_mlp<<<(NN + 63) / 64, 256, 0, stream>>>(xnew, W1, b1, W2, b2, evid);
}

// Round 6
// 259.149 us; speedup vs baseline: 3.4456x; 1.1414x over previous
//
#include <hip/hip_runtime.h>
#include <math.h>

#define NN 50000
#define NE 800000
#define IND 256
#define OUTD 128
#define HIDD 64
#define NBLK 196   // ceil(NN/256)

typedef __attribute__((ext_vector_type(8))) short short8;   // 8 bf16 (4 VGPR)
typedef __attribute__((ext_vector_type(4))) float f32x4;    // MFMA acc

// ---------- helpers ----------
static __device__ __forceinline__ unsigned enc_f(float f) {
  unsigned u = __float_as_uint(f);
  return (u & 0x80000000u) ? ~u : (u | 0x80000000u);
}
static __device__ __forceinline__ float dec_f(unsigned u) {
  unsigned b = (u & 0x80000000u) ? (u ^ 0x80000000u) : ~u;
  return __uint_as_float(b);
}
static __device__ __forceinline__ unsigned f2bf(float f) {       // RNE f32->bf16 bits
  unsigned u = __float_as_uint(f);
  return (u + 0x7fffu + ((u >> 16) & 1u)) >> 16;
}
static __device__ __forceinline__ float bf2f(unsigned b) {
  return __uint_as_float(b << 16);
}

// ---------- K0: zero target-histogram + init reduction scalars ----------
__global__ __launch_bounds__(256) void k_zero(int* __restrict__ cnt,
                                              unsigned* __restrict__ umax,
                                              float* __restrict__ sumexp) {
  int i = blockIdx.x * 256 + threadIdx.x;     // 196*256 = 50176 >= NN
  if (i < NN) cnt[i] = 0;
  if (i == 0) { *umax = 0x007FFFFFu /* enc(-inf) */; *sumexp = 0.f; }
}

// ---------- K0b: Wt[n][k] = bf16(W[k][n]) (one-time, 32768 elems) ----------
__global__ __launch_bounds__(256) void k_wconv(const float* __restrict__ W,
                                               unsigned short* __restrict__ Wt) {
  int t = blockIdx.x * 256 + threadIdx.x;     // 128 blocks
  int n = t >> 8, k = t & 255;
  Wt[t] = (unsigned short)f2bf(W[k * OUTD + n]);
}

// ---------- K1: Wh16 = bf16(x @ W) via MFMA 16x16x32 bf16 ----------
// BM=64, BN=128(full), BK=32, 4 waves: wave w owns cols w*32..+31 (2 n-frags),
// all 64 rows (4 m-frags). A staged f32->bf16 in LDS [64][40] (40-short rows:
// 80B stride -> 16B aligned, worst 2-way bank conflict = free). B staged from
// pre-converted Wt [128][40]. Epilogue repacks acc via LDS tile (aliased over
// staging memory) into coalesced uint4 bf16 stores.
__global__ __launch_bounds__(256) void k_gemm(const float* __restrict__ x,
                                              const unsigned short* __restrict__ Wt,
                                              unsigned* __restrict__ Whu) {
  __shared__ float smem[8448];                 // max(A+B = 15360B, Cs = 33792B)
  short* As = (short*)smem;                    // [64][40] bf16
  short* Bs = As + 64 * 40;                    // [128][40] bf16
  float* Cs = smem;                            // [64][132] f32 (epilogue alias)

  const int tid  = threadIdx.x;
  const int bm   = blockIdx.x * 64;
  const int wave = tid >> 6;                   // 0..3 -> col block wave*32
  const int lane = tid & 63;
  const int l15  = lane & 15;
  const int lg   = lane >> 4;                  // 0..3

  f32x4 acc[4][2];
#pragma unroll
  for (int i = 0; i < 4; i++)
#pragma unroll
    for (int j = 0; j < 2; j++) acc[i][j] = (f32x4){0.f, 0.f, 0.f, 0.f};

  // A staging map: thread t -> row=t>>2, octet q=t&3 (8 f32 -> 8 bf16)
  const int arow = tid >> 2, aq = tid & 3;
  long arow_g = bm + arow; if (arow_g >= NN) arow_g = NN - 1;   // clamp, writes guarded
  const float* xp = &x[arow_g * IND + aq * 8];
  short* asp = &As[arow * 40 + aq * 8];
  // B staging map: thread t -> n=t>>1, half h=t&1 (16 bf16 copy)
  const int bn = tid >> 1, bh = tid & 1;
  const unsigned short* wtp = &Wt[bn * 256 + bh * 16];
  short* bsp = &Bs[bn * 40 + bh * 16];

  for (int k0 = 0; k0 < IND; k0 += 32) {
    // stage A: 8 f32 -> short8 -> one ds_write_b128
    float4 v0 = *(const float4*)(xp + k0);
    float4 v1 = *(const float4*)(xp + k0 + 4);
    short8 apk;
    apk[0] = (short)f2bf(v0.x); apk[1] = (short)f2bf(v0.y);
    apk[2] = (short)f2bf(v0.z); apk[3] = (short)f2bf(v0.w);
    apk[4] = (short)f2bf(v1.x); apk[5] = (short)f2bf(v1.y);
    apk[6] = (short)f2bf(v1.z); apk[7] = (short)f2bf(v1.w);
    *(short8*)asp = apk;
    // stage B: 32B bf16 copy
    *(short8*)bsp       = *(const short8*)(wtp + k0);
    *(short8*)(bsp + 8) = *(const short8*)(wtp + k0 + 8);
    __syncthreads();

    short8 af[4], bf[2];
#pragma unroll
    for (int mi = 0; mi < 4; mi++)
      af[mi] = *(const short8*)&As[(mi * 16 + l15) * 40 + lg * 8];
#pragma unroll
    for (int ni = 0; ni < 2; ni++)
      bf[ni] = *(const short8*)&Bs[(wave * 32 + ni * 16 + l15) * 40 + lg * 8];
#pragma unroll
    for (int mi = 0; mi < 4; mi++)
#pragma unroll
      for (int ni = 0; ni < 2; ni++)
        acc[mi][ni] = __builtin_amdgcn_mfma_f32_16x16x32_bf16(
            af[mi], bf[ni], acc[mi][ni], 0, 0, 0);
    __syncthreads();
  }

  // epilogue: acc -> Cs (f32) -> coalesced bf16 global
#pragma unroll
  for (int mi = 0; mi < 4; mi++)
#pragma unroll
    for (int ni = 0; ni < 2; ni++)
#pragma unroll
      for (int r = 0; r < 4; r++) {
        int row = mi * 16 + lg * 4 + r;
        int col = wave * 32 + ni * 16 + l15;
        Cs[row * 132 + col] = acc[mi][ni][r];
      }
  __syncthreads();
#pragma unroll
  for (int i = 0; i < 4; i++) {
    int f = tid + i * 256;                    // 1024 chunks of 8 f32
    int nd = f >> 4, seg = f & 15;
    long gnode = bm + nd;
    if (gnode < NN) {
      float4 c0 = *(const float4*)&Cs[nd * 132 + seg * 8];
      float4 c1 = *(const float4*)&Cs[nd * 132 + seg * 8 + 4];
      uint4 o;
      o.x = f2bf(c0.x) | (f2bf(c0.y) << 16);
      o.y = f2bf(c0.z) | (f2bf(c0.w) << 16);
      o.z = f2bf(c1.x) | (f2bf(c1.y) << 16);
      o.w = f2bf(c1.z) | (f2bf(c1.w) << 16);
      *(uint4*)&Whu[gnode * 64 + seg * 4] = o;
    }
  }
}

// ---------- K2: s_src/s_tgt from bf16 Wh (one wave per node) ----------
__global__ __launch_bounds__(256) void k_s(const unsigned* __restrict__ Whu,
                                           const float* __restrict__ a,
                                           float* __restrict__ s_src,
                                           float* __restrict__ s_tgt) {
  int wid = (blockIdx.x * 256 + threadIdx.x) >> 6;
  int lane = threadIdx.x & 63;
  if (wid >= NN) return;
  unsigned v = Whu[(long)wid * 64 + lane];
  float w0 = bf2f(v & 0xffffu), w1 = bf2f(v >> 16);
  float p1 = w0 * a[2 * lane]       + w1 * a[2 * lane + 1];
  float p2 = w0 * a[128 + 2 * lane] + w1 * a[128 + 2 * lane + 1];
#pragma unroll
  for (int off = 32; off; off >>= 1) {
    p1 += __shfl_down(p1, off);
    p2 += __shfl_down(p2, off);
  }
  if (lane == 0) { s_src[wid] = p1; s_tgt[wid] = p2; }
}

// ---------- K3: scores + global max + target histogram ----------
__global__ __launch_bounds__(256) void k_score(const int* __restrict__ ei,
                                               const float* __restrict__ s_src,
                                               const float* __restrict__ s_tgt,
                                               float* __restrict__ scores,
                                               unsigned* __restrict__ umax,
                                               int* __restrict__ cnt) {
  int e = blockIdx.x * 256 + threadIdx.x;             // grid covers NE exactly
  int s = ei[e];
  int t = ei[NE + e];
  float v = s_src[s] + s_tgt[t];
  float sc = v > 0.f ? v : 0.2f * v;                  // leaky_relu(0.2)
  scores[e] = sc;
  atomicAdd(&cnt[t], 1);                              // histogram of targets
  float m = sc;
#pragma unroll
  for (int off = 32; off; off >>= 1) m = fmaxf(m, __shfl_down(m, off));
  __shared__ float red[4];
  int w = threadIdx.x >> 6, lane = threadIdx.x & 63;
  if (lane == 0) red[w] = m;
  __syncthreads();
  if (threadIdx.x == 0) {
    float bm = fmaxf(fmaxf(red[0], red[1]), fmaxf(red[2], red[3]));
    atomicMax(umax, enc_f(bm));
  }
}

// ---------- K4: sum of exp(score - max) ----------
__global__ __launch_bounds__(256) void k_sum(const float* __restrict__ scores,
                                             const unsigned* __restrict__ umax,
                                             float* __restrict__ sumexp) {
  int e = blockIdx.x * 256 + threadIdx.x;
  float m = dec_f(*umax);
  float v = __expf(scores[e] - m);
#pragma unroll
  for (int off = 32; off; off >>= 1) v += __shfl_down(v, off);
  __shared__ float red[4];
  int w = threadIdx.x >> 6, lane = threadIdx.x & 63;
  if (lane == 0) red[w] = v;
  __syncthreads();
  if (threadIdx.x == 0)
    atomicAdd(sumexp, red[0] + red[1] + red[2] + red[3]);
}

// ---------- K5a: per-block sums of cnt ----------
__global__ __launch_bounds__(256) void k_scan1(const int* __restrict__ cnt,
                                               int* __restrict__ bsum) {
  int i = blockIdx.x * 256 + threadIdx.x;
  int v = (i < NN) ? cnt[i] : 0;
#pragma unroll
  for (int off = 32; off; off >>= 1) v += __shfl_down(v, off);
  __shared__ int red[4];
  int w = threadIdx.x >> 6, lane = threadIdx.x & 63;
  if (lane == 0) red[w] = v;
  __syncthreads();
  if (threadIdx.x == 0)
    bsum[blockIdx.x] = red[0] + red[1] + red[2] + red[3];
}

// ---------- K5b: exclusive scan of 196 block sums (1 small block) ----------
__global__ __launch_bounds__(256) void k_scan2(int* __restrict__ bsum) {
  __shared__ int s[256];
  int tid = threadIdx.x;
  int v = (tid < NBLK) ? bsum[tid] : 0;
  s[tid] = v;
  __syncthreads();
  for (int off = 1; off < 256; off <<= 1) {
    int t = (tid >= off) ? s[tid - off] : 0;
    __syncthreads();
    s[tid] += t;
    __syncthreads();
  }
  int excl = (tid == 0) ? 0 : s[tid - 1];
  if (tid < NBLK) bsum[tid] = excl;
}

// ---------- K5c: block-local exclusive scan + base -> offs, cursor ----------
__global__ __launch_bounds__(256) void k_scan3(const int* __restrict__ cnt,
                                               const int* __restrict__ bsum,
                                               int* __restrict__ offs,
                                               int* __restrict__ cursor) {
  int i = blockIdx.x * 256 + threadIdx.x;
  int lane = threadIdx.x & 63;
  int w = threadIdx.x >> 6;
  int v = (i < NN) ? cnt[i] : 0;
  int inc = v;
#pragma unroll
  for (int off = 1; off < 64; off <<= 1) {
    int t = __shfl_up(inc, off);
    if (lane >= off) inc += t;
  }
  __shared__ int wsum[4];
  if (lane == 63) wsum[w] = inc;
  __syncthreads();
  int woff = 0;
#pragma unroll
  for (int j = 0; j < 4; j++) woff += (j < w) ? wsum[j] : 0;
  int excl = bsum[blockIdx.x] + woff + inc - v;
  if (i < NN) { offs[i] = excl; cursor[i] = excl; }
}

// ---------- K6: bin edges by target: (src, alpha) records ----------
__global__ __launch_bounds__(256) void k_bin(const int* __restrict__ ei,
                                             const float* __restrict__ scores,
                                             const unsigned* __restrict__ umax,
                                             const float* __restrict__ sumexp,
                                             int* __restrict__ cursor,
                                             int2* __restrict__ recs) {
  int e = blockIdx.x * 256 + threadIdx.x;
  int t = ei[NE + e];
  float m = dec_f(*umax);
  float inv = 1.0f / *sumexp;
  int pos = atomicAdd(&cursor[t], 1);
  float al = __expf(scores[e] - m) * inv;
  recs[pos] = make_int2(ei[e], __float_as_int(al));
}

// ---------- K7: gather-sum per target node (one wave per node, bf16 rows) ----------
__global__ __launch_bounds__(256) void k_gather(const int* __restrict__ offs,
                                                const int* __restrict__ cnt,
                                                const int2* __restrict__ recs,
                                                const unsigned* __restrict__ Whu,
                                                float* __restrict__ xnew) {
  int wid = (blockIdx.x * 256 + threadIdx.x) >> 6;    // 12500*4 = NN waves
  int lane = threadIdx.x & 63;
  int start = offs[wid];
  int n = cnt[wid];
  float2 acc = make_float2(0.f, 0.f);
  for (int base = 0; base < n; base += 64) {
    int m = n - base; if (m > 64) m = 64;
    int li = lane < m ? lane : m - 1;
    int2 r = recs[start + base + li];                 // coalesced chunk load
    for (int i = 0; i < m; i += 4) {                  // 4 row-loads in flight
      int sj[4]; float aj[4];
#pragma unroll
      for (int j = 0; j < 4; j++) {
        int idx = i + j;
        sj[j] = __shfl(r.x, idx);
        float al = __int_as_float(__shfl(r.y, idx));
        aj[j] = (idx < m) ? al : 0.f;
      }
      unsigned v[4];
#pragma unroll
      for (int j = 0; j < 4; j++)
        v[j] = Whu[(long)sj[j] * 64 + lane];
#pragma unroll
      for (int j = 0; j < 4; j++) {
        acc.x = fmaf(aj[j], bf2f(v[j] & 0xffffu), acc.x);
        acc.y = fmaf(aj[j], bf2f(v[j] >> 16), acc.y);
      }
    }
  }
  ((float2*)xnew)[(long)wid * 64 + lane] = acc;
}

// ---------- K8: fused MLP head as register-tiled GEMM ----------
__global__ __launch_bounds__(256) void k_mlp(const float* __restrict__ xnew,
                                             const float* __restrict__ W1,
                                             const float* __restrict__ b1,
                                             const float* __restrict__ W2,
                                             const float* __restrict__ b2,
                                             float* __restrict__ evid) {
  __shared__ float xs[64][132];     // row stride 132 (528B, 16B-aligned)
  __shared__ float w1s[128][64];    // [k][hid]
  const int tid = threadIdx.x;
  const int nb = blockIdx.x * 64;
  const int ty = tid >> 4;          // 0..15 -> nodes ty*4..+3
  const int tx = tid & 15;          // 0..15 -> hid tx*4..+3

#pragma unroll
  for (int i = 0; i < 8; i++) {
    int f = tid + i * 256;
    int n = f >> 5;
    int kq = (f & 31) * 4;
    int row = nb + n; if (row >= NN) row = NN - 1;
    *(float4*)&xs[n][kq] = *(const float4*)&xnew[(long)row * OUTD + kq];
  }
#pragma unroll
  for (int i = 0; i < 8; i++) {
    int f = tid + i * 256;
    int kr = f >> 4;
    int cq = (f & 15) * 4;
    *(float4*)&w1s[kr][cq] = *(const float4*)&W1[kr * HIDD + cq];
  }
  __syncthreads();

  float acc[4][4];
#pragma unroll
  for (int i = 0; i < 4; i++)
#pragma unroll
    for (int j = 0; j < 4; j++) acc[i][j] = 0.f;

#pragma unroll 2
  for (int k0 = 0; k0 < OUTD; k0 += 4) {
    float4 xv[4], wv[4];
#pragma unroll
    for (int i = 0; i < 4; i++) xv[i] = *(const float4*)&xs[ty * 4 + i][k0];
#pragma unroll
    for (int d = 0; d < 4; d++) wv[d] = *(const float4*)&w1s[k0 + d][tx * 4];
#pragma unroll
    for (int i = 0; i < 4; i++) {
      float xr[4] = {xv[i].x, xv[i].y, xv[i].z, xv[i].w};
#pragma unroll
      for (int d = 0; d < 4; d++) {
        float wr[4] = {wv[d].x, wv[d].y, wv[d].z, wv[d].w};
#pragma unroll
        for (int j = 0; j < 4; j++)
          acc[i][j] = fmaf(xr[d], wr[j], acc[i][j]);
      }
    }
  }

  float b1r[4], w2r[4][3];
#pragma unroll
  for (int j = 0; j < 4; j++) {
    int jg = tx * 4 + j;
    b1r[j] = b1[jg];
    w2r[j][0] = W2[jg * 3 + 0];
    w2r[j][1] = W2[jg * 3 + 1];
    w2r[j][2] = W2[jg * 3 + 2];
  }
#pragma unroll
  for (int i = 0; i < 4; i++) {
    float p0 = 0.f, p1 = 0.f, p2 = 0.f;
#pragma unroll
    for (int j = 0; j < 4; j++) {
      float h = fmaxf(acc[i][j] + b1r[j], 0.f);
      p0 = fmaf(h, w2r[j][0], p0);
      p1 = fmaf(h, w2r[j][1], p1);
      p2 = fmaf(h, w2r[j][2], p2);
    }
#pragma unroll
    for (int m = 1; m < 16; m <<= 1) {
      p0 += __shfl_xor(p0, m);
      p1 += __shfl_xor(p1, m);
      p2 += __shfl_xor(p2, m);
    }
    if (tx == 0) {
      int n = nb + ty * 4 + i;
      if (n < NN) {
        float e0 = p0 + b2[0], e1 = p1 + b2[1], e2 = p2 + b2[2];
        float s0 = e0 > 20.f ? e0 : log1pf(expf(e0));
        float s1 = e1 > 20.f ? e1 : log1pf(expf(e1));
        float s2 = e2 > 20.f ? e2 : log1pf(expf(e2));
        evid[(long)n * 3 + 0] = s0 + 1.0f;
        evid[(long)n * 3 + 1] = s1 + 1.0f;
        evid[(long)n * 3 + 2] = s2 + 1.0f;
      }
    }
  }
}

extern "C" void kernel_launch(void* const* d_in, const int* in_sizes, int n_in,
                              void* d_out, int out_size, void* d_ws, size_t ws_size,
                              hipStream_t stream) {
  const float* x   = (const float*)d_in[0];
  const int*   ei  = (const int*)d_in[1];
  const float* W   = (const float*)d_in[2];
  const float* a   = (const float*)d_in[3];
  const float* W1  = (const float*)d_in[4];
  const float* b1  = (const float*)d_in[5];
  const float* W2  = (const float*)d_in[6];
  const float* b2  = (const float*)d_in[7];

  float* xnew = (float*)d_out;                       // [NN*OUTD]
  float* evid = (float*)d_out + (size_t)NN * OUTD;   // [NN*3]

  float* wsf = (float*)d_ws;
  unsigned* Whu    = (unsigned*)wsf;                 // 3,200,000 u32 (12.8 MB bf16 Wh)
  float*    s_src  = wsf + 3200000;                  //    50,000 f
  float*    s_tgt  = wsf + 3250000;                  //    50,000 f
  float*    scores = wsf + 3300000;                  //   800,000 f
  int2*     recs   = (int2*)(wsf + 4100000);         //   800,000 int2 (8B-aligned)
  unsigned* umax   = (unsigned*)(wsf + 5700000);
  float*    sumexp = wsf + 5700002;
  int*      cnt    = (int*)(wsf + 5700004);          //    50,000 i
  int*      offs   = (int*)(wsf + 5750004);          //    50,000 i
  int*      cursor = (int*)(wsf + 5800004);          //    50,000 i
  int*      bsum   = (int*)(wsf + 5850004);          //       196 i
  unsigned short* Wt = (unsigned short*)(wsf + 5851000);  // 32,768 bf16 (end ~23.5 MB)

  k_zero<<<196, 256, 0, stream>>>(cnt, umax, sumexp);
  k_wconv<<<128, 256, 0, stream>>>(W, Wt);
  k_gemm<<<(NN + 63) / 64, 256, 0, stream>>>(x, Wt, Whu);
  k_s<<<12500, 256, 0, stream>>>(Whu, a, s_src, s_tgt);
  k_score<<<NE / 256, 256, 0, stream>>>(ei, s_src, s_tgt, scores, umax, cnt);
  k_sum<<<NE / 256, 256, 0, stream>>>(scores, umax, sumexp);
  k_scan1<<<NBLK, 256, 0, stream>>>(cnt, bsum);
  k_scan2<<<1, 256, 0, stream>>>(bsum);
  k_scan3<<<NBLK, 256, 0, stream>>>(cnt, bsum, offs, cursor);
  k_bin<<<NE / 256, 256, 0, stream>>>(ei, scores, umax, sumexp, cursor, recs);
  k_gather<<<NN / 4, 256, 0, stream>>>(offs, cnt, recs, Whu, xnew);
  k_mlp<<<(NN + 63) / 64, 256, 0, stream>>>(xnew, W1, b1, W2, b2, evid);
}

// Round 7
// 227.100 us; speedup vs baseline: 3.9318x; 1.1411x over previous
//
#include <hip/hip_runtime.h>
#include <math.h>

#define NN 50000
#define NE 800000
#define IND 256
#define OUTD 128
#define HIDD 64
#define NBLK 196   // ceil(NN/256) = number of 256-target coarse buckets
#define BCAP 6144  // bucket capacity for LDS sort (mean 4096, sigma ~64)

typedef __attribute__((ext_vector_type(8))) short short8;   // 8 bf16 (4 VGPR)
typedef __attribute__((ext_vector_type(4))) float f32x4;    // MFMA acc

// ---------- helpers ----------
static __device__ __forceinline__ unsigned enc_f(float f) {
  unsigned u = __float_as_uint(f);
  return (u & 0x80000000u) ? ~u : (u | 0x80000000u);
}
static __device__ __forceinline__ float dec_f(unsigned u) {
  unsigned b = (u & 0x80000000u) ? (u ^ 0x80000000u) : ~u;
  return __uint_as_float(b);
}
static __device__ __forceinline__ unsigned f2bf(float f) {       // RNE f32->bf16 bits
  unsigned u = __float_as_uint(f);
  return (u + 0x7fffu + ((u >> 16) & 1u)) >> 16;
}
static __device__ __forceinline__ float bf2f(unsigned b) {
  return __uint_as_float(b << 16);
}

// ---------- K0: zero target-histogram + init reduction scalars ----------
__global__ __launch_bounds__(256) void k_zero(int* __restrict__ cnt,
                                              unsigned* __restrict__ umax,
                                              float* __restrict__ sumexp) {
  int i = blockIdx.x * 256 + threadIdx.x;     // 196*256 = 50176 >= NN
  if (i < NN) cnt[i] = 0;
  if (i == 0) { *umax = 0x007FFFFFu /* enc(-inf) */; *sumexp = 0.f; }
}

// ---------- K0b: Wt[n][k] = bf16(W[k][n]) (one-time, 32768 elems) ----------
__global__ __launch_bounds__(256) void k_wconv(const float* __restrict__ W,
                                               unsigned short* __restrict__ Wt) {
  int t = blockIdx.x * 256 + threadIdx.x;     // 128 blocks
  int n = t >> 8, k = t & 255;
  Wt[t] = (unsigned short)f2bf(W[k * OUTD + n]);
}

// ---------- K1: Wh16 = bf16(x @ W) via MFMA 16x16x32 bf16 ----------
__global__ __launch_bounds__(256) void k_gemm(const float* __restrict__ x,
                                              const unsigned short* __restrict__ Wt,
                                              unsigned* __restrict__ Whu) {
  __shared__ float smem[8448];                 // max(A+B = 15360B, Cs = 33792B)
  short* As = (short*)smem;                    // [64][40] bf16
  short* Bs = As + 64 * 40;                    // [128][40] bf16
  float* Cs = smem;                            // [64][132] f32 (epilogue alias)

  const int tid  = threadIdx.x;
  const int bm   = blockIdx.x * 64;
  const int wave = tid >> 6;                   // 0..3 -> col block wave*32
  const int lane = tid & 63;
  const int l15  = lane & 15;
  const int lg   = lane >> 4;                  // 0..3

  f32x4 acc[4][2];
#pragma unroll
  for (int i = 0; i < 4; i++)
#pragma unroll
    for (int j = 0; j < 2; j++) acc[i][j] = (f32x4){0.f, 0.f, 0.f, 0.f};

  const int arow = tid >> 2, aq = tid & 3;
  long arow_g = bm + arow; if (arow_g >= NN) arow_g = NN - 1;   // clamp, writes guarded
  const float* xp = &x[arow_g * IND + aq * 8];
  short* asp = &As[arow * 40 + aq * 8];
  const int bn = tid >> 1, bh = tid & 1;
  const unsigned short* wtp = &Wt[bn * 256 + bh * 16];
  short* bsp = &Bs[bn * 40 + bh * 16];

  for (int k0 = 0; k0 < IND; k0 += 32) {
    float4 v0 = *(const float4*)(xp + k0);
    float4 v1 = *(const float4*)(xp + k0 + 4);
    short8 apk;
    apk[0] = (short)f2bf(v0.x); apk[1] = (short)f2bf(v0.y);
    apk[2] = (short)f2bf(v0.z); apk[3] = (short)f2bf(v0.w);
    apk[4] = (short)f2bf(v1.x); apk[5] = (short)f2bf(v1.y);
    apk[6] = (short)f2bf(v1.z); apk[7] = (short)f2bf(v1.w);
    *(short8*)asp = apk;
    *(short8*)bsp       = *(const short8*)(wtp + k0);
    *(short8*)(bsp + 8) = *(const short8*)(wtp + k0 + 8);
    __syncthreads();

    short8 af[4], bf[2];
#pragma unroll
    for (int mi = 0; mi < 4; mi++)
      af[mi] = *(const short8*)&As[(mi * 16 + l15) * 40 + lg * 8];
#pragma unroll
    for (int ni = 0; ni < 2; ni++)
      bf[ni] = *(const short8*)&Bs[(wave * 32 + ni * 16 + l15) * 40 + lg * 8];
#pragma unroll
    for (int mi = 0; mi < 4; mi++)
#pragma unroll
      for (int ni = 0; ni < 2; ni++)
        acc[mi][ni] = __builtin_amdgcn_mfma_f32_16x16x32_bf16(
            af[mi], bf[ni], acc[mi][ni], 0, 0, 0);
    __syncthreads();
  }

  // epilogue: acc -> Cs (f32) -> coalesced bf16 global
#pragma unroll
  for (int mi = 0; mi < 4; mi++)
#pragma unroll
    for (int ni = 0; ni < 2; ni++)
#pragma unroll
      for (int r = 0; r < 4; r++) {
        int row = mi * 16 + lg * 4 + r;
        int col = wave * 32 + ni * 16 + l15;
        Cs[row * 132 + col] = acc[mi][ni][r];
      }
  __syncthreads();
#pragma unroll
  for (int i = 0; i < 4; i++) {
    int f = tid + i * 256;                    // 1024 chunks of 8 f32
    int nd = f >> 4, seg = f & 15;
    long gnode = bm + nd;
    if (gnode < NN) {
      float4 c0 = *(const float4*)&Cs[nd * 132 + seg * 8];
      float4 c1 = *(const float4*)&Cs[nd * 132 + seg * 8 + 4];
      uint4 o;
      o.x = f2bf(c0.x) | (f2bf(c0.y) << 16);
      o.y = f2bf(c0.z) | (f2bf(c0.w) << 16);
      o.z = f2bf(c1.x) | (f2bf(c1.y) << 16);
      o.w = f2bf(c1.z) | (f2bf(c1.w) << 16);
      *(uint4*)&Whu[gnode * 64 + seg * 4] = o;
    }
  }
}

// ---------- K2: s_src/s_tgt from bf16 Wh (one wave per node) ----------
__global__ __launch_bounds__(256) void k_s(const unsigned* __restrict__ Whu,
                                           const float* __restrict__ a,
                                           float* __restrict__ s_src,
                                           float* __restrict__ s_tgt) {
  int wid = (blockIdx.x * 256 + threadIdx.x) >> 6;
  int lane = threadIdx.x & 63;
  if (wid >= NN) return;
  unsigned v = Whu[(long)wid * 64 + lane];
  float w0 = bf2f(v & 0xffffu), w1 = bf2f(v >> 16);
  float p1 = w0 * a[2 * lane]       + w1 * a[2 * lane + 1];
  float p2 = w0 * a[128 + 2 * lane] + w1 * a[128 + 2 * lane + 1];
#pragma unroll
  for (int off = 32; off; off >>= 1) {
    p1 += __shfl_down(p1, off);
    p2 += __shfl_down(p2, off);
  }
  if (lane == 0) { s_src[wid] = p1; s_tgt[wid] = p2; }
}

// ---------- K3: scores + global max + target histogram ----------
__global__ __launch_bounds__(256) void k_score(const int* __restrict__ ei,
                                               const float* __restrict__ s_src,
                                               const float* __restrict__ s_tgt,
                                               float* __restrict__ scores,
                                               unsigned* __restrict__ umax,
                                               int* __restrict__ cnt) {
  int e = blockIdx.x * 256 + threadIdx.x;             // grid covers NE exactly
  int s = ei[e];
  int t = ei[NE + e];
  float v = s_src[s] + s_tgt[t];
  float sc = v > 0.f ? v : 0.2f * v;                  // leaky_relu(0.2)
  scores[e] = sc;
  atomicAdd(&cnt[t], 1);                              // histogram of targets
  float m = sc;
#pragma unroll
  for (int off = 32; off; off >>= 1) m = fmaxf(m, __shfl_down(m, off));
  __shared__ float red[4];
  int w = threadIdx.x >> 6, lane = threadIdx.x & 63;
  if (lane == 0) red[w] = m;
  __syncthreads();
  if (threadIdx.x == 0) {
    float bm = fmaxf(fmaxf(red[0], red[1]), fmaxf(red[2], red[3]));
    atomicMax(umax, enc_f(bm));
  }
}

// ---------- K4: sum of exp(score - max) ----------
__global__ __launch_bounds__(256) void k_sum(const float* __restrict__ scores,
                                             const unsigned* __restrict__ umax,
                                             float* __restrict__ sumexp) {
  int e = blockIdx.x * 256 + threadIdx.x;
  float m = dec_f(*umax);
  float v = __expf(scores[e] - m);
#pragma unroll
  for (int off = 32; off; off >>= 1) v += __shfl_down(v, off);
  __shared__ float red[4];
  int w = threadIdx.x >> 6, lane = threadIdx.x & 63;
  if (lane == 0) red[w] = v;
  __syncthreads();
  if (threadIdx.x == 0)
    atomicAdd(sumexp, red[0] + red[1] + red[2] + red[3]);
}

// ---------- K5a: per-block sums of cnt (= coarse bucket sizes) ----------
__global__ __launch_bounds__(256) void k_scan1(const int* __restrict__ cnt,
                                               int* __restrict__ bsum) {
  int i = blockIdx.x * 256 + threadIdx.x;
  int v = (i < NN) ? cnt[i] : 0;
#pragma unroll
  for (int off = 32; off; off >>= 1) v += __shfl_down(v, off);
  __shared__ int red[4];
  int w = threadIdx.x >> 6, lane = threadIdx.x & 63;
  if (lane == 0) red[w] = v;
  __syncthreads();
  if (threadIdx.x == 0)
    bsum[blockIdx.x] = red[0] + red[1] + red[2] + red[3];
}

// ---------- K5b: exclusive scan of bucket sums; emit offsets + cursor + sentinel ----------
__global__ __launch_bounds__(256) void k_scan2(int* __restrict__ bsum,
                                               int* __restrict__ bcursor) {
  __shared__ int s[256];
  int tid = threadIdx.x;
  int v = (tid < NBLK) ? bsum[tid] : 0;
  s[tid] = v;
  __syncthreads();
  for (int off = 1; off < 256; off <<= 1) {
    int t = (tid >= off) ? s[tid - off] : 0;
    __syncthreads();
    s[tid] += t;
    __syncthreads();
  }
  int excl = (tid == 0) ? 0 : s[tid - 1];
  if (tid <= NBLK) bsum[tid] = excl;          // bsum[NBLK] = NE sentinel
  if (tid < NBLK) bcursor[tid] = excl;
}

// ---------- K5c: per-target exclusive offsets ----------
__global__ __launch_bounds__(256) void k_scan3(const int* __restrict__ cnt,
                                               const int* __restrict__ bsum,
                                               int* __restrict__ offs) {
  int i = blockIdx.x * 256 + threadIdx.x;
  int lane = threadIdx.x & 63;
  int w = threadIdx.x >> 6;
  int v = (i < NN) ? cnt[i] : 0;
  int inc = v;
#pragma unroll
  for (int off = 1; off < 64; off <<= 1) {
    int t = __shfl_up(inc, off);
    if (lane >= off) inc += t;
  }
  __shared__ int wsum[4];
  if (lane == 63) wsum[w] = inc;
  __syncthreads();
  int woff = 0;
#pragma unroll
  for (int j = 0; j < 4; j++) woff += (j < w) ? wsum[j] : 0;
  int excl = bsum[blockIdx.x] + woff + inc - v;
  if (i < NN) offs[i] = excl;
}

// ---------- K6a: coarse bucket scatter (block-owned chunks, XCD-local lines) ----------
// 196 blocks x 4096 edges. LDS histogram of 196 buckets -> one global atomic
// per (block,bucket) chunk reservation -> records written into block-owned
// contiguous chunks. Record: {src | tlocal<<16, alpha_bits}.
__global__ __launch_bounds__(256) void k_binA(const int* __restrict__ ei,
                                              const float* __restrict__ scores,
                                              const unsigned* __restrict__ umax,
                                              const float* __restrict__ sumexp,
                                              int* __restrict__ bcursor,
                                              int2* __restrict__ recs_mid) {
  __shared__ int bh[NBLK];
  __shared__ int gbase[NBLK];
  const int tid = threadIdx.x;
  const long eb = (long)blockIdx.x * 4096;
  if (tid < NBLK) bh[tid] = 0;
  __syncthreads();

  float m = dec_f(*umax);
  float inv = 1.0f / *sumexp;

  int tv[16]; int sv[16]; float av[16];
#pragma unroll
  for (int i = 0; i < 16; i++) {
    long e = eb + i * 256 + tid;
    if (e < NE) {
      sv[i] = ei[e];
      tv[i] = ei[NE + e];
      av[i] = __expf(scores[e] - m) * inv;
      atomicAdd(&bh[tv[i] >> 8], 1);
    } else {
      tv[i] = -1;
    }
  }
  __syncthreads();
  if (tid < NBLK) {
    int c = bh[tid];
    gbase[tid] = (c > 0) ? atomicAdd(&bcursor[tid], c) : 0;
    bh[tid] = 0;                               // reuse as local cursor
  }
  __syncthreads();
#pragma unroll
  for (int i = 0; i < 16; i++) {
    if (tv[i] >= 0) {
      int b = tv[i] >> 8;
      int off = atomicAdd(&bh[b], 1);
      int pos = gbase[b] + off;
      recs_mid[pos] = make_int2(sv[i] | ((tv[i] & 255) << 16),
                                __float_as_int(av[i]));
    }
  }
}

// ---------- K6b: in-bucket LDS sort by target + coalesced final write ----------
// One block per bucket. Local scan of 256 target counts == offs[t]-bsum[b],
// so writing srt[] sequentially lands exactly in [offs] order.
__global__ __launch_bounds__(256) void k_sortB(const int* __restrict__ bsum,
                                               const int2* __restrict__ recs_mid,
                                               int2* __restrict__ recs) {
  __shared__ int h[256], sc[256], cur[256];
  __shared__ int2 srt[BCAP];
  const int tid = threadIdx.x;
  const int b = blockIdx.x;
  const int start = bsum[b];
  const int m = bsum[b + 1] - start;

  h[tid] = 0;
  __syncthreads();
  for (int i = tid; i < m; i += 256) {
    int2 r = recs_mid[start + i];
    atomicAdd(&h[(r.x >> 16) & 255], 1);
  }
  __syncthreads();
  sc[tid] = h[tid];
  __syncthreads();
  for (int off = 1; off < 256; off <<= 1) {
    int t = (tid >= off) ? sc[tid - off] : 0;
    __syncthreads();
    sc[tid] += t;
    __syncthreads();
  }
  cur[tid] = sc[tid] - h[tid];                 // exclusive
  __syncthreads();
  for (int i = tid; i < m; i += 256) {
    int2 r = recs_mid[start + i];
    int tl = (r.x >> 16) & 255;
    int p = atomicAdd(&cur[tl], 1);
    if (p < BCAP) srt[p] = make_int2(r.x & 0xffff, r.y);
  }
  __syncthreads();
  for (int i = tid; i < m; i += 256)
    recs[start + i] = srt[i];                  // fully coalesced
}

// ---------- K7: gather-sum per target node (one wave per node, bf16 rows) ----------
__global__ __launch_bounds__(256) void k_gather(const int* __restrict__ offs,
                                                const int* __restrict__ cnt,
                                                const int2* __restrict__ recs,
                                                const unsigned* __restrict__ Whu,
                                                float* __restrict__ xnew) {
  int wid = (blockIdx.x * 256 + threadIdx.x) >> 6;    // 12500*4 = NN waves
  int lane = threadIdx.x & 63;
  int start = offs[wid];
  int n = cnt[wid];
  float2 acc = make_float2(0.f, 0.f);
  for (int base = 0; base < n; base += 64) {
    int m = n - base; if (m > 64) m = 64;
    int li = lane < m ? lane : m - 1;
    int2 r = recs[start + base + li];                 // coalesced chunk load
    for (int i = 0; i < m; i += 4) {                  // 4 row-loads in flight
      int sj[4]; float aj[4];
#pragma unroll
      for (int j = 0; j < 4; j++) {
        int idx = i + j;
        sj[j] = __shfl(r.x, idx);
        float al = __int_as_float(__shfl(r.y, idx));
        aj[j] = (idx < m) ? al : 0.f;
      }
      unsigned v[4];
#pragma unroll
      for (int j = 0; j < 4; j++)
        v[j] = Whu[(long)sj[j] * 64 + lane];
#pragma unroll
      for (int j = 0; j < 4; j++) {
        acc.x = fmaf(aj[j], bf2f(v[j] & 0xffffu), acc.x);
        acc.y = fmaf(aj[j], bf2f(v[j] >> 16), acc.y);
      }
    }
  }
  ((float2*)xnew)[(long)wid * 64 + lane] = acc;
}

// ---------- K8: fused MLP head as register-tiled GEMM ----------
__global__ __launch_bounds__(256) void k_mlp(const float* __restrict__ xnew,
                                             const float* __restrict__ W1,
                                             const float* __restrict__ b1,
                                             const float* __restrict__ W2,
                                             const float* __restrict__ b2,
                                             float* __restrict__ evid) {
  __shared__ float xs[64][132];     // row stride 132 (528B, 16B-aligned)
  __shared__ float w1s[128][64];    // [k][hid]
  const int tid = threadIdx.x;
  const int nb = blockIdx.x * 64;
  const int ty = tid >> 4;          // 0..15 -> nodes ty*4..+3
  const int tx = tid & 15;          // 0..15 -> hid tx*4..+3

#pragma unroll
  for (int i = 0; i < 8; i++) {
    int f = tid + i * 256;
    int n = f >> 5;
    int kq = (f & 31) * 4;
    int row = nb + n; if (row >= NN) row = NN - 1;
    *(float4*)&xs[n][kq] = *(const float4*)&xnew[(long)row * OUTD + kq];
  }
#pragma unroll
  for (int i = 0; i < 8; i++) {
    int f = tid + i * 256;
    int kr = f >> 4;
    int cq = (f & 15) * 4;
    *(float4*)&w1s[kr][cq] = *(const float4*)&W1[kr * HIDD + cq];
  }
  __syncthreads();

  float acc[4][4];
#pragma unroll
  for (int i = 0; i < 4; i++)
#pragma unroll
    for (int j = 0; j < 4; j++) acc[i][j] = 0.f;

#pragma unroll 2
  for (int k0 = 0; k0 < OUTD; k0 += 4) {
    float4 xv[4], wv[4];
#pragma unroll
    for (int i = 0; i < 4; i++) xv[i] = *(const float4*)&xs[ty * 4 + i][k0];
#pragma unroll
    for (int d = 0; d < 4; d++) wv[d] = *(const float4*)&w1s[k0 + d][tx * 4];
#pragma unroll
    for (int i = 0; i < 4; i++) {
      float xr[4] = {xv[i].x, xv[i].y, xv[i].z, xv[i].w};
#pragma unroll
      for (int d = 0; d < 4; d++) {
        float wr[4] = {wv[d].x, wv[d].y, wv[d].z, wv[d].w};
#pragma unroll
        for (int j = 0; j < 4; j++)
          acc[i][j] = fmaf(xr[d], wr[j], acc[i][j]);
      }
    }
  }

  float b1r[4], w2r[4][3];
#pragma unroll
  for (int j = 0; j < 4; j++) {
    int jg = tx * 4 + j;
    b1r[j] = b1[jg];
    w2r[j][0] = W2[jg * 3 + 0];
    w2r[j][1] = W2[jg * 3 + 1];
    w2r[j][2] = W2[jg * 3 + 2];
  }
#pragma unroll
  for (int i = 0; i < 4; i++) {
    float p0 = 0.f, p1 = 0.f, p2 = 0.f;
#pragma unroll
    for (int j = 0; j < 4; j++) {
      float h = fmaxf(acc[i][j] + b1r[j], 0.f);
      p0 = fmaf(h, w2r[j][0], p0);
      p1 = fmaf(h, w2r[j][1], p1);
      p2 = fmaf(h, w2r[j][2], p2);
    }
#pragma unroll
    for (int m = 1; m < 16; m <<= 1) {
      p0 += __shfl_xor(p0, m);
      p1 += __shfl_xor(p1, m);
      p2 += __shfl_xor(p2, m);
    }
    if (tx == 0) {
      int n = nb + ty * 4 + i;
      if (n < NN) {
        float e0 = p0 + b2[0], e1 = p1 + b2[1], e2 = p2 + b2[2];
        float s0 = e0 > 20.f ? e0 : log1pf(expf(e0));
        float s1 = e1 > 20.f ? e1 : log1pf(expf(e1));
        float s2 = e2 > 20.f ? e2 : log1pf(expf(e2));
        evid[(long)n * 3 + 0] = s0 + 1.0f;
        evid[(long)n * 3 + 1] = s1 + 1.0f;
        evid[(long)n * 3 + 2] = s2 + 1.0f;
      }
    }
  }
}

extern "C" void kernel_launch(void* const* d_in, const int* in_sizes, int n_in,
                              void* d_out, int out_size, void* d_ws, size_t ws_size,
                              hipStream_t stream) {
  const float* x   = (const float*)d_in[0];
  const int*   ei  = (const int*)d_in[1];
  const float* W   = (const float*)d_in[2];
  const float* a   = (const float*)d_in[3];
  const float* W1  = (const float*)d_in[4];
  const float* b1  = (const float*)d_in[5];
  const float* W2  = (const float*)d_in[6];
  const float* b2  = (const float*)d_in[7];

  float* xnew = (float*)d_out;                       // [NN*OUTD]
  float* evid = (float*)d_out + (size_t)NN * OUTD;   // [NN*3]

  float* wsf = (float*)d_ws;
  unsigned* Whu      = (unsigned*)wsf;               // 3,200,000 u32 (12.8 MB bf16 Wh)
  float*    s_src    = wsf + 3200000;                //    50,000 f
  float*    s_tgt    = wsf + 3250000;                //    50,000 f
  float*    scores   = wsf + 3300000;                //   800,000 f
  int2*     recs_mid = (int2*)(wsf + 4100000);       //   800,000 int2
  int2*     recs     = (int2*)(wsf + 5700000);       //   800,000 int2
  unsigned* umax     = (unsigned*)(wsf + 7300000);
  float*    sumexp   = wsf + 7300002;
  int*      cnt      = (int*)(wsf + 7300004);        //    50,000 i
  int*      offs     = (int*)(wsf + 7350004);        //    50,000 i
  int*      bsum     = (int*)(wsf + 7400004);        //       197 i
  int*      bcursor  = (int*)(wsf + 7400204);        //       196 i
  unsigned short* Wt = (unsigned short*)(wsf + 7400400);  // 32,768 bf16 (end ~29.7 MB)

  k_zero<<<196, 256, 0, stream>>>(cnt, umax, sumexp);
  k_wconv<<<128, 256, 0, stream>>>(W, Wt);
  k_gemm<<<(NN + 63) / 64, 256, 0, stream>>>(x, Wt, Whu);
  k_s<<<12500, 256, 0, stream>>>(Whu, a, s_src, s_tgt);
  k_score<<<NE / 256, 256, 0, stream>>>(ei, s_src, s_tgt, scores, umax, cnt);
  k_sum<<<NE / 256, 256, 0, stream>>>(scores, umax, sumexp);
  k_scan1<<<NBLK, 256, 0, stream>>>(cnt, bsum);
  k_scan2<<<1, 256, 0, stream>>>(bsum, bcursor);
  k_scan3<<<NBLK, 256, 0, stream>>>(cnt, bsum, offs);
  k_binA<<<NBLK, 256, 0, stream>>>(ei, scores, umax, sumexp, bcursor, recs_mid);
  k_sortB<<<NBLK, 256, 0, stream>>>(bsum, recs_mid, recs);
  k_gather<<<NN / 4, 256, 0, stream>>>(offs, cnt, recs, Whu, xnew);
  k_mlp<<<(NN + 63) / 64, 256, 0, stream>>>(xnew, W1, b1, W2, b2, evid);
}

// Round 8
// 187.650 us; speedup vs baseline: 4.7584x; 1.2102x over previous
//
#include <hip/hip_runtime.h>
#include <math.h>

#define NN 50000
#define NE 800000
#define IND 256
#define OUTD 128
#define HIDD 64
#define NBLK 196   // number of 256-target coarse buckets (196*256 = 50176 >= NN)
#define BCAP 6144  // bucket capacity for LDS sort (mean 4082, tail-safe)

typedef __attribute__((ext_vector_type(8))) short short8;   // 8 bf16 (4 VGPR)
typedef __attribute__((ext_vector_type(4))) float f32x4;    // MFMA acc

// ---------- helpers ----------
static __device__ __forceinline__ unsigned enc_f(float f) {
  unsigned u = __float_as_uint(f);
  return (u & 0x80000000u) ? ~u : (u | 0x80000000u);
}
static __device__ __forceinline__ float dec_f(unsigned u) {
  unsigned b = (u & 0x80000000u) ? (u ^ 0x80000000u) : ~u;
  return __uint_as_float(b);
}
static __device__ __forceinline__ unsigned f2bf(float f) {       // RNE f32->bf16 bits
  unsigned u = __float_as_uint(f);
  return (u + 0x7fffu + ((u >> 16) & 1u)) >> 16;
}
static __device__ __forceinline__ float bf2f(unsigned b) {
  return __uint_as_float(b << 16);
}

// ---------- K0: zero bucket histogram + init reduction scalars (1 block) ----------
__global__ __launch_bounds__(256) void k_zero(int* __restrict__ bsum,
                                              unsigned* __restrict__ umax,
                                              float* __restrict__ sumexp) {
  int i = threadIdx.x;
  if (i <= NBLK) bsum[i] = 0;
  if (i == 0) { *umax = 0x007FFFFFu /* enc(-inf) */; *sumexp = 0.f; }
}

// ---------- K0b: Wt[n][k] = bf16(W[k][n]) (one-time, 32768 elems) ----------
__global__ __launch_bounds__(256) void k_wconv(const float* __restrict__ W,
                                               unsigned short* __restrict__ Wt) {
  int t = blockIdx.x * 256 + threadIdx.x;     // 128 blocks
  int n = t >> 8, k = t & 255;
  Wt[t] = (unsigned short)f2bf(W[k * OUTD + n]);
}

// ---------- K1: Wh16 = bf16(x @ W) via MFMA 16x16x32 bf16 ----------
__global__ __launch_bounds__(256) void k_gemm(const float* __restrict__ x,
                                              const unsigned short* __restrict__ Wt,
                                              unsigned* __restrict__ Whu) {
  __shared__ float smem[8448];                 // max(A+B = 15360B, Cs = 33792B)
  short* As = (short*)smem;                    // [64][40] bf16
  short* Bs = As + 64 * 40;                    // [128][40] bf16
  float* Cs = smem;                            // [64][132] f32 (epilogue alias)

  const int tid  = threadIdx.x;
  const int bm   = blockIdx.x * 64;
  const int wave = tid >> 6;                   // 0..3 -> col block wave*32
  const int lane = tid & 63;
  const int l15  = lane & 15;
  const int lg   = lane >> 4;                  // 0..3

  f32x4 acc[4][2];
#pragma unroll
  for (int i = 0; i < 4; i++)
#pragma unroll
    for (int j = 0; j < 2; j++) acc[i][j] = (f32x4){0.f, 0.f, 0.f, 0.f};

  const int arow = tid >> 2, aq = tid & 3;
  long arow_g = bm + arow; if (arow_g >= NN) arow_g = NN - 1;   // clamp, writes guarded
  const float* xp = &x[arow_g * IND + aq * 8];
  short* asp = &As[arow * 40 + aq * 8];
  const int bn = tid >> 1, bh = tid & 1;
  const unsigned short* wtp = &Wt[bn * 256 + bh * 16];
  short* bsp = &Bs[bn * 40 + bh * 16];

  for (int k0 = 0; k0 < IND; k0 += 32) {
    float4 v0 = *(const float4*)(xp + k0);
    float4 v1 = *(const float4*)(xp + k0 + 4);
    short8 apk;
    apk[0] = (short)f2bf(v0.x); apk[1] = (short)f2bf(v0.y);
    apk[2] = (short)f2bf(v0.z); apk[3] = (short)f2bf(v0.w);
    apk[4] = (short)f2bf(v1.x); apk[5] = (short)f2bf(v1.y);
    apk[6] = (short)f2bf(v1.z); apk[7] = (short)f2bf(v1.w);
    *(short8*)asp = apk;
    *(short8*)bsp       = *(const short8*)(wtp + k0);
    *(short8*)(bsp + 8) = *(const short8*)(wtp + k0 + 8);
    __syncthreads();

    short8 af[4], bf[2];
#pragma unroll
    for (int mi = 0; mi < 4; mi++)
      af[mi] = *(const short8*)&As[(mi * 16 + l15) * 40 + lg * 8];
#pragma unroll
    for (int ni = 0; ni < 2; ni++)
      bf[ni] = *(const short8*)&Bs[(wave * 32 + ni * 16 + l15) * 40 + lg * 8];
#pragma unroll
    for (int mi = 0; mi < 4; mi++)
#pragma unroll
      for (int ni = 0; ni < 2; ni++)
        acc[mi][ni] = __builtin_amdgcn_mfma_f32_16x16x32_bf16(
            af[mi], bf[ni], acc[mi][ni], 0, 0, 0);
    __syncthreads();
  }

  // epilogue: acc -> Cs (f32) -> coalesced bf16 global
#pragma unroll
  for (int mi = 0; mi < 4; mi++)
#pragma unroll
    for (int ni = 0; ni < 2; ni++)
#pragma unroll
      for (int r = 0; r < 4; r++) {
        int row = mi * 16 + lg * 4 + r;
        int col = wave * 32 + ni * 16 + l15;
        Cs[row * 132 + col] = acc[mi][ni][r];
      }
  __syncthreads();
#pragma unroll
  for (int i = 0; i < 4; i++) {
    int f = tid + i * 256;                    // 1024 chunks of 8 f32
    int nd = f >> 4, seg = f & 15;
    long gnode = bm + nd;
    if (gnode < NN) {
      float4 c0 = *(const float4*)&Cs[nd * 132 + seg * 8];
      float4 c1 = *(const float4*)&Cs[nd * 132 + seg * 8 + 4];
      uint4 o;
      o.x = f2bf(c0.x) | (f2bf(c0.y) << 16);
      o.y = f2bf(c0.z) | (f2bf(c0.w) << 16);
      o.z = f2bf(c1.x) | (f2bf(c1.y) << 16);
      o.w = f2bf(c1.z) | (f2bf(c1.w) << 16);
      *(uint4*)&Whu[gnode * 64 + seg * 4] = o;
    }
  }
}

// ---------- K2: s_src/s_tgt from bf16 Wh (one wave per node) ----------
__global__ __launch_bounds__(256) void k_s(const unsigned* __restrict__ Whu,
                                           const float* __restrict__ a,
                                           float* __restrict__ s_src,
                                           float* __restrict__ s_tgt) {
  int wid = (blockIdx.x * 256 + threadIdx.x) >> 6;
  int lane = threadIdx.x & 63;
  if (wid >= NN) return;
  unsigned v = Whu[(long)wid * 64 + lane];
  float w0 = bf2f(v & 0xffffu), w1 = bf2f(v >> 16);
  float p1 = w0 * a[2 * lane]       + w1 * a[2 * lane + 1];
  float p2 = w0 * a[128 + 2 * lane] + w1 * a[128 + 2 * lane + 1];
#pragma unroll
  for (int off = 32; off; off >>= 1) {
    p1 += __shfl_down(p1, off);
    p2 += __shfl_down(p2, off);
  }
  if (lane == 0) { s_src[wid] = p1; s_tgt[wid] = p2; }
}

// ---------- K3: scores + global max + COARSE bucket histogram (LDS-aggregated) ----------
// 196 blocks x 4096 edges. Replaces 800K per-target global atomics with
// 196 LDS counters per block + <=196 global atomics per block (38K total).
__global__ __launch_bounds__(256) void k_score(const int* __restrict__ ei,
                                               const float* __restrict__ s_src,
                                               const float* __restrict__ s_tgt,
                                               float* __restrict__ scores,
                                               unsigned* __restrict__ umax,
                                               int* __restrict__ bsum) {
  __shared__ int bh[NBLK];
  const int tid = threadIdx.x;
  const long eb = (long)blockIdx.x * 4096;
  if (tid < NBLK) bh[tid] = 0;
  __syncthreads();

  float mx = -1e30f;
#pragma unroll
  for (int i = 0; i < 16; i++) {
    long e = eb + i * 256 + tid;
    if (e < NE) {
      int s = ei[e];
      int t = ei[NE + e];
      float v = s_src[s] + s_tgt[t];
      float sc = v > 0.f ? v : 0.2f * v;              // leaky_relu(0.2)
      scores[e] = sc;
      atomicAdd(&bh[t >> 8], 1);
      mx = fmaxf(mx, sc);
    }
  }
  __syncthreads();
  if (tid < NBLK) {
    int c = bh[tid];
    if (c) atomicAdd(&bsum[tid], c);
  }
  // block max
#pragma unroll
  for (int off = 32; off; off >>= 1) mx = fmaxf(mx, __shfl_down(mx, off));
  __shared__ float red[4];
  int w = tid >> 6, lane = tid & 63;
  if (lane == 0) red[w] = mx;
  __syncthreads();
  if (tid == 0) {
    float bm = fmaxf(fmaxf(red[0], red[1]), fmaxf(red[2], red[3]));
    atomicMax(umax, enc_f(bm));
  }
}

// ---------- K4: sum of exp(score - max) ----------
__global__ __launch_bounds__(256) void k_sum(const float* __restrict__ scores,
                                             const unsigned* __restrict__ umax,
                                             float* __restrict__ sumexp) {
  int e = blockIdx.x * 256 + threadIdx.x;
  float m = dec_f(*umax);
  float v = __expf(scores[e] - m);
#pragma unroll
  for (int off = 32; off; off >>= 1) v += __shfl_down(v, off);
  __shared__ float red[4];
  int w = threadIdx.x >> 6, lane = threadIdx.x & 63;
  if (lane == 0) red[w] = v;
  __syncthreads();
  if (threadIdx.x == 0)
    atomicAdd(sumexp, red[0] + red[1] + red[2] + red[3]);
}

// ---------- K5: exclusive scan of bucket sums; emit offsets + cursor + sentinel ----------
__global__ __launch_bounds__(256) void k_scan2(int* __restrict__ bsum,
                                               int* __restrict__ bcursor) {
  __shared__ int s[256];
  int tid = threadIdx.x;
  int v = (tid < NBLK) ? bsum[tid] : 0;
  s[tid] = v;
  __syncthreads();
  for (int off = 1; off < 256; off <<= 1) {
    int t = (tid >= off) ? s[tid - off] : 0;
    __syncthreads();
    s[tid] += t;
    __syncthreads();
  }
  int excl = (tid == 0) ? 0 : s[tid - 1];
  if (tid <= NBLK) bsum[tid] = excl;          // bsum[NBLK] = NE sentinel
  if (tid < NBLK) bcursor[tid] = excl;
}

// ---------- K6a: coarse bucket scatter (block-owned chunks, XCD-local lines) ----------
__global__ __launch_bounds__(256) void k_binA(const int* __restrict__ ei,
                                              const float* __restrict__ scores,
                                              const unsigned* __restrict__ umax,
                                              const float* __restrict__ sumexp,
                                              int* __restrict__ bcursor,
                                              int2* __restrict__ recs_mid) {
  __shared__ int bh[NBLK];
  __shared__ int gbase[NBLK];
  const int tid = threadIdx.x;
  const long eb = (long)blockIdx.x * 4096;
  if (tid < NBLK) bh[tid] = 0;
  __syncthreads();

  float m = dec_f(*umax);
  float inv = 1.0f / *sumexp;

  int tv[16]; int sv[16]; float av[16];
#pragma unroll
  for (int i = 0; i < 16; i++) {
    long e = eb + i * 256 + tid;
    if (e < NE) {
      sv[i] = ei[e];
      tv[i] = ei[NE + e];
      av[i] = __expf(scores[e] - m) * inv;
      atomicAdd(&bh[tv[i] >> 8], 1);
    } else {
      tv[i] = -1;
    }
  }
  __syncthreads();
  if (tid < NBLK) {
    int c = bh[tid];
    gbase[tid] = (c > 0) ? atomicAdd(&bcursor[tid], c) : 0;
    bh[tid] = 0;                               // reuse as local cursor
  }
  __syncthreads();
#pragma unroll
  for (int i = 0; i < 16; i++) {
    if (tv[i] >= 0) {
      int b = tv[i] >> 8;
      int off = atomicAdd(&bh[b], 1);
      int pos = gbase[b] + off;
      recs_mid[pos] = make_int2(sv[i] | ((tv[i] & 255) << 16),
                                __float_as_int(av[i]));
    }
  }
}

// ---------- K6b: in-bucket LDS sort by target + coalesced write + offs emit ----------
// One block per bucket. Local exclusive scan of 256 target counts gives both
// the in-bucket placement and the global offs[] (start + local exclusive).
__global__ __launch_bounds__(256) void k_sortB(const int* __restrict__ bsum,
                                               const int2* __restrict__ recs_mid,
                                               int2* __restrict__ recs,
                                               int* __restrict__ offs) {
  __shared__ int h[256], sc[256], cur[256];
  __shared__ int2 srt[BCAP];
  const int tid = threadIdx.x;
  const int b = blockIdx.x;
  const int start = bsum[b];
  const int m = bsum[b + 1] - start;

  h[tid] = 0;
  __syncthreads();
  for (int i = tid; i < m; i += 256) {
    int2 r = recs_mid[start + i];
    atomicAdd(&h[(r.x >> 16) & 255], 1);
  }
  __syncthreads();
  sc[tid] = h[tid];
  __syncthreads();
  for (int off = 1; off < 256; off <<= 1) {
    int t = (tid >= off) ? sc[tid - off] : 0;
    __syncthreads();
    sc[tid] += t;
    __syncthreads();
  }
  int excl = sc[tid] - h[tid];
  cur[tid] = excl;
  offs[b * 256 + tid] = start + excl;          // global per-target offsets
  __syncthreads();
  for (int i = tid; i < m; i += 256) {
    int2 r = recs_mid[start + i];
    int tl = (r.x >> 16) & 255;
    int p = atomicAdd(&cur[tl], 1);
    if (p < BCAP) srt[p] = make_int2(r.x & 0xffff, r.y);
  }
  __syncthreads();
  for (int i = tid; i < m; i += 256)
    recs[start + i] = srt[i];                  // fully coalesced
}

// ---------- K7: gather-sum per target node (one wave per node, bf16 rows) ----------
__global__ __launch_bounds__(256) void k_gather(const int* __restrict__ offs,
                                                const int2* __restrict__ recs,
                                                const unsigned* __restrict__ Whu,
                                                float* __restrict__ xnew) {
  int wid = (blockIdx.x * 256 + threadIdx.x) >> 6;    // 12500*4 = NN waves
  int lane = threadIdx.x & 63;
  int start = offs[wid];
  int n = offs[wid + 1] - start;
  float2 acc = make_float2(0.f, 0.f);
  for (int base = 0; base < n; base += 64) {
    int m = n - base; if (m > 64) m = 64;
    int li = lane < m ? lane : m - 1;
    int2 r = recs[start + base + li];                 // coalesced chunk load
    for (int i = 0; i < m; i += 4) {                  // 4 row-loads in flight
      int sj[4]; float aj[4];
#pragma unroll
      for (int j = 0; j < 4; j++) {
        int idx = i + j;
        sj[j] = __shfl(r.x, idx);
        float al = __int_as_float(__shfl(r.y, idx));
        aj[j] = (idx < m) ? al : 0.f;
      }
      unsigned v[4];
#pragma unroll
      for (int j = 0; j < 4; j++)
        v[j] = Whu[(long)sj[j] * 64 + lane];
#pragma unroll
      for (int j = 0; j < 4; j++) {
        acc.x = fmaf(aj[j], bf2f(v[j] & 0xffffu), acc.x);
        acc.y = fmaf(aj[j], bf2f(v[j] >> 16), acc.y);
      }
    }
  }
  ((float2*)xnew)[(long)wid * 64 + lane] = acc;
}

// ---------- K8: fused MLP head as register-tiled GEMM ----------
__global__ __launch_bounds__(256) void k_mlp(const float* __restrict__ xnew,
                                             const float* __restrict__ W1,
                                             const float* __restrict__ b1,
                                             const float* __restrict__ W2,
                                             const float* __restrict__ b2,
                                             float* __restrict__ evid) {
  __shared__ float xs[64][132];     // row stride 132 (528B, 16B-aligned)
  __shared__ float w1s[128][64];    // [k][hid]
  const int tid = threadIdx.x;
  const int nb = blockIdx.x * 64;
  const int ty = tid >> 4;          // 0..15 -> nodes ty*4..+3
  const int tx = tid & 15;          // 0..15 -> hid tx*4..+3

#pragma unroll
  for (int i = 0; i < 8; i++) {
    int f = tid + i * 256;
    int n = f >> 5;
    int kq = (f & 31) * 4;
    int row = nb + n; if (row >= NN) row = NN - 1;
    *(float4*)&xs[n][kq] = *(const float4*)&xnew[(long)row * OUTD + kq];
  }
#pragma unroll
  for (int i = 0; i < 8; i++) {
    int f = tid + i * 256;
    int kr = f >> 4;
    int cq = (f & 15) * 4;
    *(float4*)&w1s[kr][cq] = *(const float4*)&W1[kr * HIDD + cq];
  }
  __syncthreads();

  float acc[4][4];
#pragma unroll
  for (int i = 0; i < 4; i++)
#pragma unroll
    for (int j = 0; j < 4; j++) acc[i][j] = 0.f;

#pragma unroll 2
  for (int k0 = 0; k0 < OUTD; k0 += 4) {
    float4 xv[4], wv[4];
#pragma unroll
    for (int i = 0; i < 4; i++) xv[i] = *(const float4*)&xs[ty * 4 + i][k0];
#pragma unroll
    for (int d = 0; d < 4; d++) wv[d] = *(const float4*)&w1s[k0 + d][tx * 4];
#pragma unroll
    for (int i = 0; i < 4; i++) {
      float xr[4] = {xv[i].x, xv[i].y, xv[i].z, xv[i].w};
#pragma unroll
      for (int d = 0; d < 4; d++) {
        float wr[4] = {wv[d].x, wv[d].y, wv[d].z, wv[d].w};
#pragma unroll
        for (int j = 0; j < 4; j++)
          acc[i][j] = fmaf(xr[d], wr[j], acc[i][j]);
      }
    }
  }

  float b1r[4], w2r[4][3];
#pragma unroll
  for (int j = 0; j < 4; j++) {
    int jg = tx * 4 + j;
    b1r[j] = b1[jg];
    w2r[j][0] = W2[jg * 3 + 0];
    w2r[j][1] = W2[jg * 3 + 1];
    w2r[j][2] = W2[jg * 3 + 2];
  }
#pragma unroll
  for (int i = 0; i < 4; i++) {
    float p0 = 0.f, p1 = 0.f, p2 = 0.f;
#pragma unroll
    for (int j = 0; j < 4; j++) {
      float h = fmaxf(acc[i][j] + b1r[j], 0.f);
      p0 = fmaf(h, w2r[j][0], p0);
      p1 = fmaf(h, w2r[j][1], p1);
      p2 = fmaf(h, w2r[j][2], p2);
    }
#pragma unroll
    for (int m = 1; m < 16; m <<= 1) {
      p0 += __shfl_xor(p0, m);
      p1 += __shfl_xor(p1, m);
      p2 += __shfl_xor(p2, m);
    }
    if (tx == 0) {
      int n = nb + ty * 4 + i;
      if (n < NN) {
        float e0 = p0 + b2[0], e1 = p1 + b2[1], e2 = p2 + b2[2];
        float s0 = e0 > 20.f ? e0 : log1pf(expf(e0));
        float s1 = e1 > 20.f ? e1 : log1pf(expf(e1));
        float s2 = e2 > 20.f ? e2 : log1pf(expf(e2));
        evid[(long)n * 3 + 0] = s0 + 1.0f;
        evid[(long)n * 3 + 1] = s1 + 1.0f;
        evid[(long)n * 3 + 2] = s2 + 1.0f;
      }
    }
  }
}

extern "C" void kernel_launch(void* const* d_in, const int* in_sizes, int n_in,
                              void* d_out, int out_size, void* d_ws, size_t ws_size,
                              hipStream_t stream) {
  const float* x   = (const float*)d_in[0];
  const int*   ei  = (const int*)d_in[1];
  const float* W   = (const float*)d_in[2];
  const float* a   = (const float*)d_in[3];
  const float* W1  = (const float*)d_in[4];
  const float* b1  = (const float*)d_in[5];
  const float* W2  = (const float*)d_in[6];
  const float* b2  = (const float*)d_in[7];

  float* xnew = (float*)d_out;                       // [NN*OUTD]
  float* evid = (float*)d_out + (size_t)NN * OUTD;   // [NN*3]

  float* wsf = (float*)d_ws;
  unsigned* Whu      = (unsigned*)wsf;               // 3,200,000 u32 (12.8 MB bf16 Wh)
  float*    s_src    = wsf + 3200000;                //    50,000 f
  float*    s_tgt    = wsf + 3250000;                //    50,000 f
  float*    scores   = wsf + 3300000;                //   800,000 f
  int2*     recs_mid = (int2*)(wsf + 4100000);       //   800,000 int2
  int2*     recs     = (int2*)(wsf + 5700000);       //   800,000 int2
  unsigned* umax     = (unsigned*)(wsf + 7300000);
  float*    sumexp   = wsf + 7300002;
  int*      offs     = (int*)(wsf + 7300004);        //    50,200 i (incl sentinel range)
  int*      bsum     = (int*)(wsf + 7350204);        //       197 i
  int*      bcursor  = (int*)(wsf + 7350404);        //       196 i
  unsigned short* Wt = (unsigned short*)(wsf + 7350600);  // 32,768 bf16 (end ~29.5 MB)

  k_zero<<<1, 256, 0, stream>>>(bsum, umax, sumexp);
  k_wconv<<<128, 256, 0, stream>>>(W, Wt);
  k_gemm<<<(NN + 63) / 64, 256, 0, stream>>>(x, Wt, Whu);
  k_s<<<12500, 256, 0, stream>>>(Whu, a, s_src, s_tgt);
  k_score<<<NBLK, 256, 0, stream>>>(ei, s_src, s_tgt, scores, umax, bsum);
  k_sum<<<NE / 256, 256, 0, stream>>>(scores, umax, sumexp);
  k_scan2<<<1, 256, 0, stream>>>(bsum, bcursor);
  k_binA<<<NBLK, 256, 0, stream>>>(ei, scores, umax, sumexp, bcursor, recs_mid);
  k_sortB<<<NBLK, 256, 0, stream>>>(bsum, recs_mid, recs, offs);
  k_gather<<<NN / 4, 256, 0, stream>>>(offs, recs, Whu, xnew);
  k_mlp<<<(NN + 63) / 64, 256, 0, stream>>>(xnew, W1, b1, W2, b2, evid);
}

// Round 9
// 147.462 us; speedup vs baseline: 6.0553x; 1.2725x over previous
//
#include <hip/hip_runtime.h>
#include <math.h>

#define NN 50000
#define NE 800000
#define IND 256
#define OUTD 128
#define HIDD 64
#define NBLK 196   // number of 256-target coarse buckets (196*256 = 50176 >= NN)
#define BCAP 6144  // bucket capacity for LDS sort (mean 4082, tail-safe)

typedef __attribute__((ext_vector_type(8))) short short8;   // 8 bf16 (4 VGPR)
typedef __attribute__((ext_vector_type(4))) float f32x4;    // MFMA acc

// ---------- helpers ----------
static __device__ __forceinline__ unsigned f2bf(float f) {       // RNE f32->bf16 bits
  unsigned u = __float_as_uint(f);
  return (u + 0x7fffu + ((u >> 16) & 1u)) >> 16;
}
static __device__ __forceinline__ float bf2f(unsigned b) {
  return __uint_as_float(b << 16);
}

// ---------- K0: zero bucket histogram (1 block) ----------
__global__ __launch_bounds__(256) void k_zero(int* __restrict__ bsum) {
  int i = threadIdx.x;
  if (i <= NBLK) bsum[i] = 0;
}

// ---------- K0b: Wt[n][k] = bf16(W[k][n]) (one-time, 32768 elems) ----------
__global__ __launch_bounds__(256) void k_wconv(const float* __restrict__ W,
                                               unsigned short* __restrict__ Wt) {
  int t = blockIdx.x * 256 + threadIdx.x;     // 128 blocks
  int n = t >> 8, k = t & 255;
  Wt[t] = (unsigned short)f2bf(W[k * OUTD + n]);
}

// ---------- K1: Wh16 = bf16(x @ W) via MFMA 16x16x32 bf16 ----------
__global__ __launch_bounds__(256) void k_gemm(const float* __restrict__ x,
                                              const unsigned short* __restrict__ Wt,
                                              unsigned* __restrict__ Whu) {
  __shared__ float smem[8448];                 // max(A+B = 15360B, Cs = 33792B)
  short* As = (short*)smem;                    // [64][40] bf16
  short* Bs = As + 64 * 40;                    // [128][40] bf16
  float* Cs = smem;                            // [64][132] f32 (epilogue alias)

  const int tid  = threadIdx.x;
  const int bm   = blockIdx.x * 64;
  const int wave = tid >> 6;                   // 0..3 -> col block wave*32
  const int lane = tid & 63;
  const int l15  = lane & 15;
  const int lg   = lane >> 4;                  // 0..3

  f32x4 acc[4][2];
#pragma unroll
  for (int i = 0; i < 4; i++)
#pragma unroll
    for (int j = 0; j < 2; j++) acc[i][j] = (f32x4){0.f, 0.f, 0.f, 0.f};

  const int arow = tid >> 2, aq = tid & 3;
  long arow_g = bm + arow; if (arow_g >= NN) arow_g = NN - 1;   // clamp, writes guarded
  const float* xp = &x[arow_g * IND + aq * 8];
  short* asp = &As[arow * 40 + aq * 8];
  const int bn = tid >> 1, bh = tid & 1;
  const unsigned short* wtp = &Wt[bn * 256 + bh * 16];
  short* bsp = &Bs[bn * 40 + bh * 16];

  for (int k0 = 0; k0 < IND; k0 += 32) {
    float4 v0 = *(const float4*)(xp + k0);
    float4 v1 = *(const float4*)(xp + k0 + 4);
    short8 apk;
    apk[0] = (short)f2bf(v0.x); apk[1] = (short)f2bf(v0.y);
    apk[2] = (short)f2bf(v0.z); apk[3] = (short)f2bf(v0.w);
    apk[4] = (short)f2bf(v1.x); apk[5] = (short)f2bf(v1.y);
    apk[6] = (short)f2bf(v1.z); apk[7] = (short)f2bf(v1.w);
    *(short8*)asp = apk;
    *(short8*)bsp       = *(const short8*)(wtp + k0);
    *(short8*)(bsp + 8) = *(const short8*)(wtp + k0 + 8);
    __syncthreads();

    short8 af[4], bf[2];
#pragma unroll
    for (int mi = 0; mi < 4; mi++)
      af[mi] = *(const short8*)&As[(mi * 16 + l15) * 40 + lg * 8];
#pragma unroll
    for (int ni = 0; ni < 2; ni++)
      bf[ni] = *(const short8*)&Bs[(wave * 32 + ni * 16 + l15) * 40 + lg * 8];
#pragma unroll
    for (int mi = 0; mi < 4; mi++)
#pragma unroll
      for (int ni = 0; ni < 2; ni++)
        acc[mi][ni] = __builtin_amdgcn_mfma_f32_16x16x32_bf16(
            af[mi], bf[ni], acc[mi][ni], 0, 0, 0);
    __syncthreads();
  }

  // epilogue: acc -> Cs (f32) -> coalesced bf16 global
#pragma unroll
  for (int mi = 0; mi < 4; mi++)
#pragma unroll
    for (int ni = 0; ni < 2; ni++)
#pragma unroll
      for (int r = 0; r < 4; r++) {
        int row = mi * 16 + lg * 4 + r;
        int col = wave * 32 + ni * 16 + l15;
        Cs[row * 132 + col] = acc[mi][ni][r];
      }
  __syncthreads();
#pragma unroll
  for (int i = 0; i < 4; i++) {
    int f = tid + i * 256;                    // 1024 chunks of 8 f32
    int nd = f >> 4, seg = f & 15;
    long gnode = bm + nd;
    if (gnode < NN) {
      float4 c0 = *(const float4*)&Cs[nd * 132 + seg * 8];
      float4 c1 = *(const float4*)&Cs[nd * 132 + seg * 8 + 4];
      uint4 o;
      o.x = f2bf(c0.x) | (f2bf(c0.y) << 16);
      o.y = f2bf(c0.z) | (f2bf(c0.w) << 16);
      o.z = f2bf(c1.x) | (f2bf(c1.y) << 16);
      o.w = f2bf(c1.z) | (f2bf(c1.w) << 16);
      *(uint4*)&Whu[gnode * 64 + seg * 4] = o;
    }
  }
}

// ---------- K2: s_src/s_tgt from bf16 Wh (one wave per node) ----------
__global__ __launch_bounds__(256) void k_s(const unsigned* __restrict__ Whu,
                                           const float* __restrict__ a,
                                           float* __restrict__ s_src,
                                           float* __restrict__ s_tgt) {
  int wid = (blockIdx.x * 256 + threadIdx.x) >> 6;
  int lane = threadIdx.x & 63;
  if (wid >= NN) return;
  unsigned v = Whu[(long)wid * 64 + lane];
  float w0 = bf2f(v & 0xffffu), w1 = bf2f(v >> 16);
  float p1 = w0 * a[2 * lane]       + w1 * a[2 * lane + 1];
  float p2 = w0 * a[128 + 2 * lane] + w1 * a[128 + 2 * lane + 1];
#pragma unroll
  for (int off = 32; off; off >>= 1) {
    p1 += __shfl_down(p1, off);
    p2 += __shfl_down(p2, off);
  }
  if (lane == 0) { s_src[wid] = p1; s_tgt[wid] = p2; }
}

// ---------- K3: scores + coarse-bucket histogram + per-block softmax stats ----------
// 196 blocks x 4096 edges. Emits bmax[b] = block max, bsexp[b] = sum exp(sc-bmax).
// No single-address global atomics (the 42us k_sum pathology).
__global__ __launch_bounds__(256) void k_score(const int* __restrict__ ei,
                                               const float* __restrict__ s_src,
                                               const float* __restrict__ s_tgt,
                                               float* __restrict__ scores,
                                               int* __restrict__ bsum,
                                               float* __restrict__ bmax,
                                               float* __restrict__ bsexp) {
  __shared__ int bh[NBLK];
  __shared__ float red[4];
  __shared__ float bmx;
  const int tid = threadIdx.x;
  const long eb = (long)blockIdx.x * 4096;
  if (tid < NBLK) bh[tid] = 0;
  __syncthreads();

  float scv[16];
  float mx = -1e30f;
#pragma unroll
  for (int i = 0; i < 16; i++) {
    long e = eb + i * 256 + tid;
    float sc = -1e30f;
    if (e < NE) {
      int s = ei[e];
      int t = ei[NE + e];
      float v = s_src[s] + s_tgt[t];
      sc = v > 0.f ? v : 0.2f * v;              // leaky_relu(0.2)
      scores[e] = sc;
      atomicAdd(&bh[t >> 8], 1);
    }
    scv[i] = sc;
    mx = fmaxf(mx, sc);
  }
  __syncthreads();
  if (tid < NBLK) {
    int c = bh[tid];
    if (c) atomicAdd(&bsum[tid], c);
  }
  // block max
#pragma unroll
  for (int off = 32; off; off >>= 1) mx = fmaxf(mx, __shfl_down(mx, off));
  int w = tid >> 6, lane = tid & 63;
  if (lane == 0) red[w] = mx;
  __syncthreads();
  if (tid == 0) bmx = fmaxf(fmaxf(red[0], red[1]), fmaxf(red[2], red[3]));
  __syncthreads();
  const float M = bmx;
  // block sum of exp(sc - M)  (invalid lanes: exp(-huge) == 0)
  float s = 0.f;
#pragma unroll
  for (int i = 0; i < 16; i++) s += __expf(scv[i] - M);
#pragma unroll
  for (int off = 32; off; off >>= 1) s += __shfl_down(s, off);
  if (lane == 0) red[w] = s;
  __syncthreads();
  if (tid == 0) {
    bmax[blockIdx.x] = M;
    bsexp[blockIdx.x] = red[0] + red[1] + red[2] + red[3];
  }
}

// ---------- K5: scan bucket sums + combine softmax stats (1 block) ----------
__global__ __launch_bounds__(256) void k_scan2(int* __restrict__ bsum,
                                               int* __restrict__ bcursor,
                                               const float* __restrict__ bmax,
                                               const float* __restrict__ bsexp,
                                               float* __restrict__ softstat) {
  __shared__ int s[256];
  __shared__ float fred[256];
  int tid = threadIdx.x;
  int v = (tid < NBLK) ? bsum[tid] : 0;
  s[tid] = v;
  __syncthreads();
  for (int off = 1; off < 256; off <<= 1) {
    int t = (tid >= off) ? s[tid - off] : 0;
    __syncthreads();
    s[tid] += t;
    __syncthreads();
  }
  int excl = (tid == 0) ? 0 : s[tid - 1];
  if (tid <= NBLK) bsum[tid] = excl;          // bsum[NBLK] = NE sentinel
  if (tid < NBLK) bcursor[tid] = excl;

  // global max
  float m = (tid < NBLK) ? bmax[tid] : -1e30f;
  fred[tid] = m;
  __syncthreads();
  for (int off = 128; off; off >>= 1) {
    if (tid < off) fred[tid] = fmaxf(fred[tid], fred[tid + off]);
    __syncthreads();
  }
  const float M = fred[0];
  __syncthreads();
  // global sum: sum bsexp[b] * exp(bmax[b] - M)
  float se = (tid < NBLK) ? bsexp[tid] * __expf(bmax[tid] - M) : 0.f;
  fred[tid] = se;
  __syncthreads();
  for (int off = 128; off; off >>= 1) {
    if (tid < off) fred[tid] += fred[tid + off];
    __syncthreads();
  }
  if (tid == 0) { softstat[0] = M; softstat[1] = fred[0]; }
}

// ---------- K6a: coarse bucket scatter (block-owned chunks, XCD-local lines) ----------
__global__ __launch_bounds__(256) void k_binA(const int* __restrict__ ei,
                                              const float* __restrict__ scores,
                                              const float* __restrict__ softstat,
                                              int* __restrict__ bcursor,
                                              int2* __restrict__ recs_mid) {
  __shared__ int bh[NBLK];
  __shared__ int gbase[NBLK];
  const int tid = threadIdx.x;
  const long eb = (long)blockIdx.x * 4096;
  if (tid < NBLK) bh[tid] = 0;
  __syncthreads();

  float m = softstat[0];
  float inv = 1.0f / softstat[1];

  int tv[16]; int sv[16]; float av[16];
#pragma unroll
  for (int i = 0; i < 16; i++) {
    long e = eb + i * 256 + tid;
    if (e < NE) {
      sv[i] = ei[e];
      tv[i] = ei[NE + e];
      av[i] = __expf(scores[e] - m) * inv;
      atomicAdd(&bh[tv[i] >> 8], 1);
    } else {
      tv[i] = -1;
    }
  }
  __syncthreads();
  if (tid < NBLK) {
    int c = bh[tid];
    gbase[tid] = (c > 0) ? atomicAdd(&bcursor[tid], c) : 0;
    bh[tid] = 0;                               // reuse as local cursor
  }
  __syncthreads();
#pragma unroll
  for (int i = 0; i < 16; i++) {
    if (tv[i] >= 0) {
      int b = tv[i] >> 8;
      int off = atomicAdd(&bh[b], 1);
      int pos = gbase[b] + off;
      recs_mid[pos] = make_int2(sv[i] | ((tv[i] & 255) << 16),
                                __float_as_int(av[i]));
    }
  }
}

// ---------- K6b: in-bucket LDS sort by target + coalesced write + offs emit ----------
__global__ __launch_bounds__(256) void k_sortB(const int* __restrict__ bsum,
                                               const int2* __restrict__ recs_mid,
                                               int2* __restrict__ recs,
                                               int* __restrict__ offs) {
  __shared__ int h[256], sc[256], cur[256];
  __shared__ int2 srt[BCAP];
  const int tid = threadIdx.x;
  const int b = blockIdx.x;
  const int start = bsum[b];
  const int m = bsum[b + 1] - start;

  h[tid] = 0;
  __syncthreads();
  for (int i = tid; i < m; i += 256) {
    int2 r = recs_mid[start + i];
    atomicAdd(&h[(r.x >> 16) & 255], 1);
  }
  __syncthreads();
  sc[tid] = h[tid];
  __syncthreads();
  for (int off = 1; off < 256; off <<= 1) {
    int t = (tid >= off) ? sc[tid - off] : 0;
    __syncthreads();
    sc[tid] += t;
    __syncthreads();
  }
  int excl = sc[tid] - h[tid];
  cur[tid] = excl;
  offs[b * 256 + tid] = start + excl;          // global per-target offsets
  __syncthreads();
  for (int i = tid; i < m; i += 256) {
    int2 r = recs_mid[start + i];
    int tl = (r.x >> 16) & 255;
    int p = atomicAdd(&cur[tl], 1);
    if (p < BCAP) srt[p] = make_int2(r.x & 0xffff, r.y);
  }
  __syncthreads();
  for (int i = tid; i < m; i += 256)
    recs[start + i] = srt[i];                  // fully coalesced
}

// ---------- K7: gather-sum per target node (one wave per node, bf16 rows) ----------
__global__ __launch_bounds__(256) void k_gather(const int* __restrict__ offs,
                                                const int2* __restrict__ recs,
                                                const unsigned* __restrict__ Whu,
                                                float* __restrict__ xnew) {
  int wid = (blockIdx.x * 256 + threadIdx.x) >> 6;    // 12500*4 = NN waves
  int lane = threadIdx.x & 63;
  int start = offs[wid];
  int n = offs[wid + 1] - start;
  float2 acc = make_float2(0.f, 0.f);
  for (int base = 0; base < n; base += 64) {
    int m = n - base; if (m > 64) m = 64;
    int li = lane < m ? lane : m - 1;
    int2 r = recs[start + base + li];                 // coalesced chunk load
    for (int i = 0; i < m; i += 4) {                  // 4 row-loads in flight
      int sj[4]; float aj[4];
#pragma unroll
      for (int j = 0; j < 4; j++) {
        int idx = i + j;
        sj[j] = __shfl(r.x, idx);
        float al = __int_as_float(__shfl(r.y, idx));
        aj[j] = (idx < m) ? al : 0.f;
      }
      unsigned v[4];
#pragma unroll
      for (int j = 0; j < 4; j++)
        v[j] = Whu[(long)sj[j] * 64 + lane];
#pragma unroll
      for (int j = 0; j < 4; j++) {
        acc.x = fmaf(aj[j], bf2f(v[j] & 0xffffu), acc.x);
        acc.y = fmaf(aj[j], bf2f(v[j] >> 16), acc.y);
      }
    }
  }
  ((float2*)xnew)[(long)wid * 64 + lane] = acc;
}

// ---------- K8: fused MLP head as register-tiled GEMM ----------
__global__ __launch_bounds__(256) void k_mlp(const float* __restrict__ xnew,
                                             const float* __restrict__ W1,
                                             const float* __restrict__ b1,
                                             const float* __restrict__ W2,
                                             const float* __restrict__ b2,
                                             float* __restrict__ evid) {
  __shared__ float xs[64][132];     // row stride 132 (528B, 16B-aligned)
  __shared__ float w1s[128][64];    // [k][hid]
  const int tid = threadIdx.x;
  const int nb = blockIdx.x * 64;
  const int ty = tid >> 4;          // 0..15 -> nodes ty*4..+3
  const int tx = tid & 15;          // 0..15 -> hid tx*4..+3

#pragma unroll
  for (int i = 0; i < 8; i++) {
    int f = tid + i * 256;
    int n = f >> 5;
    int kq = (f & 31) * 4;
    int row = nb + n; if (row >= NN) row = NN - 1;
    *(float4*)&xs[n][kq] = *(const float4*)&xnew[(long)row * OUTD + kq];
  }
#pragma unroll
  for (int i = 0; i < 8; i++) {
    int f = tid + i * 256;
    int kr = f >> 4;
    int cq = (f & 15) * 4;
    *(float4*)&w1s[kr][cq] = *(const float4*)&W1[kr * HIDD + cq];
  }
  __syncthreads();

  float acc[4][4];
#pragma unroll
  for (int i = 0; i < 4; i++)
#pragma unroll
    for (int j = 0; j < 4; j++) acc[i][j] = 0.f;

#pragma unroll 2
  for (int k0 = 0; k0 < OUTD; k0 += 4) {
    float4 xv[4], wv[4];
#pragma unroll
    for (int i = 0; i < 4; i++) xv[i] = *(const float4*)&xs[ty * 4 + i][k0];
#pragma unroll
    for (int d = 0; d < 4; d++) wv[d] = *(const float4*)&w1s[k0 + d][tx * 4];
#pragma unroll
    for (int i = 0; i < 4; i++) {
      float xr[4] = {xv[i].x, xv[i].y, xv[i].z, xv[i].w};
#pragma unroll
      for (int d = 0; d < 4; d++) {
        float wr[4] = {wv[d].x, wv[d].y, wv[d].z, wv[d].w};
#pragma unroll
        for (int j = 0; j < 4; j++)
          acc[i][j] = fmaf(xr[d], wr[j], acc[i][j]);
      }
    }
  }

  float b1r[4], w2r[4][3];
#pragma unroll
  for (int j = 0; j < 4; j++) {
    int jg = tx * 4 + j;
    b1r[j] = b1[jg];
    w2r[j][0] = W2[jg * 3 + 0];
    w2r[j][1] = W2[jg * 3 + 1];
    w2r[j][2] = W2[jg * 3 + 2];
  }
#pragma unroll
  for (int i = 0; i < 4; i++) {
    float p0 = 0.f, p1 = 0.f, p2 = 0.f;
#pragma unroll
    for (int j = 0; j < 4; j++) {
      float h = fmaxf(acc[i][j] + b1r[j], 0.f);
      p0 = fmaf(h, w2r[j][0], p0);
      p1 = fmaf(h, w2r[j][1], p1);
      p2 = fmaf(h, w2r[j][2], p2);
    }
#pragma unroll
    for (int m = 1; m < 16; m <<= 1) {
      p0 += __shfl_xor(p0, m);
      p1 += __shfl_xor(p1, m);
      p2 += __shfl_xor(p2, m);
    }
    if (tx == 0) {
      int n = nb + ty * 4 + i;
      if (n < NN) {
        float e0 = p0 + b2[0], e1 = p1 + b2[1], e2 = p2 + b2[2];
        float s0 = e0 > 20.f ? e0 : log1pf(expf(e0));
        float s1 = e1 > 20.f ? e1 : log1pf(expf(e1));
        float s2 = e2 > 20.f ? e2 : log1pf(expf(e2));
        evid[(long)n * 3 + 0] = s0 + 1.0f;
        evid[(long)n * 3 + 1] = s1 + 1.0f;
        evid[(long)n * 3 + 2] = s2 + 1.0f;
      }
    }
  }
}

extern "C" void kernel_launch(void* const* d_in, const int* in_sizes, int n_in,
                              void* d_out, int out_size, void* d_ws, size_t ws_size,
                              hipStream_t stream) {
  const float* x   = (const float*)d_in[0];
  const int*   ei  = (const int*)d_in[1];
  const float* W   = (const float*)d_in[2];
  const float* a   = (const float*)d_in[3];
  const float* W1  = (const float*)d_in[4];
  const float* b1  = (const float*)d_in[5];
  const float* W2  = (const float*)d_in[6];
  const float* b2  = (const float*)d_in[7];

  float* xnew = (float*)d_out;                       // [NN*OUTD]
  float* evid = (float*)d_out + (size_t)NN * OUTD;   // [NN*3]

  float* wsf = (float*)d_ws;
  unsigned* Whu      = (unsigned*)wsf;               // 3,200,000 u32 (12.8 MB bf16 Wh)
  float*    s_src    = wsf + 3200000;                //    50,000 f
  float*    s_tgt    = wsf + 3250000;                //    50,000 f
  float*    scores   = wsf + 3300000;                //   800,000 f
  int2*     recs_mid = (int2*)(wsf + 4100000);       //   800,000 int2
  int2*     recs     = (int2*)(wsf + 5700000);       //   800,000 int2
  int*      offs     = (int*)(wsf + 7300000);        //    50,200 i (incl sentinel range)
  int*      bsum     = (int*)(wsf + 7350204);        //       197 i
  int*      bcursor  = (int*)(wsf + 7350404);        //       196 i
  float*    bmax     = wsf + 7350600;                //       196 f
  float*    bsexp    = wsf + 7350796;                //       196 f
  float*    softstat = wsf + 7350992;                //         2 f
  unsigned short* Wt = (unsigned short*)(wsf + 7351000);  // 32,768 bf16 (end ~29.5 MB)

  k_zero<<<1, 256, 0, stream>>>(bsum);
  k_wconv<<<128, 256, 0, stream>>>(W, Wt);
  k_gemm<<<(NN + 63) / 64, 256, 0, stream>>>(x, Wt, Whu);
  k_s<<<12500, 256, 0, stream>>>(Whu, a, s_src, s_tgt);
  k_score<<<NBLK, 256, 0, stream>>>(ei, s_src, s_tgt, scores, bsum, bmax, bsexp);
  k_scan2<<<1, 256, 0, stream>>>(bsum, bcursor, bmax, bsexp, softstat);
  k_binA<<<NBLK, 256, 0, stream>>>(ei, scores, softstat, bcursor, recs_mid);
  k_sortB<<<NBLK, 256, 0, stream>>>(bsum, recs_mid, recs, offs);
  k_gather<<<NN / 4, 256, 0, stream>>>(offs, recs, Whu, xnew);
  k_mlp<<<(NN + 63) / 64, 256, 0, stream>>>(xnew, W1, b1, W2, b2, evid);
}

// Round 10
// 141.287 us; speedup vs baseline: 6.3199x; 1.0437x over previous
//
#include <hip/hip_runtime.h>
#include <math.h>

#define NN 50000
#define NE 800000
#define IND 256
#define OUTD 128
#define HIDD 64
#define NBLK 196   // number of 256-target coarse buckets (196*256 = 50176 >= NN)
#define BCAP 6144  // bucket capacity for LDS sort (mean 4082, tail-safe)

typedef __attribute__((ext_vector_type(8))) short short8;   // 8 bf16 (4 VGPR)
typedef __attribute__((ext_vector_type(4))) float f32x4;    // MFMA acc
typedef __attribute__((ext_vector_type(2))) float f32x2;    // fp8 cvt result

// ---------- helpers ----------
static __device__ __forceinline__ unsigned f2bf(float f) {       // RNE f32->bf16 bits
  unsigned u = __float_as_uint(f);
  return (u + 0x7fffu + ((u >> 16) & 1u)) >> 16;
}

// ---------- K0: Wt[n][k] = bf16(W[k][n]) + (block 0) zero bsum ----------
__global__ __launch_bounds__(256) void k_wconv(const float* __restrict__ W,
                                               unsigned short* __restrict__ Wt,
                                               int* __restrict__ bsum) {
  if (blockIdx.x == 0 && threadIdx.x <= NBLK) bsum[threadIdx.x] = 0;
  int t = blockIdx.x * 256 + threadIdx.x;     // 128 blocks
  int n = t >> 8, k = t & 255;
  Wt[t] = (unsigned short)f2bf(W[k * OUTD + n]);
}

// ---------- K1: MFMA GEMM -> fp8 Wh table + fused s_src/s_tgt epilogue ----------
// BM=64, BN=128, BK=32, 4 waves. A staged f32->bf16 in LDS [64][40]; B from
// pre-converted Wt [128][40]. Epilogue: acc -> Cs(f32, LDS) -> (a) fp8 row
// store for the gather table, (b) s_src/s_tgt dot products (f32 accuracy).
__global__ __launch_bounds__(256) void k_gemm(const float* __restrict__ x,
                                              const unsigned short* __restrict__ Wt,
                                              const float* __restrict__ a,
                                              unsigned* __restrict__ Whp8,
                                              float* __restrict__ s_src,
                                              float* __restrict__ s_tgt) {
  __shared__ float smem[8448];                 // max(A+B = 15360B, Cs = 33792B)
  short* As = (short*)smem;                    // [64][40] bf16
  short* Bs = As + 64 * 40;                    // [128][40] bf16
  float* Cs = smem;                            // [64][132] f32 (epilogue alias)

  const int tid  = threadIdx.x;
  const int bm   = blockIdx.x * 64;
  const int wave = tid >> 6;                   // 0..3 -> col block wave*32
  const int lane = tid & 63;
  const int l15  = lane & 15;
  const int lg   = lane >> 4;                  // 0..3

  f32x4 acc[4][2];
#pragma unroll
  for (int i = 0; i < 4; i++)
#pragma unroll
    for (int j = 0; j < 2; j++) acc[i][j] = (f32x4){0.f, 0.f, 0.f, 0.f};

  const int arow = tid >> 2, aq = tid & 3;
  long arow_g = bm + arow; if (arow_g >= NN) arow_g = NN - 1;   // clamp, writes guarded
  const float* xp = &x[arow_g * IND + aq * 8];
  short* asp = &As[arow * 40 + aq * 8];
  const int bn = tid >> 1, bh = tid & 1;
  const unsigned short* wtp = &Wt[bn * 256 + bh * 16];
  short* bsp = &Bs[bn * 40 + bh * 16];

  for (int k0 = 0; k0 < IND; k0 += 32) {
    float4 v0 = *(const float4*)(xp + k0);
    float4 v1 = *(const float4*)(xp + k0 + 4);
    short8 apk;
    apk[0] = (short)f2bf(v0.x); apk[1] = (short)f2bf(v0.y);
    apk[2] = (short)f2bf(v0.z); apk[3] = (short)f2bf(v0.w);
    apk[4] = (short)f2bf(v1.x); apk[5] = (short)f2bf(v1.y);
    apk[6] = (short)f2bf(v1.z); apk[7] = (short)f2bf(v1.w);
    *(short8*)asp = apk;
    *(short8*)bsp       = *(const short8*)(wtp + k0);
    *(short8*)(bsp + 8) = *(const short8*)(wtp + k0 + 8);
    __syncthreads();

    short8 af[4], bf[2];
#pragma unroll
    for (int mi = 0; mi < 4; mi++)
      af[mi] = *(const short8*)&As[(mi * 16 + l15) * 40 + lg * 8];
#pragma unroll
    for (int ni = 0; ni < 2; ni++)
      bf[ni] = *(const short8*)&Bs[(wave * 32 + ni * 16 + l15) * 40 + lg * 8];
#pragma unroll
    for (int mi = 0; mi < 4; mi++)
#pragma unroll
      for (int ni = 0; ni < 2; ni++)
        acc[mi][ni] = __builtin_amdgcn_mfma_f32_16x16x32_bf16(
            af[mi], bf[ni], acc[mi][ni], 0, 0, 0);
    __syncthreads();
  }

  // epilogue: acc -> Cs (f32)
#pragma unroll
  for (int mi = 0; mi < 4; mi++)
#pragma unroll
    for (int ni = 0; ni < 2; ni++)
#pragma unroll
      for (int r = 0; r < 4; r++) {
        int row = mi * 16 + lg * 4 + r;
        int col = wave * 32 + ni * 16 + l15;
        Cs[row * 132 + col] = acc[mi][ni][r];
      }
  __syncthreads();

  // (a) fp8 row store: 1024 chunks of 8 f32 -> 8 fp8 bytes
#pragma unroll
  for (int i = 0; i < 4; i++) {
    int f = tid + i * 256;
    int nd = f >> 4, seg = f & 15;
    long gnode = bm + nd;
    if (gnode < NN) {
      float4 c0 = *(const float4*)&Cs[nd * 132 + seg * 8];
      float4 c1 = *(const float4*)&Cs[nd * 132 + seg * 8 + 4];
      int u0 = __builtin_amdgcn_cvt_pk_fp8_f32(c0.x, c0.y, 0, false);
      u0     = __builtin_amdgcn_cvt_pk_fp8_f32(c0.z, c0.w, u0, true);
      int u1 = __builtin_amdgcn_cvt_pk_fp8_f32(c1.x, c1.y, 0, false);
      u1     = __builtin_amdgcn_cvt_pk_fp8_f32(c1.z, c1.w, u1, true);
      *(uint2*)&Whp8[gnode * 32 + seg * 2] = make_uint2((unsigned)u0, (unsigned)u1);
    }
  }

  // (b) fused s_src/s_tgt: 4 threads per node, 32 cols each, shfl_xor reduce
  {
    const int nd = tid >> 2, p = tid & 3;
    float p1 = 0.f, p2 = 0.f;
    const float* crow = &Cs[nd * 132 + p * 32];
#pragma unroll
    for (int k = 0; k < 32; k++) {
      float c = crow[k];
      p1 = fmaf(c, a[p * 32 + k], p1);
      p2 = fmaf(c, a[128 + p * 32 + k], p2);
    }
    p1 += __shfl_xor(p1, 1); p1 += __shfl_xor(p1, 2);
    p2 += __shfl_xor(p2, 1); p2 += __shfl_xor(p2, 2);
    long gnode = bm + nd;
    if (p == 0 && gnode < NN) { s_src[gnode] = p1; s_tgt[gnode] = p2; }
  }
}

// ---------- K3: scores + coarse-bucket histogram + per-block softmax stats ----------
__global__ __launch_bounds__(256) void k_score(const int* __restrict__ ei,
                                               const float* __restrict__ s_src,
                                               const float* __restrict__ s_tgt,
                                               float* __restrict__ scores,
                                               int* __restrict__ bsum,
                                               float* __restrict__ bmax,
                                               float* __restrict__ bsexp) {
  __shared__ int bh[NBLK];
  __shared__ float red[4];
  __shared__ float bmx;
  const int tid = threadIdx.x;
  const long eb = (long)blockIdx.x * 4096;
  if (tid < NBLK) bh[tid] = 0;
  __syncthreads();

  float scv[16];
  float mx = -1e30f;
#pragma unroll
  for (int i = 0; i < 16; i++) {
    long e = eb + i * 256 + tid;
    float sc = -1e30f;
    if (e < NE) {
      int s = ei[e];
      int t = ei[NE + e];
      float v = s_src[s] + s_tgt[t];
      sc = v > 0.f ? v : 0.2f * v;              // leaky_relu(0.2)
      scores[e] = sc;
      atomicAdd(&bh[t >> 8], 1);
    }
    scv[i] = sc;
    mx = fmaxf(mx, sc);
  }
  __syncthreads();
  if (tid < NBLK) {
    int c = bh[tid];
    if (c) atomicAdd(&bsum[tid], c);
  }
  // block max
#pragma unroll
  for (int off = 32; off; off >>= 1) mx = fmaxf(mx, __shfl_down(mx, off));
  int w = tid >> 6, lane = tid & 63;
  if (lane == 0) red[w] = mx;
  __syncthreads();
  if (tid == 0) bmx = fmaxf(fmaxf(red[0], red[1]), fmaxf(red[2], red[3]));
  __syncthreads();
  const float M = bmx;
  float s = 0.f;
#pragma unroll
  for (int i = 0; i < 16; i++) s += __expf(scv[i] - M);
#pragma unroll
  for (int off = 32; off; off >>= 1) s += __shfl_down(s, off);
  if (lane == 0) red[w] = s;
  __syncthreads();
  if (tid == 0) {
    bmax[blockIdx.x] = M;
    bsexp[blockIdx.x] = red[0] + red[1] + red[2] + red[3];
  }
}

// ---------- K5: scan bucket sums + combine softmax stats (1 block) ----------
__global__ __launch_bounds__(256) void k_scan2(int* __restrict__ bsum,
                                               int* __restrict__ bcursor,
                                               const float* __restrict__ bmax,
                                               const float* __restrict__ bsexp,
                                               float* __restrict__ softstat) {
  __shared__ int s[256];
  __shared__ float fred[256];
  int tid = threadIdx.x;
  int v = (tid < NBLK) ? bsum[tid] : 0;
  s[tid] = v;
  __syncthreads();
  for (int off = 1; off < 256; off <<= 1) {
    int t = (tid >= off) ? s[tid - off] : 0;
    __syncthreads();
    s[tid] += t;
    __syncthreads();
  }
  int excl = (tid == 0) ? 0 : s[tid - 1];
  if (tid <= NBLK) bsum[tid] = excl;          // bsum[NBLK] = NE sentinel
  if (tid < NBLK) bcursor[tid] = excl;

  float m = (tid < NBLK) ? bmax[tid] : -1e30f;
  fred[tid] = m;
  __syncthreads();
  for (int off = 128; off; off >>= 1) {
    if (tid < off) fred[tid] = fmaxf(fred[tid], fred[tid + off]);
    __syncthreads();
  }
  const float M = fred[0];
  __syncthreads();
  float se = (tid < NBLK) ? bsexp[tid] * __expf(bmax[tid] - M) : 0.f;
  fred[tid] = se;
  __syncthreads();
  for (int off = 128; off; off >>= 1) {
    if (tid < off) fred[tid] += fred[tid + off];
    __syncthreads();
  }
  if (tid == 0) { softstat[0] = M; softstat[1] = fred[0]; }
}

// ---------- K6a: coarse bucket scatter (block-owned chunks, XCD-local lines) ----------
__global__ __launch_bounds__(256) void k_binA(const int* __restrict__ ei,
                                              const float* __restrict__ scores,
                                              const float* __restrict__ softstat,
                                              int* __restrict__ bcursor,
                                              int2* __restrict__ recs_mid) {
  __shared__ int bh[NBLK];
  __shared__ int gbase[NBLK];
  const int tid = threadIdx.x;
  const long eb = (long)blockIdx.x * 4096;
  if (tid < NBLK) bh[tid] = 0;
  __syncthreads();

  float m = softstat[0];
  float inv = 1.0f / softstat[1];

  int tv[16]; int sv[16]; float av[16];
#pragma unroll
  for (int i = 0; i < 16; i++) {
    long e = eb + i * 256 + tid;
    if (e < NE) {
      sv[i] = ei[e];
      tv[i] = ei[NE + e];
      av[i] = __expf(scores[e] - m) * inv;
      atomicAdd(&bh[tv[i] >> 8], 1);
    } else {
      tv[i] = -1;
    }
  }
  __syncthreads();
  if (tid < NBLK) {
    int c = bh[tid];
    gbase[tid] = (c > 0) ? atomicAdd(&bcursor[tid], c) : 0;
    bh[tid] = 0;                               // reuse as local cursor
  }
  __syncthreads();
#pragma unroll
  for (int i = 0; i < 16; i++) {
    if (tv[i] >= 0) {
      int b = tv[i] >> 8;
      int off = atomicAdd(&bh[b], 1);
      int pos = gbase[b] + off;
      recs_mid[pos] = make_int2(sv[i] | ((tv[i] & 255) << 16),
                                __float_as_int(av[i]));
    }
  }
}

// ---------- K6b: in-bucket LDS sort by target + coalesced write + offs emit ----------
__global__ __launch_bounds__(256) void k_sortB(const int* __restrict__ bsum,
                                               const int2* __restrict__ recs_mid,
                                               int2* __restrict__ recs,
                                               int* __restrict__ offs) {
  __shared__ int h[256], sc[256], cur[256];
  __shared__ int2 srt[BCAP];
  const int tid = threadIdx.x;
  const int b = blockIdx.x;
  const int start = bsum[b];
  const int m = bsum[b + 1] - start;

  h[tid] = 0;
  __syncthreads();
  for (int i = tid; i < m; i += 256) {
    int2 r = recs_mid[start + i];
    atomicAdd(&h[(r.x >> 16) & 255], 1);
  }
  __syncthreads();
  sc[tid] = h[tid];
  __syncthreads();
  for (int off = 1; off < 256; off <<= 1) {
    int t = (tid >= off) ? sc[tid - off] : 0;
    __syncthreads();
    sc[tid] += t;
    __syncthreads();
  }
  int excl = sc[tid] - h[tid];
  cur[tid] = excl;
  offs[b * 256 + tid] = start + excl;          // global per-target offsets
  __syncthreads();
  for (int i = tid; i < m; i += 256) {
    int2 r = recs_mid[start + i];
    int tl = (r.x >> 16) & 255;
    int p = atomicAdd(&cur[tl], 1);
    if (p < BCAP) srt[p] = make_int2(r.x & 0xffff, r.y);
  }
  __syncthreads();
  for (int i = tid; i < m; i += 256)
    recs[start + i] = srt[i];                  // fully coalesced
}

// ---------- K7: gather-sum per target node (one wave per node, fp8 rows) ----------
__global__ __launch_bounds__(256) void k_gather(const int* __restrict__ offs,
                                                const int2* __restrict__ recs,
                                                const unsigned short* __restrict__ Whp8,
                                                float* __restrict__ xnew) {
  int wid = (blockIdx.x * 256 + threadIdx.x) >> 6;    // 12500*4 = NN waves
  int lane = threadIdx.x & 63;
  int start = offs[wid];
  int n = offs[wid + 1] - start;
  float2 acc = make_float2(0.f, 0.f);
  for (int base = 0; base < n; base += 64) {
    int m = n - base; if (m > 64) m = 64;
    int li = lane < m ? lane : m - 1;
    int2 r = recs[start + base + li];                 // coalesced chunk load
    for (int i = 0; i < m; i += 4) {                  // 4 row-loads in flight
      int sj[4]; float aj[4];
#pragma unroll
      for (int j = 0; j < 4; j++) {
        int idx = i + j;
        sj[j] = __shfl(r.x, idx);
        float al = __int_as_float(__shfl(r.y, idx));
        aj[j] = (idx < m) ? al : 0.f;
      }
      unsigned short v[4];
#pragma unroll
      for (int j = 0; j < 4; j++)
        v[j] = Whp8[(long)sj[j] * 64 + lane];         // 2 fp8 = cols 2lane,2lane+1
#pragma unroll
      for (int j = 0; j < 4; j++) {
        f32x2 w = __builtin_amdgcn_cvt_pk_f32_fp8((int)(unsigned)v[j], false);
        acc.x = fmaf(aj[j], w[0], acc.x);
        acc.y = fmaf(aj[j], w[1], acc.y);
      }
    }
  }
  ((float2*)xnew)[(long)wid * 64 + lane] = acc;
}

// ---------- K8: fused MLP head as register-tiled GEMM ----------
__global__ __launch_bounds__(256) void k_mlp(const float* __restrict__ xnew,
                                             const float* __restrict__ W1,
                                             const float* __restrict__ b1,
                                             const float* __restrict__ W2,
                                             const float* __restrict__ b2,
                                             float* __restrict__ evid) {
  __shared__ float xs[64][132];     // row stride 132 (528B, 16B-aligned)
  __shared__ float w1s[128][64];    // [k][hid]
  const int tid = threadIdx.x;
  const int nb = blockIdx.x * 64;
  const int ty = tid >> 4;          // 0..15 -> nodes ty*4..+3
  const int tx = tid & 15;          // 0..15 -> hid tx*4..+3

#pragma unroll
  for (int i = 0; i < 8; i++) {
    int f = tid + i * 256;
    int n = f >> 5;
    int kq = (f & 31) * 4;
    int row = nb + n; if (row >= NN) row = NN - 1;
    *(float4*)&xs[n][kq] = *(const float4*)&xnew[(long)row * OUTD + kq];
  }
#pragma unroll
  for (int i = 0; i < 8; i++) {
    int f = tid + i * 256;
    int kr = f >> 4;
    int cq = (f & 15) * 4;
    *(float4*)&w1s[kr][cq] = *(const float4*)&W1[kr * HIDD + cq];
  }
  __syncthreads();

  float acc[4][4];
#pragma unroll
  for (int i = 0; i < 4; i++)
#pragma unroll
    for (int j = 0; j < 4; j++) acc[i][j] = 0.f;

#pragma unroll 2
  for (int k0 = 0; k0 < OUTD; k0 += 4) {
    float4 xv[4], wv[4];
#pragma unroll
    for (int i = 0; i < 4; i++) xv[i] = *(const float4*)&xs[ty * 4 + i][k0];
#pragma unroll
    for (int d = 0; d < 4; d++) wv[d] = *(const float4*)&w1s[k0 + d][tx * 4];
#pragma unroll
    for (int i = 0; i < 4; i++) {
      float xr[4] = {xv[i].x, xv[i].y, xv[i].z, xv[i].w};
#pragma unroll
      for (int d = 0; d < 4; d++) {
        float wr[4] = {wv[d].x, wv[d].y, wv[d].z, wv[d].w};
#pragma unroll
        for (int j = 0; j < 4; j++)
          acc[i][j] = fmaf(xr[d], wr[j], acc[i][j]);
      }
    }
  }

  float b1r[4], w2r[4][3];
#pragma unroll
  for (int j = 0; j < 4; j++) {
    int jg = tx * 4 + j;
    b1r[j] = b1[jg];
    w2r[j][0] = W2[jg * 3 + 0];
    w2r[j][1] = W2[jg * 3 + 1];
    w2r[j][2] = W2[jg * 3 + 2];
  }
#pragma unroll
  for (int i = 0; i < 4; i++) {
    float p0 = 0.f, p1 = 0.f, p2 = 0.f;
#pragma unroll
    for (int j = 0; j < 4; j++) {
      float h = fmaxf(acc[i][j] + b1r[j], 0.f);
      p0 = fmaf(h, w2r[j][0], p0);
      p1 = fmaf(h, w2r[j][1], p1);
      p2 = fmaf(h, w2r[j][2], p2);
    }
#pragma unroll
    for (int m = 1; m < 16; m <<= 1) {
      p0 += __shfl_xor(p0, m);
      p1 += __shfl_xor(p1, m);
      p2 += __shfl_xor(p2, m);
    }
    if (tx == 0) {
      int n = nb + ty * 4 + i;
      if (n < NN) {
        float e0 = p0 + b2[0], e1 = p1 + b2[1], e2 = p2 + b2[2];
        float s0 = e0 > 20.f ? e0 : log1pf(expf(e0));
        float s1 = e1 > 20.f ? e1 : log1pf(expf(e1));
        float s2 = e2 > 20.f ? e2 : log1pf(expf(e2));
        evid[(long)n * 3 + 0] = s0 + 1.0f;
        evid[(long)n * 3 + 1] = s1 + 1.0f;
        evid[(long)n * 3 + 2] = s2 + 1.0f;
      }
    }
  }
}

extern "C" void kernel_launch(void* const* d_in, const int* in_sizes, int n_in,
                              void* d_out, int out_size, void* d_ws, size_t ws_size,
                              hipStream_t stream) {
  const float* x   = (const float*)d_in[0];
  const int*   ei  = (const int*)d_in[1];
  const float* W   = (const float*)d_in[2];
  const float* a   = (const float*)d_in[3];
  const float* W1  = (const float*)d_in[4];
  const float* b1  = (const float*)d_in[5];
  const float* W2  = (const float*)d_in[6];
  const float* b2  = (const float*)d_in[7];

  float* xnew = (float*)d_out;                       // [NN*OUTD]
  float* evid = (float*)d_out + (size_t)NN * OUTD;   // [NN*3]

  float* wsf = (float*)d_ws;
  unsigned* Whp8     = (unsigned*)wsf;               // 1,600,000 u32 (6.4 MB fp8 Wh)
  float*    s_src    = wsf + 1600000;                //    50,000 f
  float*    s_tgt    = wsf + 1650000;                //    50,000 f
  float*    scores   = wsf + 1700000;                //   800,000 f
  int2*     recs_mid = (int2*)(wsf + 2500000);       //   800,000 int2
  int2*     recs     = (int2*)(wsf + 4100000);       //   800,000 int2
  int*      offs     = (int*)(wsf + 5700000);        //    50,200 i (incl sentinel)
  int*      bsum     = (int*)(wsf + 5750204);        //       197 i
  int*      bcursor  = (int*)(wsf + 5750404);        //       196 i
  float*    bmax     = wsf + 5750600;                //       196 f
  float*    bsexp    = wsf + 5750796;                //       196 f
  float*    softstat = wsf + 5750992;                //         2 f
  unsigned short* Wt = (unsigned short*)(wsf + 5751000);  // 32,768 bf16 (end ~23 MB)

  k_wconv<<<128, 256, 0, stream>>>(W, Wt, bsum);
  k_gemm<<<(NN + 63) / 64, 256, 0, stream>>>(x, Wt, a, Whp8, s_src, s_tgt);
  k_score<<<NBLK, 256, 0, stream>>>(ei, s_src, s_tgt, scores, bsum, bmax, bsexp);
  k_scan2<<<1, 256, 0, stream>>>(bsum, bcursor, bmax, bsexp, softstat);
  k_binA<<<NBLK, 256, 0, stream>>>(ei, scores, softstat, bcursor, recs_mid);
  k_sortB<<<NBLK, 256, 0, stream>>>(bsum, recs_mid, recs, offs);
  k_gather<<<NN / 4, 256, 0, stream>>>(offs, recs, (const unsigned short*)Whp8, xnew);
  k_mlp<<<(NN + 63) / 64, 256, 0, stream>>>(xnew, W1, b1, W2, b2, evid);
}

// Round 11
// 128.509 us; speedup vs baseline: 6.9483x; 1.0994x over previous
//
#include <hip/hip_runtime.h>
#include <math.h>

#define NN 50000
#define NE 800000
#define IND 256
#define OUTD 128
#define HIDD 64
#define NBLK 196   // number of 256-target coarse buckets (196*256 = 50176 >= NN)
#define BCAP 6144  // fixed bucket capacity (mean 4082, ~32 sigma headroom)

typedef __attribute__((ext_vector_type(8))) short short8;   // 8 bf16 (4 VGPR)
typedef __attribute__((ext_vector_type(4))) float f32x4;    // MFMA acc
typedef __attribute__((ext_vector_type(2))) float f32x2;    // fp8 cvt result

// ---------- helpers ----------
static __device__ __forceinline__ unsigned f2bf(float f) {       // RNE f32->bf16 bits
  unsigned u = __float_as_uint(f);
  return (u + 0x7fffu + ((u >> 16) & 1u)) >> 16;
}

// ---------- K0: Wt[n][k] = bf16(W[k][n]) + (block 0) init bucket cursors ----------
__global__ __launch_bounds__(256) void k_wconv(const float* __restrict__ W,
                                               unsigned short* __restrict__ Wt,
                                               int* __restrict__ bcursor) {
  if (blockIdx.x == 0 && threadIdx.x < NBLK)
    bcursor[threadIdx.x] = threadIdx.x * BCAP;       // fixed-capacity bases
  int t = blockIdx.x * 256 + threadIdx.x;     // 128 blocks
  int n = t >> 8, k = t & 255;
  Wt[t] = (unsigned short)f2bf(W[k * OUTD + n]);
}

// ---------- K1: MFMA GEMM -> fp8 Wh table + fused s_src/s_tgt epilogue ----------
__global__ __launch_bounds__(256) void k_gemm(const float* __restrict__ x,
                                              const unsigned short* __restrict__ Wt,
                                              const float* __restrict__ a,
                                              unsigned* __restrict__ Whp8,
                                              float* __restrict__ s_src,
                                              float* __restrict__ s_tgt) {
  __shared__ float smem[8448];                 // max(A+B = 15360B, Cs = 33792B)
  short* As = (short*)smem;                    // [64][40] bf16
  short* Bs = As + 64 * 40;                    // [128][40] bf16
  float* Cs = smem;                            // [64][132] f32 (epilogue alias)

  const int tid  = threadIdx.x;
  const int bm   = blockIdx.x * 64;
  const int wave = tid >> 6;                   // 0..3 -> col block wave*32
  const int lane = tid & 63;
  const int l15  = lane & 15;
  const int lg   = lane >> 4;                  // 0..3

  f32x4 acc[4][2];
#pragma unroll
  for (int i = 0; i < 4; i++)
#pragma unroll
    for (int j = 0; j < 2; j++) acc[i][j] = (f32x4){0.f, 0.f, 0.f, 0.f};

  const int arow = tid >> 2, aq = tid & 3;
  long arow_g = bm + arow; if (arow_g >= NN) arow_g = NN - 1;   // clamp, writes guarded
  const float* xp = &x[arow_g * IND + aq * 8];
  short* asp = &As[arow * 40 + aq * 8];
  const int bn = tid >> 1, bh = tid & 1;
  const unsigned short* wtp = &Wt[bn * 256 + bh * 16];
  short* bsp = &Bs[bn * 40 + bh * 16];

  for (int k0 = 0; k0 < IND; k0 += 32) {
    float4 v0 = *(const float4*)(xp + k0);
    float4 v1 = *(const float4*)(xp + k0 + 4);
    short8 apk;
    apk[0] = (short)f2bf(v0.x); apk[1] = (short)f2bf(v0.y);
    apk[2] = (short)f2bf(v0.z); apk[3] = (short)f2bf(v0.w);
    apk[4] = (short)f2bf(v1.x); apk[5] = (short)f2bf(v1.y);
    apk[6] = (short)f2bf(v1.z); apk[7] = (short)f2bf(v1.w);
    *(short8*)asp = apk;
    *(short8*)bsp       = *(const short8*)(wtp + k0);
    *(short8*)(bsp + 8) = *(const short8*)(wtp + k0 + 8);
    __syncthreads();

    short8 af[4], bf[2];
#pragma unroll
    for (int mi = 0; mi < 4; mi++)
      af[mi] = *(const short8*)&As[(mi * 16 + l15) * 40 + lg * 8];
#pragma unroll
    for (int ni = 0; ni < 2; ni++)
      bf[ni] = *(const short8*)&Bs[(wave * 32 + ni * 16 + l15) * 40 + lg * 8];
#pragma unroll
    for (int mi = 0; mi < 4; mi++)
#pragma unroll
      for (int ni = 0; ni < 2; ni++)
        acc[mi][ni] = __builtin_amdgcn_mfma_f32_16x16x32_bf16(
            af[mi], bf[ni], acc[mi][ni], 0, 0, 0);
    __syncthreads();
  }

  // epilogue: acc -> Cs (f32)
#pragma unroll
  for (int mi = 0; mi < 4; mi++)
#pragma unroll
    for (int ni = 0; ni < 2; ni++)
#pragma unroll
      for (int r = 0; r < 4; r++) {
        int row = mi * 16 + lg * 4 + r;
        int col = wave * 32 + ni * 16 + l15;
        Cs[row * 132 + col] = acc[mi][ni][r];
      }
  __syncthreads();

  // (a) fp8 row store: 1024 chunks of 8 f32 -> 8 fp8 bytes
#pragma unroll
  for (int i = 0; i < 4; i++) {
    int f = tid + i * 256;
    int nd = f >> 4, seg = f & 15;
    long gnode = bm + nd;
    if (gnode < NN) {
      float4 c0 = *(const float4*)&Cs[nd * 132 + seg * 8];
      float4 c1 = *(const float4*)&Cs[nd * 132 + seg * 8 + 4];
      int u0 = __builtin_amdgcn_cvt_pk_fp8_f32(c0.x, c0.y, 0, false);
      u0     = __builtin_amdgcn_cvt_pk_fp8_f32(c0.z, c0.w, u0, true);
      int u1 = __builtin_amdgcn_cvt_pk_fp8_f32(c1.x, c1.y, 0, false);
      u1     = __builtin_amdgcn_cvt_pk_fp8_f32(c1.z, c1.w, u1, true);
      *(uint2*)&Whp8[gnode * 32 + seg * 2] = make_uint2((unsigned)u0, (unsigned)u1);
    }
  }

  // (b) fused s_src/s_tgt: 4 threads per node, 32 cols each, shfl_xor reduce
  {
    const int nd = tid >> 2, p = tid & 3;
    float p1 = 0.f, p2 = 0.f;
    const float* crow = &Cs[nd * 132 + p * 32];
#pragma unroll
    for (int k = 0; k < 32; k++) {
      float c = crow[k];
      p1 = fmaf(c, a[p * 32 + k], p1);
      p2 = fmaf(c, a[128 + p * 32 + k], p2);
    }
    p1 += __shfl_xor(p1, 1); p1 += __shfl_xor(p1, 2);
    p2 += __shfl_xor(p2, 1); p2 += __shfl_xor(p2, 2);
    long gnode = bm + nd;
    if (p == 0 && gnode < NN) { s_src[gnode] = p1; s_tgt[gnode] = p2; }
  }
}

// ---------- K3: scores + DIRECT binning (fixed-capacity buckets) + block stats ----------
// 196 blocks x 4096 edges. Records carry raw score bits (alpha needs global
// stats, not yet known). Block-owned chunk reservation keeps record-line
// writes XCD-local. Emits bmax/bsexp per block; no scores array, no bsum.
__global__ __launch_bounds__(256) void k_score(const int* __restrict__ ei,
                                               const float* __restrict__ s_src,
                                               const float* __restrict__ s_tgt,
                                               int* __restrict__ bcursor,
                                               int2* __restrict__ recs_mid,
                                               float* __restrict__ bmax,
                                               float* __restrict__ bsexp) {
  __shared__ int bh[NBLK];
  __shared__ int gbase[NBLK];
  __shared__ float red[4];
  __shared__ float bmx;
  const int tid = threadIdx.x;
  const long eb = (long)blockIdx.x * 4096;
  if (tid < NBLK) bh[tid] = 0;
  __syncthreads();

  int sv[16]; int tv[16]; float scv[16];
  float mx = -1e30f;
#pragma unroll
  for (int i = 0; i < 16; i++) {
    long e = eb + i * 256 + tid;
    float sc = -1e30f;
    if (e < NE) {
      int s = ei[e];
      int t = ei[NE + e];
      float v = s_src[s] + s_tgt[t];
      sc = v > 0.f ? v : 0.2f * v;              // leaky_relu(0.2)
      sv[i] = s; tv[i] = t;
      atomicAdd(&bh[t >> 8], 1);
    } else {
      tv[i] = -1;
    }
    scv[i] = sc;
    mx = fmaxf(mx, sc);
  }
  __syncthreads();
  if (tid < NBLK) {
    int c = bh[tid];
    gbase[tid] = (c > 0) ? atomicAdd(&bcursor[tid], c) : 0;
    bh[tid] = 0;                               // reuse as local cursor
  }
  __syncthreads();
#pragma unroll
  for (int i = 0; i < 16; i++) {
    if (tv[i] >= 0) {
      int b = tv[i] >> 8;
      int off = atomicAdd(&bh[b], 1);
      recs_mid[gbase[b] + off] = make_int2(sv[i] | ((tv[i] & 255) << 16),
                                           __float_as_int(scv[i]));
    }
  }

  // per-block softmax stats
#pragma unroll
  for (int off = 32; off; off >>= 1) mx = fmaxf(mx, __shfl_down(mx, off));
  int w = tid >> 6, lane = tid & 63;
  if (lane == 0) red[w] = mx;
  __syncthreads();
  if (tid == 0) bmx = fmaxf(fmaxf(red[0], red[1]), fmaxf(red[2], red[3]));
  __syncthreads();
  const float M = bmx;
  float s = 0.f;
#pragma unroll
  for (int i = 0; i < 16; i++) s += __expf(scv[i] - M);   // invalid lanes -> 0
#pragma unroll
  for (int off = 32; off; off >>= 1) s += __shfl_down(s, off);
  if (lane == 0) red[w] = s;
  __syncthreads();
  if (tid == 0) {
    bmax[blockIdx.x] = M;
    bsexp[blockIdx.x] = red[0] + red[1] + red[2] + red[3];
  }
}

// ---------- K5: combine per-block softmax stats (1 block) ----------
__global__ __launch_bounds__(256) void k_stats(const float* __restrict__ bmax,
                                               const float* __restrict__ bsexp,
                                               float* __restrict__ softstat) {
  __shared__ float fred[256];
  int tid = threadIdx.x;
  float m = (tid < NBLK) ? bmax[tid] : -1e30f;
  fred[tid] = m;
  __syncthreads();
  for (int off = 128; off; off >>= 1) {
    if (tid < off) fred[tid] = fmaxf(fred[tid], fred[tid + off]);
    __syncthreads();
  }
  const float M = fred[0];
  __syncthreads();
  float se = (tid < NBLK) ? bsexp[tid] * __expf(bmax[tid] - M) : 0.f;
  fred[tid] = se;
  __syncthreads();
  for (int off = 128; off; off >>= 1) {
    if (tid < off) fred[tid] += fred[tid + off];
    __syncthreads();
  }
  if (tid == 0) { softstat[0] = M; softstat[1] = fred[0]; }
}

// ---------- K6: in-bucket LDS sort by target + sc->alpha + offs/cnt emit ----------
// One block per bucket. m = bcursor[b] - b*BCAP. Final recs stay in the
// fixed-capacity layout; offs[t] = b*BCAP + local_excl, cnt[t] = local count.
__global__ __launch_bounds__(256) void k_sortB(const int* __restrict__ bcursor,
                                               const int2* __restrict__ recs_mid,
                                               const float* __restrict__ softstat,
                                               int2* __restrict__ recs,
                                               int* __restrict__ offs,
                                               int* __restrict__ cnt) {
  __shared__ int h[256], sc[256], cur[256];
  __shared__ int2 srt[BCAP];
  const int tid = threadIdx.x;
  const int b = blockIdx.x;
  const int base = b * BCAP;
  const int m = bcursor[b] - base;
  const float M = softstat[0];
  const float inv = 1.0f / softstat[1];

  h[tid] = 0;
  __syncthreads();
  for (int i = tid; i < m; i += 256) {
    int2 r = recs_mid[base + i];
    atomicAdd(&h[(r.x >> 16) & 255], 1);
  }
  __syncthreads();
  sc[tid] = h[tid];
  __syncthreads();
  for (int off = 1; off < 256; off <<= 1) {
    int t = (tid >= off) ? sc[tid - off] : 0;
    __syncthreads();
    sc[tid] += t;
    __syncthreads();
  }
  int excl = sc[tid] - h[tid];
  cur[tid] = excl;
  offs[b * 256 + tid] = base + excl;           // global per-target offsets
  cnt[b * 256 + tid] = h[tid];
  __syncthreads();
  for (int i = tid; i < m; i += 256) {
    int2 r = recs_mid[base + i];
    int tl = (r.x >> 16) & 255;
    int p = atomicAdd(&cur[tl], 1);
    float al = __expf(__int_as_float(r.y) - M) * inv;
    if (p < BCAP) srt[p] = make_int2(r.x & 0xffff, __float_as_int(al));
  }
  __syncthreads();
  for (int i = tid; i < m; i += 256)
    recs[base + i] = srt[i];                   // coalesced
}

// ---------- K7: gather-sum per target node (one wave per node, fp8 rows) ----------
__global__ __launch_bounds__(256) void k_gather(const int* __restrict__ offs,
                                                const int* __restrict__ cnt,
                                                const int2* __restrict__ recs,
                                                const unsigned short* __restrict__ Whp8,
                                                float* __restrict__ xnew) {
  int wid = (blockIdx.x * 256 + threadIdx.x) >> 6;    // 12500*4 = NN waves
  int lane = threadIdx.x & 63;
  int start = offs[wid];
  int n = cnt[wid];
  float2 acc = make_float2(0.f, 0.f);
  for (int base = 0; base < n; base += 64) {
    int m = n - base; if (m > 64) m = 64;
    int li = lane < m ? lane : m - 1;
    int2 r = recs[start + base + li];                 // coalesced chunk load
    for (int i = 0; i < m; i += 4) {                  // 4 row-loads in flight
      int sj[4]; float aj[4];
#pragma unroll
      for (int j = 0; j < 4; j++) {
        int idx = i + j;
        sj[j] = __shfl(r.x, idx);
        float al = __int_as_float(__shfl(r.y, idx));
        aj[j] = (idx < m) ? al : 0.f;
      }
      unsigned short v[4];
#pragma unroll
      for (int j = 0; j < 4; j++)
        v[j] = Whp8[(long)sj[j] * 64 + lane];         // 2 fp8 = cols 2lane,2lane+1
#pragma unroll
      for (int j = 0; j < 4; j++) {
        f32x2 w = __builtin_amdgcn_cvt_pk_f32_fp8((int)(unsigned)v[j], false);
        acc.x = fmaf(aj[j], w[0], acc.x);
        acc.y = fmaf(aj[j], w[1], acc.y);
      }
    }
  }
  ((float2*)xnew)[(long)wid * 64 + lane] = acc;
}

// ---------- K8: fused MLP head as register-tiled GEMM ----------
__global__ __launch_bounds__(256) void k_mlp(const float* __restrict__ xnew,
                                             const float* __restrict__ W1,
                                             const float* __restrict__ b1,
                                             const float* __restrict__ W2,
                                             const float* __restrict__ b2,
                                             float* __restrict__ evid) {
  __shared__ float xs[64][132];     // row stride 132 (528B, 16B-aligned)
  __shared__ float w1s[128][64];    // [k][hid]
  const int tid = threadIdx.x;
  const int nb = blockIdx.x * 64;
  const int ty = tid >> 4;          // 0..15 -> nodes ty*4..+3
  const int tx = tid & 15;          // 0..15 -> hid tx*4..+3

#pragma unroll
  for (int i = 0; i < 8; i++) {
    int f = tid + i * 256;
    int n = f >> 5;
    int kq = (f & 31) * 4;
    int row = nb + n; if (row >= NN) row = NN - 1;
    *(float4*)&xs[n][kq] = *(const float4*)&xnew[(long)row * OUTD + kq];
  }
#pragma unroll
  for (int i = 0; i < 8; i++) {
    int f = tid + i * 256;
    int kr = f >> 4;
    int cq = (f & 15) * 4;
    *(float4*)&w1s[kr][cq] = *(const float4*)&W1[kr * HIDD + cq];
  }
  __syncthreads();

  float acc[4][4];
#pragma unroll
  for (int i = 0; i < 4; i++)
#pragma unroll
    for (int j = 0; j < 4; j++) acc[i][j] = 0.f;

#pragma unroll 2
  for (int k0 = 0; k0 < OUTD; k0 += 4) {
    float4 xv[4], wv[4];
#pragma unroll
    for (int i = 0; i < 4; i++) xv[i] = *(const float4*)&xs[ty * 4 + i][k0];
#pragma unroll
    for (int d = 0; d < 4; d++) wv[d] = *(const float4*)&w1s[k0 + d][tx * 4];
#pragma unroll
    for (int i = 0; i < 4; i++) {
      float xr[4] = {xv[i].x, xv[i].y, xv[i].z, xv[i].w};
#pragma unroll
      for (int d = 0; d < 4; d++) {
        float wr[4] = {wv[d].x, wv[d].y, wv[d].z, wv[d].w};
#pragma unroll
        for (int j = 0; j < 4; j++)
          acc[i][j] = fmaf(xr[d], wr[j], acc[i][j]);
      }
    }
  }

  float b1r[4], w2r[4][3];
#pragma unroll
  for (int j = 0; j < 4; j++) {
    int jg = tx * 4 + j;
    b1r[j] = b1[jg];
    w2r[j][0] = W2[jg * 3 + 0];
    w2r[j][1] = W2[jg * 3 + 1];
    w2r[j][2] = W2[jg * 3 + 2];
  }
#pragma unroll
  for (int i = 0; i < 4; i++) {
    float p0 = 0.f, p1 = 0.f, p2 = 0.f;
#pragma unroll
    for (int j = 0; j < 4; j++) {
      float h = fmaxf(acc[i][j] + b1r[j], 0.f);
      p0 = fmaf(h, w2r[j][0], p0);
      p1 = fmaf(h, w2r[j][1], p1);
      p2 = fmaf(h, w2r[j][2], p2);
    }
#pragma unroll
    for (int m = 1; m < 16; m <<= 1) {
      p0 += __shfl_xor(p0, m);
      p1 += __shfl_xor(p1, m);
      p2 += __shfl_xor(p2, m);
    }
    if (tx == 0) {
      int n = nb + ty * 4 + i;
      if (n < NN) {
        float e0 = p0 + b2[0], e1 = p1 + b2[1], e2 = p2 + b2[2];
        float s0 = e0 > 20.f ? e0 : log1pf(expf(e0));
        float s1 = e1 > 20.f ? e1 : log1pf(expf(e1));
        float s2 = e2 > 20.f ? e2 : log1pf(expf(e2));
        evid[(long)n * 3 + 0] = s0 + 1.0f;
        evid[(long)n * 3 + 1] = s1 + 1.0f;
        evid[(long)n * 3 + 2] = s2 + 1.0f;
      }
    }
  }
}

extern "C" void kernel_launch(void* const* d_in, const int* in_sizes, int n_in,
                              void* d_out, int out_size, void* d_ws, size_t ws_size,
                              hipStream_t stream) {
  const float* x   = (const float*)d_in[0];
  const int*   ei  = (const int*)d_in[1];
  const float* W   = (const float*)d_in[2];
  const float* a   = (const float*)d_in[3];
  const float* W1  = (const float*)d_in[4];
  const float* b1  = (const float*)d_in[5];
  const float* W2  = (const float*)d_in[6];
  const float* b2  = (const float*)d_in[7];

  float* xnew = (float*)d_out;                       // [NN*OUTD]
  float* evid = (float*)d_out + (size_t)NN * OUTD;   // [NN*3]

  float* wsf = (float*)d_ws;
  unsigned* Whp8     = (unsigned*)wsf;               // 1,600,000 u32 (6.4 MB fp8 Wh)
  float*    s_src    = wsf + 1600000;                //    50,000 f
  float*    s_tgt    = wsf + 1650000;                //    50,000 f
  int2*     recs_mid = (int2*)(wsf + 1700000);       // 196*6144 = 1,204,224 int2
  int2*     recs     = (int2*)(wsf + 4108448);       // 1,204,224 int2
  int*      offs     = (int*)(wsf + 6516896);        //    50,176 i
  int*      cnt      = (int*)(wsf + 6567328);        //    50,176 i
  int*      bcursor  = (int*)(wsf + 6617504);        //       196 i
  float*    bmax     = wsf + 6617700;                //       196 f
  float*    bsexp    = wsf + 6617896;                //       196 f
  float*    softstat = wsf + 6618092;                //         2 f
  unsigned short* Wt = (unsigned short*)(wsf + 6618096);  // 32,768 bf16 (16B-aligned, end ~26.5 MB)

  k_wconv<<<128, 256, 0, stream>>>(W, Wt, bcursor);
  k_gemm<<<(NN + 63) / 64, 256, 0, stream>>>(x, Wt, a, Whp8, s_src, s_tgt);
  k_score<<<NBLK, 256, 0, stream>>>(ei, s_src, s_tgt, bcursor, recs_mid, bmax, bsexp);
  k_stats<<<1, 256, 0, stream>>>(bmax, bsexp, softstat);
  k_sortB<<<NBLK, 256, 0, stream>>>(bcursor, recs_mid, softstat, recs, offs, cnt);
  k_gather<<<NN / 4, 256, 0, stream>>>(offs, cnt, recs, (const unsigned short*)Whp8, xnew);
  k_mlp<<<(NN + 63) / 64, 256, 0, stream>>>(xnew, W1, b1, W2, b2, evid);
}

// Round 12
// 114.538 us; speedup vs baseline: 7.7958x; 1.1220x over previous
//
#include <hip/hip_runtime.h>
#include <math.h>

#define NN 50000
#define NE 800000
#define IND 256
#define OUTD 128
#define HIDD 64
#define NBLK 196   // number of 256-target coarse buckets (196*256 = 50176 >= NN)
#define BCAP 6144  // fixed bucket capacity (mean 4082, ~32 sigma headroom)

typedef __attribute__((ext_vector_type(8))) short short8;   // 8 bf16 (4 VGPR)
typedef __attribute__((ext_vector_type(4))) float f32x4;    // MFMA acc
typedef __attribute__((ext_vector_type(2))) float f32x2;    // fp8 cvt result

// ---------- helpers ----------
static __device__ __forceinline__ unsigned f2bf(float f) {       // RNE f32->bf16 bits
  unsigned u = __float_as_uint(f);
  return (u + 0x7fffu + ((u >> 16) & 1u)) >> 16;
}

// ---------- K0: Wt[n][k]=bf16(W[k][n]), W1t[h][k]=bf16(W1[k][h]), init cursors ----------
__global__ __launch_bounds__(256) void k_wconv(const float* __restrict__ W,
                                               const float* __restrict__ W1,
                                               unsigned short* __restrict__ Wt,
                                               unsigned short* __restrict__ W1t,
                                               int* __restrict__ bcursor) {
  if (blockIdx.x == 0 && threadIdx.x < NBLK)
    bcursor[threadIdx.x] = threadIdx.x * BCAP;       // fixed-capacity bases
  int t = blockIdx.x * 256 + threadIdx.x;     // 128 blocks
  int n = t >> 8, k = t & 255;
  Wt[t] = (unsigned short)f2bf(W[k * OUTD + n]);
  if (t < HIDD * OUTD) {                      // 8192: W1 transposed bf16
    int h = t >> 7, kk = t & 127;
    W1t[t] = (unsigned short)f2bf(W1[kk * HIDD + h]);
  }
}

// ---------- K1: MFMA GEMM -> fp8 Wh table + fused s_src/s_tgt epilogue ----------
__global__ __launch_bounds__(256) void k_gemm(const float* __restrict__ x,
                                              const unsigned short* __restrict__ Wt,
                                              const float* __restrict__ a,
                                              unsigned* __restrict__ Whp8,
                                              float* __restrict__ s_src,
                                              float* __restrict__ s_tgt) {
  __shared__ float smem[8448];                 // max(A+B = 15360B, Cs = 33792B)
  short* As = (short*)smem;                    // [64][40] bf16
  short* Bs = As + 64 * 40;                    // [128][40] bf16
  float* Cs = smem;                            // [64][132] f32 (epilogue alias)

  const int tid  = threadIdx.x;
  const int bm   = blockIdx.x * 64;
  const int wave = tid >> 6;                   // 0..3 -> col block wave*32
  const int lane = tid & 63;
  const int l15  = lane & 15;
  const int lg   = lane >> 4;                  // 0..3

  f32x4 acc[4][2];
#pragma unroll
  for (int i = 0; i < 4; i++)
#pragma unroll
    for (int j = 0; j < 2; j++) acc[i][j] = (f32x4){0.f, 0.f, 0.f, 0.f};

  const int arow = tid >> 2, aq = tid & 3;
  long arow_g = bm + arow; if (arow_g >= NN) arow_g = NN - 1;   // clamp, writes guarded
  const float* xp = &x[arow_g * IND + aq * 8];
  short* asp = &As[arow * 40 + aq * 8];
  const int bn = tid >> 1, bh = tid & 1;
  const unsigned short* wtp = &Wt[bn * 256 + bh * 16];
  short* bsp = &Bs[bn * 40 + bh * 16];

  for (int k0 = 0; k0 < IND; k0 += 32) {
    float4 v0 = *(const float4*)(xp + k0);
    float4 v1 = *(const float4*)(xp + k0 + 4);
    short8 apk;
    apk[0] = (short)f2bf(v0.x); apk[1] = (short)f2bf(v0.y);
    apk[2] = (short)f2bf(v0.z); apk[3] = (short)f2bf(v0.w);
    apk[4] = (short)f2bf(v1.x); apk[5] = (short)f2bf(v1.y);
    apk[6] = (short)f2bf(v1.z); apk[7] = (short)f2bf(v1.w);
    *(short8*)asp = apk;
    *(short8*)bsp       = *(const short8*)(wtp + k0);
    *(short8*)(bsp + 8) = *(const short8*)(wtp + k0 + 8);
    __syncthreads();

    short8 af[4], bf[2];
#pragma unroll
    for (int mi = 0; mi < 4; mi++)
      af[mi] = *(const short8*)&As[(mi * 16 + l15) * 40 + lg * 8];
#pragma unroll
    for (int ni = 0; ni < 2; ni++)
      bf[ni] = *(const short8*)&Bs[(wave * 32 + ni * 16 + l15) * 40 + lg * 8];
#pragma unroll
    for (int mi = 0; mi < 4; mi++)
#pragma unroll
      for (int ni = 0; ni < 2; ni++)
        acc[mi][ni] = __builtin_amdgcn_mfma_f32_16x16x32_bf16(
            af[mi], bf[ni], acc[mi][ni], 0, 0, 0);
    __syncthreads();
  }

  // epilogue: acc -> Cs (f32)
#pragma unroll
  for (int mi = 0; mi < 4; mi++)
#pragma unroll
    for (int ni = 0; ni < 2; ni++)
#pragma unroll
      for (int r = 0; r < 4; r++) {
        int row = mi * 16 + lg * 4 + r;
        int col = wave * 32 + ni * 16 + l15;
        Cs[row * 132 + col] = acc[mi][ni][r];
      }
  __syncthreads();

  // (a) fp8 row store: 1024 chunks of 8 f32 -> 8 fp8 bytes
#pragma unroll
  for (int i = 0; i < 4; i++) {
    int f = tid + i * 256;
    int nd = f >> 4, seg = f & 15;
    long gnode = bm + nd;
    if (gnode < NN) {
      float4 c0 = *(const float4*)&Cs[nd * 132 + seg * 8];
      float4 c1 = *(const float4*)&Cs[nd * 132 + seg * 8 + 4];
      int u0 = __builtin_amdgcn_cvt_pk_fp8_f32(c0.x, c0.y, 0, false);
      u0     = __builtin_amdgcn_cvt_pk_fp8_f32(c0.z, c0.w, u0, true);
      int u1 = __builtin_amdgcn_cvt_pk_fp8_f32(c1.x, c1.y, 0, false);
      u1     = __builtin_amdgcn_cvt_pk_fp8_f32(c1.z, c1.w, u1, true);
      *(uint2*)&Whp8[gnode * 32 + seg * 2] = make_uint2((unsigned)u0, (unsigned)u1);
    }
  }

  // (b) fused s_src/s_tgt: 4 threads per node, 32 cols each, shfl_xor reduce
  {
    const int nd = tid >> 2, p = tid & 3;
    float p1 = 0.f, p2 = 0.f;
    const float* crow = &Cs[nd * 132 + p * 32];
#pragma unroll
    for (int k = 0; k < 32; k++) {
      float c = crow[k];
      p1 = fmaf(c, a[p * 32 + k], p1);
      p2 = fmaf(c, a[128 + p * 32 + k], p2);
    }
    p1 += __shfl_xor(p1, 1); p1 += __shfl_xor(p1, 2);
    p2 += __shfl_xor(p2, 1); p2 += __shfl_xor(p2, 2);
    long gnode = bm + nd;
    if (p == 0 && gnode < NN) { s_src[gnode] = p1; s_tgt[gnode] = p2; }
  }
}

// ---------- K3: scores + DIRECT binning (fixed-capacity buckets) + block stats ----------
__global__ __launch_bounds__(256) void k_score(const int* __restrict__ ei,
                                               const float* __restrict__ s_src,
                                               const float* __restrict__ s_tgt,
                                               int* __restrict__ bcursor,
                                               int2* __restrict__ recs_mid,
                                               float* __restrict__ bmax,
                                               float* __restrict__ bsexp) {
  __shared__ int bh[NBLK];
  __shared__ int gbase[NBLK];
  __shared__ float red[4];
  __shared__ float bmx;
  const int tid = threadIdx.x;
  const long eb = (long)blockIdx.x * 4096;
  if (tid < NBLK) bh[tid] = 0;
  __syncthreads();

  int sv[16]; int tv[16]; float scv[16];
  float mx = -1e30f;
#pragma unroll
  for (int i = 0; i < 16; i++) {
    long e = eb + i * 256 + tid;
    float sc = -1e30f;
    if (e < NE) {
      int s = ei[e];
      int t = ei[NE + e];
      float v = s_src[s] + s_tgt[t];
      sc = v > 0.f ? v : 0.2f * v;              // leaky_relu(0.2)
      sv[i] = s; tv[i] = t;
      atomicAdd(&bh[t >> 8], 1);
    } else {
      tv[i] = -1;
    }
    scv[i] = sc;
    mx = fmaxf(mx, sc);
  }
  __syncthreads();
  if (tid < NBLK) {
    int c = bh[tid];
    gbase[tid] = (c > 0) ? atomicAdd(&bcursor[tid], c) : 0;
    bh[tid] = 0;                               // reuse as local cursor
  }
  __syncthreads();
#pragma unroll
  for (int i = 0; i < 16; i++) {
    if (tv[i] >= 0) {
      int b = tv[i] >> 8;
      int off = atomicAdd(&bh[b], 1);
      recs_mid[gbase[b] + off] = make_int2(sv[i] | ((tv[i] & 255) << 16),
                                           __float_as_int(scv[i]));
    }
  }

  // per-block softmax stats
#pragma unroll
  for (int off = 32; off; off >>= 1) mx = fmaxf(mx, __shfl_down(mx, off));
  int w = tid >> 6, lane = tid & 63;
  if (lane == 0) red[w] = mx;
  __syncthreads();
  if (tid == 0) bmx = fmaxf(fmaxf(red[0], red[1]), fmaxf(red[2], red[3]));
  __syncthreads();
  const float M = bmx;
  float s = 0.f;
#pragma unroll
  for (int i = 0; i < 16; i++) s += __expf(scv[i] - M);   // invalid lanes -> 0
#pragma unroll
  for (int off = 32; off; off >>= 1) s += __shfl_down(s, off);
  if (lane == 0) red[w] = s;
  __syncthreads();
  if (tid == 0) {
    bmax[blockIdx.x] = M;
    bsexp[blockIdx.x] = red[0] + red[1] + red[2] + red[3];
  }
}

// ---------- K5: combine per-block softmax stats (1 block) ----------
__global__ __launch_bounds__(256) void k_stats(const float* __restrict__ bmax,
                                               const float* __restrict__ bsexp,
                                               float* __restrict__ softstat) {
  __shared__ float fred[256];
  int tid = threadIdx.x;
  float m = (tid < NBLK) ? bmax[tid] : -1e30f;
  fred[tid] = m;
  __syncthreads();
  for (int off = 128; off; off >>= 1) {
    if (tid < off) fred[tid] = fmaxf(fred[tid], fred[tid + off]);
    __syncthreads();
  }
  const float M = fred[0];
  __syncthreads();
  float se = (tid < NBLK) ? bsexp[tid] * __expf(bmax[tid] - M) : 0.f;
  fred[tid] = se;
  __syncthreads();
  for (int off = 128; off; off >>= 1) {
    if (tid < off) fred[tid] += fred[tid + off];
    __syncthreads();
  }
  if (tid == 0) { softstat[0] = M; softstat[1] = fred[0]; }
}

// ---------- K6: in-bucket LDS sort by target + sc->alpha + offs/cnt emit ----------
__global__ __launch_bounds__(256) void k_sortB(const int* __restrict__ bcursor,
                                               const int2* __restrict__ recs_mid,
                                               const float* __restrict__ softstat,
                                               int2* __restrict__ recs,
                                               int* __restrict__ offs,
                                               int* __restrict__ cnt) {
  __shared__ int h[256], sc[256], cur[256];
  __shared__ int2 srt[BCAP];
  const int tid = threadIdx.x;
  const int b = blockIdx.x;
  const int base = b * BCAP;
  const int m = bcursor[b] - base;
  const float M = softstat[0];
  const float inv = 1.0f / softstat[1];

  h[tid] = 0;
  __syncthreads();
  for (int i = tid; i < m; i += 256) {
    int2 r = recs_mid[base + i];
    atomicAdd(&h[(r.x >> 16) & 255], 1);
  }
  __syncthreads();
  sc[tid] = h[tid];
  __syncthreads();
  for (int off = 1; off < 256; off <<= 1) {
    int t = (tid >= off) ? sc[tid - off] : 0;
    __syncthreads();
    sc[tid] += t;
    __syncthreads();
  }
  int excl = sc[tid] - h[tid];
  cur[tid] = excl;
  offs[b * 256 + tid] = base + excl;           // global per-target offsets
  cnt[b * 256 + tid] = h[tid];
  __syncthreads();
  for (int i = tid; i < m; i += 256) {
    int2 r = recs_mid[base + i];
    int tl = (r.x >> 16) & 255;
    int p = atomicAdd(&cur[tl], 1);
    float al = __expf(__int_as_float(r.y) - M) * inv;
    if (p < BCAP) srt[p] = make_int2(r.x & 0xffff, __float_as_int(al));
  }
  __syncthreads();
  for (int i = tid; i < m; i += 256)
    recs[base + i] = srt[i];                   // coalesced
}

// ---------- K7: gather-sum per target node (one wave per node, fp8 rows) ----------
__global__ __launch_bounds__(256) void k_gather(const int* __restrict__ offs,
                                                const int* __restrict__ cnt,
                                                const int2* __restrict__ recs,
                                                const unsigned short* __restrict__ Whp8,
                                                float* __restrict__ xnew) {
  int wid = (blockIdx.x * 256 + threadIdx.x) >> 6;    // 12500*4 = NN waves
  int lane = threadIdx.x & 63;
  int start = offs[wid];
  int n = cnt[wid];
  float2 acc = make_float2(0.f, 0.f);
  for (int base = 0; base < n; base += 64) {
    int m = n - base; if (m > 64) m = 64;
    int li = lane < m ? lane : m - 1;
    int2 r = recs[start + base + li];                 // coalesced chunk load
    for (int i = 0; i < m; i += 4) {                  // 4 row-loads in flight
      int sj[4]; float aj[4];
#pragma unroll
      for (int j = 0; j < 4; j++) {
        int idx = i + j;
        sj[j] = __shfl(r.x, idx);
        float al = __int_as_float(__shfl(r.y, idx));
        aj[j] = (idx < m) ? al : 0.f;
      }
      unsigned short v[4];
#pragma unroll
      for (int j = 0; j < 4; j++)
        v[j] = Whp8[(long)sj[j] * 64 + lane];         // 2 fp8 = cols 2lane,2lane+1
#pragma unroll
      for (int j = 0; j < 4; j++) {
        f32x2 w = __builtin_amdgcn_cvt_pk_f32_fp8((int)(unsigned)v[j], false);
        acc.x = fmaf(aj[j], w[0], acc.x);
        acc.y = fmaf(aj[j], w[1], acc.y);
      }
    }
  }
  ((float2*)xnew)[(long)wid * 64 + lane] = acc;
}

// ---------- K8: MLP head, layer-1 via MFMA bf16 ----------
// 64 nodes/block, 4 waves. LDS: x bf16 [64][136] (17.4KB) + W1t bf16 [64][136]
// (17.4KB) = 34.8KB -> 4 blocks/CU. Wave w owns hid cols w*16..+15 (1 n-frag),
// 4 m-frags, K=128 in 4 steps -> 16 MFMA/wave. Layer 2 fused from Cs (aliased).
__global__ __launch_bounds__(256) void k_mlp(const float* __restrict__ xnew,
                                             const unsigned short* __restrict__ W1t,
                                             const float* __restrict__ b1,
                                             const float* __restrict__ W2,
                                             const float* __restrict__ b2,
                                             float* __restrict__ evid) {
  __shared__ short smem[17408];                // 34816 B
  short* As = smem;                            // [64][136] bf16 x-tile
  short* Bs = smem + 64 * 136;                 // [64][136] bf16 W1t (hid-major)
  float* Cs = (float*)smem;                    // [64][68] f32 h (aliases As)

  const int tid = threadIdx.x;
  const int nb = blockIdx.x * 64;
  const int wave = tid >> 6;
  const int lane = tid & 63;
  const int l15 = lane & 15, lg = lane >> 4;

  // stage x -> bf16 (32 elems/thread) and W1t copy (32 shorts/thread)
  {
    int row = tid >> 2, seg = tid & 3;
    long g = nb + row; if (g >= NN) g = NN - 1;
    const float* xp = &xnew[g * OUTD + seg * 32];
    short* dst = &As[row * 136 + seg * 32];
    const unsigned short* wp = &W1t[row * 128 + seg * 32];
    short* wdst = &Bs[row * 136 + seg * 32];
#pragma unroll
    for (int q = 0; q < 4; q++) {
      float4 v0 = *(const float4*)(xp + q * 8);
      float4 v1 = *(const float4*)(xp + q * 8 + 4);
      short8 pk;
      pk[0] = (short)f2bf(v0.x); pk[1] = (short)f2bf(v0.y);
      pk[2] = (short)f2bf(v0.z); pk[3] = (short)f2bf(v0.w);
      pk[4] = (short)f2bf(v1.x); pk[5] = (short)f2bf(v1.y);
      pk[6] = (short)f2bf(v1.z); pk[7] = (short)f2bf(v1.w);
      *(short8*)(dst + q * 8) = pk;
      *(short8*)(wdst + q * 8) = *(const short8*)(wp + q * 8);
    }
  }
  __syncthreads();

  f32x4 acc[4];
#pragma unroll
  for (int mi = 0; mi < 4; mi++) acc[mi] = (f32x4){0.f, 0.f, 0.f, 0.f};
#pragma unroll
  for (int ks = 0; ks < 4; ks++) {
    short8 bfr = *(const short8*)&Bs[(wave * 16 + l15) * 136 + ks * 32 + lg * 8];
#pragma unroll
    for (int mi = 0; mi < 4; mi++) {
      short8 afr = *(const short8*)&As[(mi * 16 + l15) * 136 + ks * 32 + lg * 8];
      acc[mi] = __builtin_amdgcn_mfma_f32_16x16x32_bf16(afr, bfr, acc[mi], 0, 0, 0);
    }
  }
  __syncthreads();                             // As dead; alias as Cs
#pragma unroll
  for (int mi = 0; mi < 4; mi++)
#pragma unroll
    for (int r = 0; r < 4; r++) {
      int row = mi * 16 + lg * 4 + r;
      int col = wave * 16 + l15;
      Cs[row * 68 + col] = acc[mi][r];
    }
  __syncthreads();

  // layer 2 fused from Cs
  const int ty = tid >> 4, tx = tid & 15;
  float b1r[4], w2r[4][3];
#pragma unroll
  for (int j = 0; j < 4; j++) {
    int jg = tx * 4 + j;
    b1r[j] = b1[jg];
    w2r[j][0] = W2[jg * 3 + 0];
    w2r[j][1] = W2[jg * 3 + 1];
    w2r[j][2] = W2[jg * 3 + 2];
  }
#pragma unroll
  for (int i = 0; i < 4; i++) {
    float p0 = 0.f, p1 = 0.f, p2 = 0.f;
#pragma unroll
    for (int j = 0; j < 4; j++) {
      float h = fmaxf(Cs[(ty * 4 + i) * 68 + tx * 4 + j] + b1r[j], 0.f);
      p0 = fmaf(h, w2r[j][0], p0);
      p1 = fmaf(h, w2r[j][1], p1);
      p2 = fmaf(h, w2r[j][2], p2);
    }
#pragma unroll
    for (int m = 1; m < 16; m <<= 1) {
      p0 += __shfl_xor(p0, m);
      p1 += __shfl_xor(p1, m);
      p2 += __shfl_xor(p2, m);
    }
    if (tx == 0) {
      int n = nb + ty * 4 + i;
      if (n < NN) {
        float e0 = p0 + b2[0], e1 = p1 + b2[1], e2 = p2 + b2[2];
        float s0 = e0 > 20.f ? e0 : log1pf(expf(e0));
        float s1 = e1 > 20.f ? e1 : log1pf(expf(e1));
        float s2 = e2 > 20.f ? e2 : log1pf(expf(e2));
        evid[(long)n * 3 + 0] = s0 + 1.0f;
        evid[(long)n * 3 + 1] = s1 + 1.0f;
        evid[(long)n * 3 + 2] = s2 + 1.0f;
      }
    }
  }
}

extern "C" void kernel_launch(void* const* d_in, const int* in_sizes, int n_in,
                              void* d_out, int out_size, void* d_ws, size_t ws_size,
                              hipStream_t stream) {
  const float* x   = (const float*)d_in[0];
  const int*   ei  = (const int*)d_in[1];
  const float* W   = (const float*)d_in[2];
  const float* a   = (const float*)d_in[3];
  const float* W1  = (const float*)d_in[4];
  const float* b1  = (const float*)d_in[5];
  const float* W2  = (const float*)d_in[6];
  const float* b2  = (const float*)d_in[7];

  float* xnew = (float*)d_out;                       // [NN*OUTD]
  float* evid = (float*)d_out + (size_t)NN * OUTD;   // [NN*3]

  float* wsf = (float*)d_ws;
  unsigned* Whp8     = (unsigned*)wsf;               // 1,600,000 u32 (6.4 MB fp8 Wh)
  float*    s_src    = wsf + 1600000;                //    50,000 f
  float*    s_tgt    = wsf + 1650000;                //    50,000 f
  int2*     recs_mid = (int2*)(wsf + 1700000);       // 196*6144 = 1,204,224 int2
  int2*     recs     = (int2*)(wsf + 4108448);       // 1,204,224 int2
  int*      offs     = (int*)(wsf + 6516896);        //    50,176 i
  int*      cnt      = (int*)(wsf + 6567328);        //    50,176 i
  int*      bcursor  = (int*)(wsf + 6617504);        //       196 i
  float*    bmax     = wsf + 6617700;                //       196 f
  float*    bsexp    = wsf + 6617896;                //       196 f
  float*    softstat = wsf + 6618092;                //         2 f
  unsigned short* Wt  = (unsigned short*)(wsf + 6618096);  // 32,768 bf16
  unsigned short* W1t = (unsigned short*)(wsf + 6634480);  // 8,192 bf16 (end ~26.6 MB)

  k_wconv<<<128, 256, 0, stream>>>(W, W1, Wt, W1t, bcursor);
  k_gemm<<<(NN + 63) / 64, 256, 0, stream>>>(x, Wt, a, Whp8, s_src, s_tgt);
  k_score<<<NBLK, 256, 0, stream>>>(ei, s_src, s_tgt, bcursor, recs_mid, bmax, bsexp);
  k_stats<<<1, 256, 0, stream>>>(bmax, bsexp, softstat);
  k_sortB<<<NBLK, 256, 0, stream>>>(bcursor, recs_mid, softstat, recs, offs, cnt);
  k_gather<<<NN / 4, 256, 0, stream>>>(offs, cnt, recs, (const unsigned short*)Whp8, xnew);
  k_mlp<<<(NN + 63) / 64, 256, 0, stream>>>(xnew, W1t, b1, W2, b2, evid);
}

// Round 13
// 110.662 us; speedup vs baseline: 8.0689x; 1.0350x over previous
//
#include <hip/hip_runtime.h>
#include <hip/hip_bf16.h>
#include <math.h>

#define NN 50000
#define NE 800000
#define IND 256
#define OUTD 128
#define HIDD 64
#define NBLK 196   // number of 256-target coarse buckets (196*256 = 50176 >= NN)
#define BCAP 6144  // fixed bucket capacity (mean 4082, ~32 sigma headroom)

typedef __attribute__((ext_vector_type(8))) short short8;   // 8 bf16 (4 VGPR)
typedef __attribute__((ext_vector_type(4))) float f32x4;    // MFMA acc
typedef __attribute__((ext_vector_type(2))) float f32x2;    // fp8 cvt result

// ---------- helpers ----------
static __device__ __forceinline__ unsigned short f2bf_hw(float f) {  // HW cvt (RNE)
  __hip_bfloat16 h = __float2bfloat16(f);
  return __hip_bfloat16_raw(h).x;
}
static __device__ __forceinline__ float bf2f(unsigned b) {
  return __uint_as_float(b << 16);
}

// ---------- K0: Wt[n][k]=bf16(W[k][n]), W1t[h][k]=bf16(W1[k][h]), init cursors ----------
__global__ __launch_bounds__(256) void k_wconv(const float* __restrict__ W,
                                               const float* __restrict__ W1,
                                               unsigned short* __restrict__ Wt,
                                               unsigned short* __restrict__ W1t,
                                               int* __restrict__ bcursor) {
  if (blockIdx.x == 0 && threadIdx.x < NBLK)
    bcursor[threadIdx.x] = threadIdx.x * BCAP;       // fixed-capacity bases
  int t = blockIdx.x * 256 + threadIdx.x;     // 128 blocks
  int n = t >> 8, k = t & 255;
  Wt[t] = f2bf_hw(W[k * OUTD + n]);
  if (t < HIDD * OUTD) {                      // 8192: W1 transposed bf16
    int h = t >> 7, kk = t & 127;
    W1t[t] = f2bf_hw(W1[kk * HIDD + h]);
  }
}

// ---------- K1: MFMA GEMM -> fp8 Wh table + fused s_src/s_tgt epilogue ----------
__global__ __launch_bounds__(256) void k_gemm(const float* __restrict__ x,
                                              const unsigned short* __restrict__ Wt,
                                              const float* __restrict__ a,
                                              unsigned* __restrict__ Whp8,
                                              float* __restrict__ s_src,
                                              float* __restrict__ s_tgt) {
  __shared__ float smem[8448];                 // max(A+B = 15360B, Cs = 33792B)
  short* As = (short*)smem;                    // [64][40] bf16
  short* Bs = As + 64 * 40;                    // [128][40] bf16
  float* Cs = smem;                            // [64][132] f32 (epilogue alias)

  const int tid  = threadIdx.x;
  const int bm   = blockIdx.x * 64;
  const int wave = tid >> 6;                   // 0..3 -> col block wave*32
  const int lane = tid & 63;
  const int l15  = lane & 15;
  const int lg   = lane >> 4;                  // 0..3

  f32x4 acc[4][2];
#pragma unroll
  for (int i = 0; i < 4; i++)
#pragma unroll
    for (int j = 0; j < 2; j++) acc[i][j] = (f32x4){0.f, 0.f, 0.f, 0.f};

  const int arow = tid >> 2, aq = tid & 3;
  long arow_g = bm + arow; if (arow_g >= NN) arow_g = NN - 1;   // clamp, writes guarded
  const float* xp = &x[arow_g * IND + aq * 8];
  short* asp = &As[arow * 40 + aq * 8];
  const int bn = tid >> 1, bh = tid & 1;
  const unsigned short* wtp = &Wt[bn * 256 + bh * 16];
  short* bsp = &Bs[bn * 40 + bh * 16];

  for (int k0 = 0; k0 < IND; k0 += 32) {
    float4 v0 = *(const float4*)(xp + k0);
    float4 v1 = *(const float4*)(xp + k0 + 4);
    short8 apk;                                // HW cvt: compiler fuses to cvt_pk
    apk[0] = (short)f2bf_hw(v0.x); apk[1] = (short)f2bf_hw(v0.y);
    apk[2] = (short)f2bf_hw(v0.z); apk[3] = (short)f2bf_hw(v0.w);
    apk[4] = (short)f2bf_hw(v1.x); apk[5] = (short)f2bf_hw(v1.y);
    apk[6] = (short)f2bf_hw(v1.z); apk[7] = (short)f2bf_hw(v1.w);
    *(short8*)asp = apk;
    *(short8*)bsp       = *(const short8*)(wtp + k0);
    *(short8*)(bsp + 8) = *(const short8*)(wtp + k0 + 8);
    __syncthreads();

    short8 af[4], bf[2];
#pragma unroll
    for (int mi = 0; mi < 4; mi++)
      af[mi] = *(const short8*)&As[(mi * 16 + l15) * 40 + lg * 8];
#pragma unroll
    for (int ni = 0; ni < 2; ni++)
      bf[ni] = *(const short8*)&Bs[(wave * 32 + ni * 16 + l15) * 40 + lg * 8];
#pragma unroll
    for (int mi = 0; mi < 4; mi++)
#pragma unroll
      for (int ni = 0; ni < 2; ni++)
        acc[mi][ni] = __builtin_amdgcn_mfma_f32_16x16x32_bf16(
            af[mi], bf[ni], acc[mi][ni], 0, 0, 0);
    __syncthreads();
  }

  // epilogue: acc -> Cs (f32)
#pragma unroll
  for (int mi = 0; mi < 4; mi++)
#pragma unroll
    for (int ni = 0; ni < 2; ni++)
#pragma unroll
      for (int r = 0; r < 4; r++) {
        int row = mi * 16 + lg * 4 + r;
        int col = wave * 32 + ni * 16 + l15;
        Cs[row * 132 + col] = acc[mi][ni][r];
      }
  __syncthreads();

  // (a) fp8 row store: 1024 chunks of 8 f32 -> 8 fp8 bytes
#pragma unroll
  for (int i = 0; i < 4; i++) {
    int f = tid + i * 256;
    int nd = f >> 4, seg = f & 15;
    long gnode = bm + nd;
    if (gnode < NN) {
      float4 c0 = *(const float4*)&Cs[nd * 132 + seg * 8];
      float4 c1 = *(const float4*)&Cs[nd * 132 + seg * 8 + 4];
      int u0 = __builtin_amdgcn_cvt_pk_fp8_f32(c0.x, c0.y, 0, false);
      u0     = __builtin_amdgcn_cvt_pk_fp8_f32(c0.z, c0.w, u0, true);
      int u1 = __builtin_amdgcn_cvt_pk_fp8_f32(c1.x, c1.y, 0, false);
      u1     = __builtin_amdgcn_cvt_pk_fp8_f32(c1.z, c1.w, u1, true);
      *(uint2*)&Whp8[gnode * 32 + seg * 2] = make_uint2((unsigned)u0, (unsigned)u1);
    }
  }

  // (b) fused s_src/s_tgt: 4 threads per node, 32 cols each, shfl_xor reduce
  {
    const int nd = tid >> 2, p = tid & 3;
    float p1 = 0.f, p2 = 0.f;
    const float* crow = &Cs[nd * 132 + p * 32];
#pragma unroll
    for (int k = 0; k < 32; k++) {
      float c = crow[k];
      p1 = fmaf(c, a[p * 32 + k], p1);
      p2 = fmaf(c, a[128 + p * 32 + k], p2);
    }
    p1 += __shfl_xor(p1, 1); p1 += __shfl_xor(p1, 2);
    p2 += __shfl_xor(p2, 1); p2 += __shfl_xor(p2, 2);
    long gnode = bm + nd;
    if (p == 0 && gnode < NN) { s_src[gnode] = p1; s_tgt[gnode] = p2; }
  }
}

// ---------- K3: scores + DIRECT binning (fixed-capacity buckets) + block stats ----------
__global__ __launch_bounds__(256) void k_score(const int* __restrict__ ei,
                                               const float* __restrict__ s_src,
                                               const float* __restrict__ s_tgt,
                                               int* __restrict__ bcursor,
                                               int2* __restrict__ recs_mid,
                                               float* __restrict__ bmax,
                                               float* __restrict__ bsexp) {
  __shared__ int bh[NBLK];
  __shared__ int gbase[NBLK];
  __shared__ float red[4];
  __shared__ float bmx;
  const int tid = threadIdx.x;
  const long eb = (long)blockIdx.x * 4096;
  if (tid < NBLK) bh[tid] = 0;
  __syncthreads();

  int sv[16]; int tv[16]; float scv[16];
  float mx = -1e30f;
#pragma unroll
  for (int i = 0; i < 16; i++) {
    long e = eb + i * 256 + tid;
    float sc = -1e30f;
    if (e < NE) {
      int s = ei[e];
      int t = ei[NE + e];
      float v = s_src[s] + s_tgt[t];
      sc = v > 0.f ? v : 0.2f * v;              // leaky_relu(0.2)
      sv[i] = s; tv[i] = t;
      atomicAdd(&bh[t >> 8], 1);
    } else {
      tv[i] = -1;
    }
    scv[i] = sc;
    mx = fmaxf(mx, sc);
  }
  __syncthreads();
  if (tid < NBLK) {
    int c = bh[tid];
    gbase[tid] = (c > 0) ? atomicAdd(&bcursor[tid], c) : 0;
    bh[tid] = 0;                               // reuse as local cursor
  }
  __syncthreads();
#pragma unroll
  for (int i = 0; i < 16; i++) {
    if (tv[i] >= 0) {
      int b = tv[i] >> 8;
      int off = atomicAdd(&bh[b], 1);
      recs_mid[gbase[b] + off] = make_int2(sv[i] | ((tv[i] & 255) << 16),
                                           __float_as_int(scv[i]));
    }
  }

  // per-block softmax stats
#pragma unroll
  for (int off = 32; off; off >>= 1) mx = fmaxf(mx, __shfl_down(mx, off));
  int w = tid >> 6, lane = tid & 63;
  if (lane == 0) red[w] = mx;
  __syncthreads();
  if (tid == 0) bmx = fmaxf(fmaxf(red[0], red[1]), fmaxf(red[2], red[3]));
  __syncthreads();
  const float M = bmx;
  float s = 0.f;
#pragma unroll
  for (int i = 0; i < 16; i++) s += __expf(scv[i] - M);   // invalid lanes -> 0
#pragma unroll
  for (int off = 32; off; off >>= 1) s += __shfl_down(s, off);
  if (lane == 0) red[w] = s;
  __syncthreads();
  if (tid == 0) {
    bmax[blockIdx.x] = M;
    bsexp[blockIdx.x] = red[0] + red[1] + red[2] + red[3];
  }
}

// ---------- K5: combine per-block softmax stats (1 block) ----------
__global__ __launch_bounds__(256) void k_stats(const float* __restrict__ bmax,
                                               const float* __restrict__ bsexp,
                                               float* __restrict__ softstat) {
  __shared__ float fred[256];
  int tid = threadIdx.x;
  float m = (tid < NBLK) ? bmax[tid] : -1e30f;
  fred[tid] = m;
  __syncthreads();
  for (int off = 128; off; off >>= 1) {
    if (tid < off) fred[tid] = fmaxf(fred[tid], fred[tid + off]);
    __syncthreads();
  }
  const float M = fred[0];
  __syncthreads();
  float se = (tid < NBLK) ? bsexp[tid] * __expf(bmax[tid] - M) : 0.f;
  fred[tid] = se;
  __syncthreads();
  for (int off = 128; off; off >>= 1) {
    if (tid < off) fred[tid] += fred[tid + off];
    __syncthreads();
  }
  if (tid == 0) { softstat[0] = M; softstat[1] = fred[0]; }
}

// ---------- K6: in-bucket LDS sort + sc->alpha(bf16) + 4B record emit ----------
// Record: src(16b) | bf16(alpha)<<16. Halves record traffic; 24KB srt LDS.
__global__ __launch_bounds__(256) void k_sortB(const int* __restrict__ bcursor,
                                               const int2* __restrict__ recs_mid,
                                               const float* __restrict__ softstat,
                                               unsigned* __restrict__ recs,
                                               int* __restrict__ offs,
                                               int* __restrict__ cnt) {
  __shared__ int h[256], sc[256], cur[256];
  __shared__ unsigned srt[BCAP];
  const int tid = threadIdx.x;
  const int b = blockIdx.x;
  const int base = b * BCAP;
  const int m = bcursor[b] - base;
  const float M = softstat[0];
  const float inv = 1.0f / softstat[1];

  h[tid] = 0;
  __syncthreads();
  for (int i = tid; i < m; i += 256) {
    int2 r = recs_mid[base + i];
    atomicAdd(&h[(r.x >> 16) & 255], 1);
  }
  __syncthreads();
  sc[tid] = h[tid];
  __syncthreads();
  for (int off = 1; off < 256; off <<= 1) {
    int t = (tid >= off) ? sc[tid - off] : 0;
    __syncthreads();
    sc[tid] += t;
    __syncthreads();
  }
  int excl = sc[tid] - h[tid];
  cur[tid] = excl;
  offs[b * 256 + tid] = base + excl;           // global per-target offsets
  cnt[b * 256 + tid] = h[tid];
  __syncthreads();
  for (int i = tid; i < m; i += 256) {
    int2 r = recs_mid[base + i];
    int tl = (r.x >> 16) & 255;
    int p = atomicAdd(&cur[tl], 1);
    float al = __expf(__int_as_float(r.y) - M) * inv;
    if (p < BCAP)
      srt[p] = (unsigned)(r.x & 0xffff) | ((unsigned)f2bf_hw(al) << 16);
  }
  __syncthreads();
  for (int i = tid; i < m; i += 256)
    recs[base + i] = srt[i];                   // coalesced 4B records
}

// ---------- K7: gather-sum per target node (one wave per node, fp8 rows, 8-deep) ----------
__global__ __launch_bounds__(256) void k_gather(const int* __restrict__ offs,
                                                const int* __restrict__ cnt,
                                                const unsigned* __restrict__ recs,
                                                const unsigned short* __restrict__ Whp8,
                                                float* __restrict__ xnew) {
  int wid = (blockIdx.x * 256 + threadIdx.x) >> 6;    // 12500*4 = NN waves
  int lane = threadIdx.x & 63;
  int start = offs[wid];
  int n = cnt[wid];
  float2 acc = make_float2(0.f, 0.f);
  for (int base = 0; base < n; base += 64) {
    int m = n - base; if (m > 64) m = 64;
    int li = lane < m ? lane : m - 1;
    unsigned r = recs[start + base + li];             // coalesced chunk load
    for (int i = 0; i < m; i += 8) {                  // 8 row-loads in flight
      unsigned rv[8];
#pragma unroll
      for (int j = 0; j < 8; j++) rv[j] = __shfl(r, i + j);
      unsigned short v[8];
#pragma unroll
      for (int j = 0; j < 8; j++)
        v[j] = Whp8[(long)(rv[j] & 0xffffu) * 64 + lane];  // 2 fp8/lane
#pragma unroll
      for (int j = 0; j < 8; j++) {
        float al = (i + j < m) ? bf2f(rv[j] >> 16) : 0.f;
        f32x2 w = __builtin_amdgcn_cvt_pk_f32_fp8((int)(unsigned)v[j], false);
        acc.x = fmaf(al, w[0], acc.x);
        acc.y = fmaf(al, w[1], acc.y);
      }
    }
  }
  ((float2*)xnew)[(long)wid * 64 + lane] = acc;
}

// ---------- K8: MLP head, layer-1 via MFMA bf16 ----------
__global__ __launch_bounds__(256) void k_mlp(const float* __restrict__ xnew,
                                             const unsigned short* __restrict__ W1t,
                                             const float* __restrict__ b1,
                                             const float* __restrict__ W2,
                                             const float* __restrict__ b2,
                                             float* __restrict__ evid) {
  __shared__ short smem[17408];                // 34816 B
  short* As = smem;                            // [64][136] bf16 x-tile
  short* Bs = smem + 64 * 136;                 // [64][136] bf16 W1t (hid-major)
  float* Cs = (float*)smem;                    // [64][68] f32 h (aliases As)

  const int tid = threadIdx.x;
  const int nb = blockIdx.x * 64;
  const int wave = tid >> 6;
  const int lane = tid & 63;
  const int l15 = lane & 15, lg = lane >> 4;

  // stage x -> bf16 (32 elems/thread) and W1t copy (32 shorts/thread)
  {
    int row = tid >> 2, seg = tid & 3;
    long g = nb + row; if (g >= NN) g = NN - 1;
    const float* xp = &xnew[g * OUTD + seg * 32];
    short* dst = &As[row * 136 + seg * 32];
    const unsigned short* wp = &W1t[row * 128 + seg * 32];
    short* wdst = &Bs[row * 136 + seg * 32];
#pragma unroll
    for (int q = 0; q < 4; q++) {
      float4 v0 = *(const float4*)(xp + q * 8);
      float4 v1 = *(const float4*)(xp + q * 8 + 4);
      short8 pk;
      pk[0] = (short)f2bf_hw(v0.x); pk[1] = (short)f2bf_hw(v0.y);
      pk[2] = (short)f2bf_hw(v0.z); pk[3] = (short)f2bf_hw(v0.w);
      pk[4] = (short)f2bf_hw(v1.x); pk[5] = (short)f2bf_hw(v1.y);
      pk[6] = (short)f2bf_hw(v1.z); pk[7] = (short)f2bf_hw(v1.w);
      *(short8*)(dst + q * 8) = pk;
      *(short8*)(wdst + q * 8) = *(const short8*)(wp + q * 8);
    }
  }
  __syncthreads();

  f32x4 acc[4];
#pragma unroll
  for (int mi = 0; mi < 4; mi++) acc[mi] = (f32x4){0.f, 0.f, 0.f, 0.f};
#pragma unroll
  for (int ks = 0; ks < 4; ks++) {
    short8 bfr = *(const short8*)&Bs[(wave * 16 + l15) * 136 + ks * 32 + lg * 8];
#pragma unroll
    for (int mi = 0; mi < 4; mi++) {
      short8 afr = *(const short8*)&As[(mi * 16 + l15) * 136 + ks * 32 + lg * 8];
      acc[mi] = __builtin_amdgcn_mfma_f32_16x16x32_bf16(afr, bfr, acc[mi], 0, 0, 0);
    }
  }
  __syncthreads();                             // As dead; alias as Cs
#pragma unroll
  for (int mi = 0; mi < 4; mi++)
#pragma unroll
    for (int r = 0; r < 4; r++) {
      int row = mi * 16 + lg * 4 + r;
      int col = wave * 16 + l15;
      Cs[row * 68 + col] = acc[mi][r];
    }
  __syncthreads();

  // layer 2 fused from Cs
  const int ty = tid >> 4, tx = tid & 15;
  float b1r[4], w2r[4][3];
#pragma unroll
  for (int j = 0; j < 4; j++) {
    int jg = tx * 4 + j;
    b1r[j] = b1[jg];
    w2r[j][0] = W2[jg * 3 + 0];
    w2r[j][1] = W2[jg * 3 + 1];
    w2r[j][2] = W2[jg * 3 + 2];
  }
#pragma unroll
  for (int i = 0; i < 4; i++) {
    float p0 = 0.f, p1 = 0.f, p2 = 0.f;
#pragma unroll
    for (int j = 0; j < 4; j++) {
      float h = fmaxf(Cs[(ty * 4 + i) * 68 + tx * 4 + j] + b1r[j], 0.f);
      p0 = fmaf(h, w2r[j][0], p0);
      p1 = fmaf(h, w2r[j][1], p1);
      p2 = fmaf(h, w2r[j][2], p2);
    }
#pragma unroll
    for (int m = 1; m < 16; m <<= 1) {
      p0 += __shfl_xor(p0, m);
      p1 += __shfl_xor(p1, m);
      p2 += __shfl_xor(p2, m);
    }
    if (tx == 0) {
      int n = nb + ty * 4 + i;
      if (n < NN) {
        float e0 = p0 + b2[0], e1 = p1 + b2[1], e2 = p2 + b2[2];
        float s0 = e0 > 20.f ? e0 : log1pf(expf(e0));
        float s1 = e1 > 20.f ? e1 : log1pf(expf(e1));
        float s2 = e2 > 20.f ? e2 : log1pf(expf(e2));
        evid[(long)n * 3 + 0] = s0 + 1.0f;
        evid[(long)n * 3 + 1] = s1 + 1.0f;
        evid[(long)n * 3 + 2] = s2 + 1.0f;
      }
    }
  }
}

extern "C" void kernel_launch(void* const* d_in, const int* in_sizes, int n_in,
                              void* d_out, int out_size, void* d_ws, size_t ws_size,
                              hipStream_t stream) {
  const float* x   = (const float*)d_in[0];
  const int*   ei  = (const int*)d_in[1];
  const float* W   = (const float*)d_in[2];
  const float* a   = (const float*)d_in[3];
  const float* W1  = (const float*)d_in[4];
  const float* b1  = (const float*)d_in[5];
  const float* W2  = (const float*)d_in[6];
  const float* b2  = (const float*)d_in[7];

  float* xnew = (float*)d_out;                       // [NN*OUTD]
  float* evid = (float*)d_out + (size_t)NN * OUTD;   // [NN*3]

  float* wsf = (float*)d_ws;
  unsigned* Whp8     = (unsigned*)wsf;               // 1,600,000 u32 (6.4 MB fp8 Wh)
  float*    s_src    = wsf + 1600000;                //    50,000 f
  float*    s_tgt    = wsf + 1650000;                //    50,000 f
  int2*     recs_mid = (int2*)(wsf + 1700000);       // 1,204,224 int2 (9.6 MB)
  unsigned* recs     = (unsigned*)(wsf + 4108448);   // 1,204,224 u32 (4.8 MB)
  int*      offs     = (int*)(wsf + 5312672);        //    50,176 i
  int*      cnt      = (int*)(wsf + 5362848);        //    50,176 i
  int*      bcursor  = (int*)(wsf + 5413024);        //       196 i
  float*    bmax     = wsf + 5413220;                //       196 f
  float*    bsexp    = wsf + 5413416;                //       196 f
  float*    softstat = wsf + 5413612;                //         2 f
  unsigned short* Wt  = (unsigned short*)(wsf + 5413616);  // 32,768 bf16
  unsigned short* W1t = (unsigned short*)(wsf + 5430000);  // 8,192 bf16 (end ~21.7 MB)

  k_wconv<<<128, 256, 0, stream>>>(W, W1, Wt, W1t, bcursor);
  k_gemm<<<(NN + 63) / 64, 256, 0, stream>>>(x, Wt, a, Whp8, s_src, s_tgt);
  k_score<<<NBLK, 256, 0, stream>>>(ei, s_src, s_tgt, bcursor, recs_mid, bmax, bsexp);
  k_stats<<<1, 256, 0, stream>>>(bmax, bsexp, softstat);
  k_sortB<<<NBLK, 256, 0, stream>>>(bcursor, recs_mid, softstat, recs, offs, cnt);
  k_gather<<<NN / 4, 256, 0, stream>>>(offs, cnt, recs, (const unsigned short*)Whp8, xnew);
  k_mlp<<<(NN + 63) / 64, 256, 0, stream>>>(xnew, W1t, b1, W2, b2, evid);
}

// Round 14
// 103.594 us; speedup vs baseline: 8.6194x; 1.0682x over previous
//
#include <hip/hip_runtime.h>
#include <hip/hip_bf16.h>
#include <math.h>

#define NN 50000
#define NE 800000
#define IND 256
#define OUTD 128
#define HIDD 64
#define NBLK 196   // number of 256-target coarse buckets (196*256 = 50176 >= NN)
#define BCAP 6144  // fixed bucket capacity (mean 4082, ~32 sigma headroom)

typedef __attribute__((ext_vector_type(8))) short short8;   // 8 bf16 (4 VGPR)
typedef __attribute__((ext_vector_type(4))) float f32x4;    // MFMA acc
typedef __attribute__((ext_vector_type(2))) float f32x2;    // fp8 cvt result

// ---------- helpers ----------
static __device__ __forceinline__ unsigned short f2bf_hw(float f) {  // HW cvt (RNE)
  __hip_bfloat16 h = __float2bfloat16(f);
  return __hip_bfloat16_raw(h).x;
}
static __device__ __forceinline__ float bf2f(unsigned b) {
  return __uint_as_float(b << 16);
}

// ---------- K0: Wt[n][k]=bf16(W[k][n]), W1t[h][k]=bf16(W1[k][h]), init cursors ----------
__global__ __launch_bounds__(256) void k_wconv(const float* __restrict__ W,
                                               const float* __restrict__ W1,
                                               unsigned short* __restrict__ Wt,
                                               unsigned short* __restrict__ W1t,
                                               int* __restrict__ bcursor) {
  if (blockIdx.x == 0 && threadIdx.x < NBLK)
    bcursor[threadIdx.x] = threadIdx.x * BCAP;       // fixed-capacity bases
  int t = blockIdx.x * 256 + threadIdx.x;     // 128 blocks
  int n = t >> 8, k = t & 255;
  Wt[t] = f2bf_hw(W[k * OUTD + n]);
  if (t < HIDD * OUTD) {                      // 8192: W1 transposed bf16
    int h = t >> 7, kk = t & 127;
    W1t[t] = f2bf_hw(W1[kk * HIDD + h]);
  }
}

// ---------- K1: MFMA GEMM (BK=64, 4 K-steps) -> fp8 Wh + fused s_src/s_tgt ----------
// BM=64, BN=128, 4 waves. LDS: A [64][72] bf16 (9.2KB) + B [128][72] bf16
// (18.4KB) = 27.6KB; Cs [64][132] f32 (33.8KB) aliases for epilogue.
// Halved barrier count vs BK=32 (8 vs 16 barrier drains).
__global__ __launch_bounds__(256) void k_gemm(const float* __restrict__ x,
                                              const unsigned short* __restrict__ Wt,
                                              const float* __restrict__ a,
                                              unsigned* __restrict__ Whp8,
                                              float* __restrict__ s_src,
                                              float* __restrict__ s_tgt) {
  __shared__ float smem[8448];                 // 33792 B
  short* As = (short*)smem;                    // [64][72] bf16
  short* Bs = As + 64 * 72;                    // [128][72] bf16
  float* Cs = smem;                            // [64][132] f32 (epilogue alias)

  const int tid  = threadIdx.x;
  const int bm   = blockIdx.x * 64;
  const int wave = tid >> 6;                   // 0..3 -> col block wave*32
  const int lane = tid & 63;
  const int l15  = lane & 15;
  const int lg   = lane >> 4;                  // 0..3

  f32x4 acc[4][2];
#pragma unroll
  for (int i = 0; i < 4; i++)
#pragma unroll
    for (int j = 0; j < 2; j++) acc[i][j] = (f32x4){0.f, 0.f, 0.f, 0.f};

  // A staging: thread -> row=t>>2, quarter q=t&3 (16 f32 -> 16 bf16)
  const int arow = tid >> 2, aq = tid & 3;
  long arow_g = bm + arow; if (arow_g >= NN) arow_g = NN - 1;   // clamp, writes guarded
  const float* xp = &x[arow_g * IND + aq * 16];
  short* asp = &As[arow * 72 + aq * 16];
  // B staging: thread -> n=t>>1, half h=t&1 (32 bf16 copy)
  const int bn = tid >> 1, bh = tid & 1;
  const unsigned short* wtp = &Wt[bn * 256 + bh * 32];
  short* bsp = &Bs[bn * 72 + bh * 32];

  for (int k0 = 0; k0 < IND; k0 += 64) {
    float4 va0 = *(const float4*)(xp + k0);
    float4 va1 = *(const float4*)(xp + k0 + 4);
    float4 va2 = *(const float4*)(xp + k0 + 8);
    float4 va3 = *(const float4*)(xp + k0 + 12);
    short8 apk0, apk1;
    apk0[0] = (short)f2bf_hw(va0.x); apk0[1] = (short)f2bf_hw(va0.y);
    apk0[2] = (short)f2bf_hw(va0.z); apk0[3] = (short)f2bf_hw(va0.w);
    apk0[4] = (short)f2bf_hw(va1.x); apk0[5] = (short)f2bf_hw(va1.y);
    apk0[6] = (short)f2bf_hw(va1.z); apk0[7] = (short)f2bf_hw(va1.w);
    apk1[0] = (short)f2bf_hw(va2.x); apk1[1] = (short)f2bf_hw(va2.y);
    apk1[2] = (short)f2bf_hw(va2.z); apk1[3] = (short)f2bf_hw(va2.w);
    apk1[4] = (short)f2bf_hw(va3.x); apk1[5] = (short)f2bf_hw(va3.y);
    apk1[6] = (short)f2bf_hw(va3.z); apk1[7] = (short)f2bf_hw(va3.w);
    *(short8*)asp       = apk0;
    *(short8*)(asp + 8) = apk1;
#pragma unroll
    for (int q = 0; q < 4; q++)
      *(short8*)(bsp + q * 8) = *(const short8*)(wtp + k0 + q * 8);
    __syncthreads();

    short8 af[4][2], bf[2][2];
#pragma unroll
    for (int mi = 0; mi < 4; mi++)
#pragma unroll
      for (int ks = 0; ks < 2; ks++)
        af[mi][ks] = *(const short8*)&As[(mi * 16 + l15) * 72 + ks * 32 + lg * 8];
#pragma unroll
    for (int ni = 0; ni < 2; ni++)
#pragma unroll
      for (int ks = 0; ks < 2; ks++)
        bf[ni][ks] = *(const short8*)&Bs[(wave * 32 + ni * 16 + l15) * 72 + ks * 32 + lg * 8];
#pragma unroll
    for (int ks = 0; ks < 2; ks++)
#pragma unroll
      for (int mi = 0; mi < 4; mi++)
#pragma unroll
        for (int ni = 0; ni < 2; ni++)
          acc[mi][ni] = __builtin_amdgcn_mfma_f32_16x16x32_bf16(
              af[mi][ks], bf[ni][ks], acc[mi][ni], 0, 0, 0);
    __syncthreads();
  }

  // epilogue: acc -> Cs (f32)
#pragma unroll
  for (int mi = 0; mi < 4; mi++)
#pragma unroll
    for (int ni = 0; ni < 2; ni++)
#pragma unroll
      for (int r = 0; r < 4; r++) {
        int row = mi * 16 + lg * 4 + r;
        int col = wave * 32 + ni * 16 + l15;
        Cs[row * 132 + col] = acc[mi][ni][r];
      }
  __syncthreads();

  // (a) fp8 row store: 1024 chunks of 8 f32 -> 8 fp8 bytes
#pragma unroll
  for (int i = 0; i < 4; i++) {
    int f = tid + i * 256;
    int nd = f >> 4, seg = f & 15;
    long gnode = bm + nd;
    if (gnode < NN) {
      float4 c0 = *(const float4*)&Cs[nd * 132 + seg * 8];
      float4 c1 = *(const float4*)&Cs[nd * 132 + seg * 8 + 4];
      int u0 = __builtin_amdgcn_cvt_pk_fp8_f32(c0.x, c0.y, 0, false);
      u0     = __builtin_amdgcn_cvt_pk_fp8_f32(c0.z, c0.w, u0, true);
      int u1 = __builtin_amdgcn_cvt_pk_fp8_f32(c1.x, c1.y, 0, false);
      u1     = __builtin_amdgcn_cvt_pk_fp8_f32(c1.z, c1.w, u1, true);
      *(uint2*)&Whp8[gnode * 32 + seg * 2] = make_uint2((unsigned)u0, (unsigned)u1);
    }
  }

  // (b) fused s_src/s_tgt: 4 threads per node, 32 cols each, shfl_xor reduce
  {
    const int nd = tid >> 2, p = tid & 3;
    float p1 = 0.f, p2 = 0.f;
    const float* crow = &Cs[nd * 132 + p * 32];
#pragma unroll
    for (int k = 0; k < 32; k++) {
      float c = crow[k];
      p1 = fmaf(c, a[p * 32 + k], p1);
      p2 = fmaf(c, a[128 + p * 32 + k], p2);
    }
    p1 += __shfl_xor(p1, 1); p1 += __shfl_xor(p1, 2);
    p2 += __shfl_xor(p2, 1); p2 += __shfl_xor(p2, 2);
    long gnode = bm + nd;
    if (p == 0 && gnode < NN) { s_src[gnode] = p1; s_tgt[gnode] = p2; }
  }
}

// ---------- K3: scores + DIRECT binning (fixed-capacity buckets) + block stats ----------
__global__ __launch_bounds__(256) void k_score(const int* __restrict__ ei,
                                               const float* __restrict__ s_src,
                                               const float* __restrict__ s_tgt,
                                               int* __restrict__ bcursor,
                                               int2* __restrict__ recs_mid,
                                               float* __restrict__ bmax,
                                               float* __restrict__ bsexp) {
  __shared__ int bh[NBLK];
  __shared__ int gbase[NBLK];
  __shared__ float red[4];
  __shared__ float bmx;
  const int tid = threadIdx.x;
  const long eb = (long)blockIdx.x * 4096;
  if (tid < NBLK) bh[tid] = 0;
  __syncthreads();

  int sv[16]; int tv[16]; float scv[16];
  float mx = -1e30f;
#pragma unroll
  for (int i = 0; i < 16; i++) {
    long e = eb + i * 256 + tid;
    float sc = -1e30f;
    if (e < NE) {
      int s = ei[e];
      int t = ei[NE + e];
      float v = s_src[s] + s_tgt[t];
      sc = v > 0.f ? v : 0.2f * v;              // leaky_relu(0.2)
      sv[i] = s; tv[i] = t;
      atomicAdd(&bh[t >> 8], 1);
    } else {
      tv[i] = -1;
    }
    scv[i] = sc;
    mx = fmaxf(mx, sc);
  }
  __syncthreads();
  if (tid < NBLK) {
    int c = bh[tid];
    gbase[tid] = (c > 0) ? atomicAdd(&bcursor[tid], c) : 0;
    bh[tid] = 0;                               // reuse as local cursor
  }
  __syncthreads();
#pragma unroll
  for (int i = 0; i < 16; i++) {
    if (tv[i] >= 0) {
      int b = tv[i] >> 8;
      int off = atomicAdd(&bh[b], 1);
      recs_mid[gbase[b] + off] = make_int2(sv[i] | ((tv[i] & 255) << 16),
                                           __float_as_int(scv[i]));
    }
  }

  // per-block softmax stats
#pragma unroll
  for (int off = 32; off; off >>= 1) mx = fmaxf(mx, __shfl_down(mx, off));
  int w = tid >> 6, lane = tid & 63;
  if (lane == 0) red[w] = mx;
  __syncthreads();
  if (tid == 0) bmx = fmaxf(fmaxf(red[0], red[1]), fmaxf(red[2], red[3]));
  __syncthreads();
  const float M = bmx;
  float s = 0.f;
#pragma unroll
  for (int i = 0; i < 16; i++) s += __expf(scv[i] - M);   // invalid lanes -> 0
#pragma unroll
  for (int off = 32; off; off >>= 1) s += __shfl_down(s, off);
  if (lane == 0) red[w] = s;
  __syncthreads();
  if (tid == 0) {
    bmax[blockIdx.x] = M;
    bsexp[blockIdx.x] = red[0] + red[1] + red[2] + red[3];
  }
}

// ---------- K6: stats combine (per-block, redundant) + in-bucket LDS sort ----------
// Record out: src(16b) | bf16(alpha)<<16.
__global__ __launch_bounds__(256) void k_sortB(const int* __restrict__ bcursor,
                                               const int2* __restrict__ recs_mid,
                                               const float* __restrict__ bmax,
                                               const float* __restrict__ bsexp,
                                               unsigned* __restrict__ recs,
                                               int* __restrict__ offs,
                                               int* __restrict__ cnt) {
  __shared__ float fred[256];
  __shared__ int h[256], sc[256], cur[256];
  __shared__ unsigned srt[BCAP];
  const int tid = threadIdx.x;
  const int b = blockIdx.x;
  const int base = b * BCAP;
  const int m = bcursor[b] - base;

  // global softmax stats (redundant 196-way reduce; L2-hit reads)
  float mv = (tid < NBLK) ? bmax[tid] : -1e30f;
  fred[tid] = mv;
  __syncthreads();
  for (int off = 128; off; off >>= 1) {
    if (tid < off) fred[tid] = fmaxf(fred[tid], fred[tid + off]);
    __syncthreads();
  }
  const float M = fred[0];
  __syncthreads();
  float se = (tid < NBLK) ? bsexp[tid] * __expf(bmax[tid] - M) : 0.f;
  fred[tid] = se;
  __syncthreads();
  for (int off = 128; off; off >>= 1) {
    if (tid < off) fred[tid] += fred[tid + off];
    __syncthreads();
  }
  const float inv = 1.0f / fred[0];

  h[tid] = 0;
  __syncthreads();
  for (int i = tid; i < m; i += 256) {
    int2 r = recs_mid[base + i];
    atomicAdd(&h[(r.x >> 16) & 255], 1);
  }
  __syncthreads();
  sc[tid] = h[tid];
  __syncthreads();
  for (int off = 1; off < 256; off <<= 1) {
    int t = (tid >= off) ? sc[tid - off] : 0;
    __syncthreads();
    sc[tid] += t;
    __syncthreads();
  }
  int excl = sc[tid] - h[tid];
  cur[tid] = excl;
  offs[b * 256 + tid] = base + excl;           // global per-target offsets
  cnt[b * 256 + tid] = h[tid];
  __syncthreads();
  for (int i = tid; i < m; i += 256) {
    int2 r = recs_mid[base + i];
    int tl = (r.x >> 16) & 255;
    int p = atomicAdd(&cur[tl], 1);
    float al = __expf(__int_as_float(r.y) - M) * inv;
    if (p < BCAP)
      srt[p] = (unsigned)(r.x & 0xffff) | ((unsigned)f2bf_hw(al) << 16);
  }
  __syncthreads();
  for (int i = tid; i < m; i += 256)
    recs[base + i] = srt[i];                   // coalesced 4B records
}

// ---------- K7: gather-sum per target node (one wave per node, fp8 rows, 8-deep) ----------
__global__ __launch_bounds__(256) void k_gather(const int* __restrict__ offs,
                                                const int* __restrict__ cnt,
                                                const unsigned* __restrict__ recs,
                                                const unsigned short* __restrict__ Whp8,
                                                float* __restrict__ xnew) {
  int wid = (blockIdx.x * 256 + threadIdx.x) >> 6;    // 12500*4 = NN waves
  int lane = threadIdx.x & 63;
  int start = offs[wid];
  int n = cnt[wid];
  float2 acc = make_float2(0.f, 0.f);
  for (int base = 0; base < n; base += 64) {
    int m = n - base; if (m > 64) m = 64;
    int li = lane < m ? lane : m - 1;
    unsigned r = recs[start + base + li];             // coalesced chunk load
    for (int i = 0; i < m; i += 8) {                  // 8 row-loads in flight
      unsigned rv[8];
#pragma unroll
      for (int j = 0; j < 8; j++) rv[j] = __shfl(r, i + j);
      unsigned short v[8];
#pragma unroll
      for (int j = 0; j < 8; j++)
        v[j] = Whp8[(long)(rv[j] & 0xffffu) * 64 + lane];  // 2 fp8/lane
#pragma unroll
      for (int j = 0; j < 8; j++) {
        float al = (i + j < m) ? bf2f(rv[j] >> 16) : 0.f;
        f32x2 w = __builtin_amdgcn_cvt_pk_f32_fp8((int)(unsigned)v[j], false);
        acc.x = fmaf(al, w[0], acc.x);
        acc.y = fmaf(al, w[1], acc.y);
      }
    }
  }
  ((float2*)xnew)[(long)wid * 64 + lane] = acc;
}

// ---------- K8: MLP head, layer-1 via MFMA bf16 (BM=32 for 2x grid parallelism) ----------
// 32 nodes/block, 4 waves. LDS: x bf16 [32][136] (8.7KB) + W1t bf16 [64][136]
// (17.4KB) = 26.1KB. Wave w owns hid cols w*16..+15; 2 m-frags; 8 MFMA/wave.
__global__ __launch_bounds__(256) void k_mlp(const float* __restrict__ xnew,
                                             const unsigned short* __restrict__ W1t,
                                             const float* __restrict__ b1,
                                             const float* __restrict__ W2,
                                             const float* __restrict__ b2,
                                             float* __restrict__ evid) {
  __shared__ short smem[13056];                // 26112 B
  short* As = smem;                            // [32][136] bf16 x-tile
  short* Bs = smem + 32 * 136;                 // [64][136] bf16 W1t (hid-major)
  float* Cs = (float*)smem;                    // [32][68] f32 h (aliases As)

  const int tid = threadIdx.x;
  const int nb = blockIdx.x * 32;
  const int wave = tid >> 6;
  const int lane = tid & 63;
  const int l15 = lane & 15, lg = lane >> 4;

  // stage x -> bf16 (16 elems/thread) and W1t copy (32 shorts/thread)
  {
    int row = tid >> 3, seg = tid & 7;         // 32 rows x 8 segs of 16
    long g = nb + row; if (g >= NN) g = NN - 1;
    const float* xp = &xnew[g * OUTD + seg * 16];
    short* dst = &As[row * 136 + seg * 16];
#pragma unroll
    for (int q = 0; q < 2; q++) {
      float4 v0 = *(const float4*)(xp + q * 8);
      float4 v1 = *(const float4*)(xp + q * 8 + 4);
      short8 pk;
      pk[0] = (short)f2bf_hw(v0.x); pk[1] = (short)f2bf_hw(v0.y);
      pk[2] = (short)f2bf_hw(v0.z); pk[3] = (short)f2bf_hw(v0.w);
      pk[4] = (short)f2bf_hw(v1.x); pk[5] = (short)f2bf_hw(v1.y);
      pk[6] = (short)f2bf_hw(v1.z); pk[7] = (short)f2bf_hw(v1.w);
      *(short8*)(dst + q * 8) = pk;
    }
    int wrow = tid >> 2, wseg = tid & 3;       // 64 rows x 4 segs of 32
    const unsigned short* wp = &W1t[wrow * 128 + wseg * 32];
    short* wdst = &Bs[wrow * 136 + wseg * 32];
#pragma unroll
    for (int q = 0; q < 4; q++)
      *(short8*)(wdst + q * 8) = *(const short8*)(wp + q * 8);
  }
  __syncthreads();

  f32x4 acc[2];
#pragma unroll
  for (int mi = 0; mi < 2; mi++) acc[mi] = (f32x4){0.f, 0.f, 0.f, 0.f};
#pragma unroll
  for (int ks = 0; ks < 4; ks++) {
    short8 bfr = *(const short8*)&Bs[(wave * 16 + l15) * 136 + ks * 32 + lg * 8];
#pragma unroll
    for (int mi = 0; mi < 2; mi++) {
      short8 afr = *(const short8*)&As[(mi * 16 + l15) * 136 + ks * 32 + lg * 8];
      acc[mi] = __builtin_amdgcn_mfma_f32_16x16x32_bf16(afr, bfr, acc[mi], 0, 0, 0);
    }
  }
  __syncthreads();                             // As dead; alias as Cs
#pragma unroll
  for (int mi = 0; mi < 2; mi++)
#pragma unroll
    for (int r = 0; r < 4; r++) {
      int row = mi * 16 + lg * 4 + r;
      int col = wave * 16 + l15;
      Cs[row * 68 + col] = acc[mi][r];
    }
  __syncthreads();

  // layer 2 fused from Cs: 32 nodes, ty covers 2 rows each
  const int ty = tid >> 4, tx = tid & 15;
  float b1r[4], w2r[4][3];
#pragma unroll
  for (int j = 0; j < 4; j++) {
    int jg = tx * 4 + j;
    b1r[j] = b1[jg];
    w2r[j][0] = W2[jg * 3 + 0];
    w2r[j][1] = W2[jg * 3 + 1];
    w2r[j][2] = W2[jg * 3 + 2];
  }
#pragma unroll
  for (int i = 0; i < 2; i++) {
    float p0 = 0.f, p1 = 0.f, p2 = 0.f;
#pragma unroll
    for (int j = 0; j < 4; j++) {
      float h = fmaxf(Cs[(ty * 2 + i) * 68 + tx * 4 + j] + b1r[j], 0.f);
      p0 = fmaf(h, w2r[j][0], p0);
      p1 = fmaf(h, w2r[j][1], p1);
      p2 = fmaf(h, w2r[j][2], p2);
    }
#pragma unroll
    for (int m = 1; m < 16; m <<= 1) {
      p0 += __shfl_xor(p0, m);
      p1 += __shfl_xor(p1, m);
      p2 += __shfl_xor(p2, m);
    }
    if (tx == 0) {
      int n = nb + ty * 2 + i;
      if (n < NN) {
        float e0 = p0 + b2[0], e1 = p1 + b2[1], e2 = p2 + b2[2];
        float s0 = e0 > 20.f ? e0 : log1pf(expf(e0));
        float s1 = e1 > 20.f ? e1 : log1pf(expf(e1));
        float s2 = e2 > 20.f ? e2 : log1pf(expf(e2));
        evid[(long)n * 3 + 0] = s0 + 1.0f;
        evid[(long)n * 3 + 1] = s1 + 1.0f;
        evid[(long)n * 3 + 2] = s2 + 1.0f;
      }
    }
  }
}

extern "C" void kernel_launch(void* const* d_in, const int* in_sizes, int n_in,
                              void* d_out, int out_size, void* d_ws, size_t ws_size,
                              hipStream_t stream) {
  const float* x   = (const float*)d_in[0];
  const int*   ei  = (const int*)d_in[1];
  const float* W   = (const float*)d_in[2];
  const float* a   = (const float*)d_in[3];
  const float* W1  = (const float*)d_in[4];
  const float* b1  = (const float*)d_in[5];
  const float* W2  = (const float*)d_in[6];
  const float* b2  = (const float*)d_in[7];

  float* xnew = (float*)d_out;                       // [NN*OUTD]
  float* evid = (float*)d_out + (size_t)NN * OUTD;   // [NN*3]

  float* wsf = (float*)d_ws;
  unsigned* Whp8     = (unsigned*)wsf;               // 1,600,000 u32 (6.4 MB fp8 Wh)
  float*    s_src    = wsf + 1600000;                //    50,000 f
  float*    s_tgt    = wsf + 1650000;                //    50,000 f
  int2*     recs_mid = (int2*)(wsf + 1700000);       // 1,204,224 int2 (9.6 MB)
  unsigned* recs     = (unsigned*)(wsf + 4108448);   // 1,204,224 u32 (4.8 MB)
  int*      offs     = (int*)(wsf + 5312672);        //    50,176 i
  int*      cnt      = (int*)(wsf + 5362848);        //    50,176 i
  int*      bcursor  = (int*)(wsf + 5413024);        //       196 i
  float*    bmax     = wsf + 5413220;                //       196 f
  float*    bsexp    = wsf + 5413416;                //       196 f
  unsigned short* Wt  = (unsigned short*)(wsf + 5413616);  // 32,768 bf16
  unsigned short* W1t = (unsigned short*)(wsf + 5430000);  // 8,192 bf16 (end ~21.7 MB)

  k_wconv<<<128, 256, 0, stream>>>(W, W1, Wt, W1t, bcursor);
  k_gemm<<<(NN + 63) / 64, 256, 0, stream>>>(x, Wt, a, Whp8, s_src, s_tgt);
  k_score<<<NBLK, 256, 0, stream>>>(ei, s_src, s_tgt, bcursor, recs_mid, bmax, bsexp);
  k_sortB<<<NBLK, 256, 0, stream>>>(bcursor, recs_mid, bmax, bsexp, recs, offs, cnt);
  k_gather<<<NN / 4, 256, 0, stream>>>(offs, cnt, recs, (const unsigned short*)Whp8, xnew);
  k_mlp<<<(NN + 31) / 32, 256, 0, stream>>>(xnew, W1t, b1, W2, b2, evid);
}

// Round 15
// 100.839 us; speedup vs baseline: 8.8549x; 1.0273x over previous
//
#include <hip/hip_runtime.h>
#include <hip/hip_bf16.h>
#include <math.h>

#define NN 50000
#define NE 800000
#define IND 256
#define OUTD 128
#define HIDD 64
#define NBLK 196   // number of 256-target coarse buckets (196*256 = 50176 >= NN)
#define BCAP 6144  // fixed bucket capacity (mean 4082, ~32 sigma headroom)

typedef __attribute__((ext_vector_type(8))) short short8;   // 8 bf16 (4 VGPR)
typedef __attribute__((ext_vector_type(4))) float f32x4;    // MFMA acc
typedef __attribute__((ext_vector_type(2))) float f32x2;    // fp8 cvt result

// ---------- helpers ----------
static __device__ __forceinline__ unsigned short f2bf_hw(float f) {  // HW cvt (RNE)
  __hip_bfloat16 h = __float2bfloat16(f);
  return __hip_bfloat16_raw(h).x;
}
static __device__ __forceinline__ float bf2f(unsigned b) {
  return __uint_as_float(b << 16);
}

// ---------- K0: Wt[n][k]=bf16(W[k][n]), W1t[h][k]=bf16(W1[k][h]), init cursors ----------
__global__ __launch_bounds__(256) void k_wconv(const float* __restrict__ W,
                                               const float* __restrict__ W1,
                                               unsigned short* __restrict__ Wt,
                                               unsigned short* __restrict__ W1t,
                                               int* __restrict__ bcursor) {
  if (blockIdx.x == 0 && threadIdx.x < NBLK)
    bcursor[threadIdx.x] = threadIdx.x * BCAP;       // fixed-capacity bases
  int t = blockIdx.x * 256 + threadIdx.x;     // 128 blocks
  int n = t >> 8, k = t & 255;
  Wt[t] = f2bf_hw(W[k * OUTD + n]);
  if (t < HIDD * OUTD) {                      // 8192: W1 transposed bf16
    int h = t >> 7, kk = t & 127;
    W1t[t] = f2bf_hw(W1[kk * HIDD + h]);
  }
}

// ---------- K1: MFMA GEMM (BM=32, BK=64) -> fp8 Wh + fused s_src/s_tgt ----------
// BM=32 doubles grid to 1563 blocks (~6.1/CU) for latency hiding; LDS 23KB:
// A [32][72] bf16 (4.6KB) + B [128][72] bf16 (18.4KB); Cs [32][132] f32
// (16.9KB) aliases for epilogue. 4 waves, wave w owns cols w*32 (2 n-frags),
// 2 m-frags, 8 MFMA per K-step, 4 K-steps.
__global__ __launch_bounds__(256) void k_gemm(const float* __restrict__ x,
                                              const unsigned short* __restrict__ Wt,
                                              const float* __restrict__ a,
                                              unsigned* __restrict__ Whp8,
                                              float* __restrict__ s_src,
                                              float* __restrict__ s_tgt) {
  __shared__ float smem[5760];                 // 23040 B
  short* As = (short*)smem;                    // [32][72] bf16
  short* Bs = As + 32 * 72;                    // [128][72] bf16
  float* Cs = smem;                            // [32][132] f32 (epilogue alias)

  const int tid  = threadIdx.x;
  const int bm   = blockIdx.x * 32;
  const int wave = tid >> 6;                   // 0..3 -> col block wave*32
  const int lane = tid & 63;
  const int l15  = lane & 15;
  const int lg   = lane >> 4;                  // 0..3

  f32x4 acc[2][2];
#pragma unroll
  for (int i = 0; i < 2; i++)
#pragma unroll
    for (int j = 0; j < 2; j++) acc[i][j] = (f32x4){0.f, 0.f, 0.f, 0.f};

  // A staging: thread -> row=t>>3 (32 rows), octet q=t&7 (8 f32 -> 8 bf16)
  const int arow = tid >> 3, aq = tid & 7;
  long arow_g = bm + arow; if (arow_g >= NN) arow_g = NN - 1;   // clamp, writes guarded
  const float* xp = &x[arow_g * IND + aq * 8];
  short* asp = &As[arow * 72 + aq * 8];
  // B staging: thread -> n=t>>1, half h=t&1 (32 bf16 copy)
  const int bn = tid >> 1, bh = tid & 1;
  const unsigned short* wtp = &Wt[bn * 256 + bh * 32];
  short* bsp = &Bs[bn * 72 + bh * 32];

  for (int k0 = 0; k0 < IND; k0 += 64) {
    float4 va0 = *(const float4*)(xp + k0);
    float4 va1 = *(const float4*)(xp + k0 + 4);
    short8 apk;
    apk[0] = (short)f2bf_hw(va0.x); apk[1] = (short)f2bf_hw(va0.y);
    apk[2] = (short)f2bf_hw(va0.z); apk[3] = (short)f2bf_hw(va0.w);
    apk[4] = (short)f2bf_hw(va1.x); apk[5] = (short)f2bf_hw(va1.y);
    apk[6] = (short)f2bf_hw(va1.z); apk[7] = (short)f2bf_hw(va1.w);
    *(short8*)asp = apk;
#pragma unroll
    for (int q = 0; q < 4; q++)
      *(short8*)(bsp + q * 8) = *(const short8*)(wtp + k0 + q * 8);
    __syncthreads();

    short8 af[2][2], bf[2][2];
#pragma unroll
    for (int mi = 0; mi < 2; mi++)
#pragma unroll
      for (int ks = 0; ks < 2; ks++)
        af[mi][ks] = *(const short8*)&As[(mi * 16 + l15) * 72 + ks * 32 + lg * 8];
#pragma unroll
    for (int ni = 0; ni < 2; ni++)
#pragma unroll
      for (int ks = 0; ks < 2; ks++)
        bf[ni][ks] = *(const short8*)&Bs[(wave * 32 + ni * 16 + l15) * 72 + ks * 32 + lg * 8];
#pragma unroll
    for (int ks = 0; ks < 2; ks++)
#pragma unroll
      for (int mi = 0; mi < 2; mi++)
#pragma unroll
        for (int ni = 0; ni < 2; ni++)
          acc[mi][ni] = __builtin_amdgcn_mfma_f32_16x16x32_bf16(
              af[mi][ks], bf[ni][ks], acc[mi][ni], 0, 0, 0);
    __syncthreads();
  }

  // epilogue: acc -> Cs (f32)
#pragma unroll
  for (int mi = 0; mi < 2; mi++)
#pragma unroll
    for (int ni = 0; ni < 2; ni++)
#pragma unroll
      for (int r = 0; r < 4; r++) {
        int row = mi * 16 + lg * 4 + r;
        int col = wave * 32 + ni * 16 + l15;
        Cs[row * 132 + col] = acc[mi][ni][r];
      }
  __syncthreads();

  // (a) fp8 row store: 512 chunks of 8 f32 -> 8 fp8 bytes (2 per thread)
#pragma unroll
  for (int i = 0; i < 2; i++) {
    int f = tid + i * 256;
    int nd = f >> 4, seg = f & 15;
    long gnode = bm + nd;
    if (gnode < NN) {
      float4 c0 = *(const float4*)&Cs[nd * 132 + seg * 8];
      float4 c1 = *(const float4*)&Cs[nd * 132 + seg * 8 + 4];
      int u0 = __builtin_amdgcn_cvt_pk_fp8_f32(c0.x, c0.y, 0, false);
      u0     = __builtin_amdgcn_cvt_pk_fp8_f32(c0.z, c0.w, u0, true);
      int u1 = __builtin_amdgcn_cvt_pk_fp8_f32(c1.x, c1.y, 0, false);
      u1     = __builtin_amdgcn_cvt_pk_fp8_f32(c1.z, c1.w, u1, true);
      *(uint2*)&Whp8[gnode * 32 + seg * 2] = make_uint2((unsigned)u0, (unsigned)u1);
    }
  }

  // (b) fused s_src/s_tgt: 8 threads per node, 16 cols each, shfl_xor reduce
  {
    const int nd = tid >> 3, p = tid & 7;
    float p1 = 0.f, p2 = 0.f;
    const float* crow = &Cs[nd * 132 + p * 16];
#pragma unroll
    for (int k = 0; k < 16; k++) {
      float c = crow[k];
      p1 = fmaf(c, a[p * 16 + k], p1);
      p2 = fmaf(c, a[128 + p * 16 + k], p2);
    }
    p1 += __shfl_xor(p1, 1); p1 += __shfl_xor(p1, 2); p1 += __shfl_xor(p1, 4);
    p2 += __shfl_xor(p2, 1); p2 += __shfl_xor(p2, 2); p2 += __shfl_xor(p2, 4);
    long gnode = bm + nd;
    if (p == 0 && gnode < NN) { s_src[gnode] = p1; s_tgt[gnode] = p2; }
  }
}

// ---------- K3: scores + DIRECT binning (fixed-capacity buckets) + block stats ----------
__global__ __launch_bounds__(256) void k_score(const int* __restrict__ ei,
                                               const float* __restrict__ s_src,
                                               const float* __restrict__ s_tgt,
                                               int* __restrict__ bcursor,
                                               int2* __restrict__ recs_mid,
                                               float* __restrict__ bmax,
                                               float* __restrict__ bsexp) {
  __shared__ int bh[NBLK];
  __shared__ int gbase[NBLK];
  __shared__ float red[4];
  __shared__ float bmx;
  const int tid = threadIdx.x;
  const long eb = (long)blockIdx.x * 4096;
  if (tid < NBLK) bh[tid] = 0;
  __syncthreads();

  int sv[16]; int tv[16]; float scv[16];
  float mx = -1e30f;
#pragma unroll
  for (int i = 0; i < 16; i++) {
    long e = eb + i * 256 + tid;
    float sc = -1e30f;
    if (e < NE) {
      int s = ei[e];
      int t = ei[NE + e];
      float v = s_src[s] + s_tgt[t];
      sc = v > 0.f ? v : 0.2f * v;              // leaky_relu(0.2)
      sv[i] = s; tv[i] = t;
      atomicAdd(&bh[t >> 8], 1);
    } else {
      tv[i] = -1;
    }
    scv[i] = sc;
    mx = fmaxf(mx, sc);
  }
  __syncthreads();
  if (tid < NBLK) {
    int c = bh[tid];
    gbase[tid] = (c > 0) ? atomicAdd(&bcursor[tid], c) : 0;
    bh[tid] = 0;                               // reuse as local cursor
  }
  __syncthreads();
#pragma unroll
  for (int i = 0; i < 16; i++) {
    if (tv[i] >= 0) {
      int b = tv[i] >> 8;
      int off = atomicAdd(&bh[b], 1);
      recs_mid[gbase[b] + off] = make_int2(sv[i] | ((tv[i] & 255) << 16),
                                           __float_as_int(scv[i]));
    }
  }

  // per-block softmax stats
#pragma unroll
  for (int off = 32; off; off >>= 1) mx = fmaxf(mx, __shfl_down(mx, off));
  int w = tid >> 6, lane = tid & 63;
  if (lane == 0) red[w] = mx;
  __syncthreads();
  if (tid == 0) bmx = fmaxf(fmaxf(red[0], red[1]), fmaxf(red[2], red[3]));
  __syncthreads();
  const float M = bmx;
  float s = 0.f;
#pragma unroll
  for (int i = 0; i < 16; i++) s += __expf(scv[i] - M);   // invalid lanes -> 0
#pragma unroll
  for (int off = 32; off; off >>= 1) s += __shfl_down(s, off);
  if (lane == 0) red[w] = s;
  __syncthreads();
  if (tid == 0) {
    bmax[blockIdx.x] = M;
    bsexp[blockIdx.x] = red[0] + red[1] + red[2] + red[3];
  }
}

// ---------- K6: stats combine (per-block, redundant) + in-bucket LDS sort ----------
// Record out: src(16b) | bf16(alpha)<<16.
__global__ __launch_bounds__(256) void k_sortB(const int* __restrict__ bcursor,
                                               const int2* __restrict__ recs_mid,
                                               const float* __restrict__ bmax,
                                               const float* __restrict__ bsexp,
                                               unsigned* __restrict__ recs,
                                               int* __restrict__ offs,
                                               int* __restrict__ cnt) {
  __shared__ float fred[256];
  __shared__ int h[256], sc[256], cur[256];
  __shared__ unsigned srt[BCAP];
  const int tid = threadIdx.x;
  const int b = blockIdx.x;
  const int base = b * BCAP;
  const int m = bcursor[b] - base;

  // global softmax stats (redundant 196-way reduce; L2-hit reads)
  float mv = (tid < NBLK) ? bmax[tid] : -1e30f;
  fred[tid] = mv;
  __syncthreads();
  for (int off = 128; off; off >>= 1) {
    if (tid < off) fred[tid] = fmaxf(fred[tid], fred[tid + off]);
    __syncthreads();
  }
  const float M = fred[0];
  __syncthreads();
  float se = (tid < NBLK) ? bsexp[tid] * __expf(bmax[tid] - M) : 0.f;
  fred[tid] = se;
  __syncthreads();
  for (int off = 128; off; off >>= 1) {
    if (tid < off) fred[tid] += fred[tid + off];
    __syncthreads();
  }
  const float inv = 1.0f / fred[0];

  h[tid] = 0;
  __syncthreads();
  for (int i = tid; i < m; i += 256) {
    int2 r = recs_mid[base + i];
    atomicAdd(&h[(r.x >> 16) & 255], 1);
  }
  __syncthreads();
  sc[tid] = h[tid];
  __syncthreads();
  for (int off = 1; off < 256; off <<= 1) {
    int t = (tid >= off) ? sc[tid - off] : 0;
    __syncthreads();
    sc[tid] += t;
    __syncthreads();
  }
  int excl = sc[tid] - h[tid];
  cur[tid] = excl;
  offs[b * 256 + tid] = base + excl;           // global per-target offsets
  cnt[b * 256 + tid] = h[tid];
  __syncthreads();
  for (int i = tid; i < m; i += 256) {
    int2 r = recs_mid[base + i];
    int tl = (r.x >> 16) & 255;
    int p = atomicAdd(&cur[tl], 1);
    float al = __expf(__int_as_float(r.y) - M) * inv;
    if (p < BCAP)
      srt[p] = (unsigned)(r.x & 0xffff) | ((unsigned)f2bf_hw(al) << 16);
  }
  __syncthreads();
  for (int i = tid; i < m; i += 256)
    recs[base + i] = srt[i];                   // coalesced 4B records
}

// ---------- K7: gather-sum per target node (one wave per node, fp8 rows, 8-deep) ----------
__global__ __launch_bounds__(256) void k_gather(const int* __restrict__ offs,
                                                const int* __restrict__ cnt,
                                                const unsigned* __restrict__ recs,
                                                const unsigned short* __restrict__ Whp8,
                                                float* __restrict__ xnew) {
  int wid = (blockIdx.x * 256 + threadIdx.x) >> 6;    // 12500*4 = NN waves
  int lane = threadIdx.x & 63;
  int start = offs[wid];
  int n = cnt[wid];
  float2 acc = make_float2(0.f, 0.f);
  for (int base = 0; base < n; base += 64) {
    int m = n - base; if (m > 64) m = 64;
    int li = lane < m ? lane : m - 1;
    unsigned r = recs[start + base + li];             // coalesced chunk load
    for (int i = 0; i < m; i += 8) {                  // 8 row-loads in flight
      unsigned rv[8];
#pragma unroll
      for (int j = 0; j < 8; j++) rv[j] = __shfl(r, i + j);
      unsigned short v[8];
#pragma unroll
      for (int j = 0; j < 8; j++)
        v[j] = Whp8[(long)(rv[j] & 0xffffu) * 64 + lane];  // 2 fp8/lane
#pragma unroll
      for (int j = 0; j < 8; j++) {
        float al = (i + j < m) ? bf2f(rv[j] >> 16) : 0.f;
        f32x2 w = __builtin_amdgcn_cvt_pk_f32_fp8((int)(unsigned)v[j], false);
        acc.x = fmaf(al, w[0], acc.x);
        acc.y = fmaf(al, w[1], acc.y);
      }
    }
  }
  ((float2*)xnew)[(long)wid * 64 + lane] = acc;
}

// ---------- K8: MLP head, layer-1 via MFMA bf16 (BM=32) ----------
__global__ __launch_bounds__(256) void k_mlp(const float* __restrict__ xnew,
                                             const unsigned short* __restrict__ W1t,
                                             const float* __restrict__ b1,
                                             const float* __restrict__ W2,
                                             const float* __restrict__ b2,
                                             float* __restrict__ evid) {
  __shared__ short smem[13056];                // 26112 B
  short* As = smem;                            // [32][136] bf16 x-tile
  short* Bs = smem + 32 * 136;                 // [64][136] bf16 W1t (hid-major)
  float* Cs = (float*)smem;                    // [32][68] f32 h (aliases As)

  const int tid = threadIdx.x;
  const int nb = blockIdx.x * 32;
  const int wave = tid >> 6;
  const int lane = tid & 63;
  const int l15 = lane & 15, lg = lane >> 4;

  // stage x -> bf16 (16 elems/thread) and W1t copy (32 shorts/thread)
  {
    int row = tid >> 3, seg = tid & 7;         // 32 rows x 8 segs of 16
    long g = nb + row; if (g >= NN) g = NN - 1;
    const float* xp = &xnew[g * OUTD + seg * 16];
    short* dst = &As[row * 136 + seg * 16];
#pragma unroll
    for (int q = 0; q < 2; q++) {
      float4 v0 = *(const float4*)(xp + q * 8);
      float4 v1 = *(const float4*)(xp + q * 8 + 4);
      short8 pk;
      pk[0] = (short)f2bf_hw(v0.x); pk[1] = (short)f2bf_hw(v0.y);
      pk[2] = (short)f2bf_hw(v0.z); pk[3] = (short)f2bf_hw(v0.w);
      pk[4] = (short)f2bf_hw(v1.x); pk[5] = (short)f2bf_hw(v1.y);
      pk[6] = (short)f2bf_hw(v1.z); pk[7] = (short)f2bf_hw(v1.w);
      *(short8*)(dst + q * 8) = pk;
    }
    int wrow = tid >> 2, wseg = tid & 3;       // 64 rows x 4 segs of 32
    const unsigned short* wp = &W1t[wrow * 128 + wseg * 32];
    short* wdst = &Bs[wrow * 136 + wseg * 32];
#pragma unroll
    for (int q = 0; q < 4; q++)
      *(short8*)(wdst + q * 8) = *(const short8*)(wp + q * 8);
  }
  __syncthreads();

  f32x4 acc[2];
#pragma unroll
  for (int mi = 0; mi < 2; mi++) acc[mi] = (f32x4){0.f, 0.f, 0.f, 0.f};
#pragma unroll
  for (int ks = 0; ks < 4; ks++) {
    short8 bfr = *(const short8*)&Bs[(wave * 16 + l15) * 136 + ks * 32 + lg * 8];
#pragma unroll
    for (int mi = 0; mi < 2; mi++) {
      short8 afr = *(const short8*)&As[(mi * 16 + l15) * 136 + ks * 32 + lg * 8];
      acc[mi] = __builtin_amdgcn_mfma_f32_16x16x32_bf16(afr, bfr, acc[mi], 0, 0, 0);
    }
  }
  __syncthreads();                             // As dead; alias as Cs
#pragma unroll
  for (int mi = 0; mi < 2; mi++)
#pragma unroll
    for (int r = 0; r < 4; r++) {
      int row = mi * 16 + lg * 4 + r;
      int col = wave * 16 + l15;
      Cs[row * 68 + col] = acc[mi][r];
    }
  __syncthreads();

  // layer 2 fused from Cs: 32 nodes, ty covers 2 rows each
  const int ty = tid >> 4, tx = tid & 15;
  float b1r[4], w2r[4][3];
#pragma unroll
  for (int j = 0; j < 4; j++) {
    int jg = tx * 4 + j;
    b1r[j] = b1[jg];
    w2r[j][0] = W2[jg * 3 + 0];
    w2r[j][1] = W2[jg * 3 + 1];
    w2r[j][2] = W2[jg * 3 + 2];
  }
#pragma unroll
  for (int i = 0; i < 2; i++) {
    float p0 = 0.f, p1 = 0.f, p2 = 0.f;
#pragma unroll
    for (int j = 0; j < 4; j++) {
      float h = fmaxf(Cs[(ty * 2 + i) * 68 + tx * 4 + j] + b1r[j], 0.f);
      p0 = fmaf(h, w2r[j][0], p0);
      p1 = fmaf(h, w2r[j][1], p1);
      p2 = fmaf(h, w2r[j][2], p2);
    }
#pragma unroll
    for (int m = 1; m < 16; m <<= 1) {
      p0 += __shfl_xor(p0, m);
      p1 += __shfl_xor(p1, m);
      p2 += __shfl_xor(p2, m);
    }
    if (tx == 0) {
      int n = nb + ty * 2 + i;
      if (n < NN) {
        float e0 = p0 + b2[0], e1 = p1 + b2[1], e2 = p2 + b2[2];
        float s0 = e0 > 20.f ? e0 : log1pf(expf(e0));
        float s1 = e1 > 20.f ? e1 : log1pf(expf(e1));
        float s2 = e2 > 20.f ? e2 : log1pf(expf(e2));
        evid[(long)n * 3 + 0] = s0 + 1.0f;
        evid[(long)n * 3 + 1] = s1 + 1.0f;
        evid[(long)n * 3 + 2] = s2 + 1.0f;
      }
    }
  }
}

extern "C" void kernel_launch(void* const* d_in, const int* in_sizes, int n_in,
                              void* d_out, int out_size, void* d_ws, size_t ws_size,
                              hipStream_t stream) {
  const float* x   = (const float*)d_in[0];
  const int*   ei  = (const int*)d_in[1];
  const float* W   = (const float*)d_in[2];
  const float* a   = (const float*)d_in[3];
  const float* W1  = (const float*)d_in[4];
  const float* b1  = (const float*)d_in[5];
  const float* W2  = (const float*)d_in[6];
  const float* b2  = (const float*)d_in[7];

  float* xnew = (float*)d_out;                       // [NN*OUTD]
  float* evid = (float*)d_out + (size_t)NN * OUTD;   // [NN*3]

  float* wsf = (float*)d_ws;
  unsigned* Whp8     = (unsigned*)wsf;               // 1,600,000 u32 (6.4 MB fp8 Wh)
  float*    s_src    = wsf + 1600000;                //    50,000 f
  float*    s_tgt    = wsf + 1650000;                //    50,000 f
  int2*     recs_mid = (int2*)(wsf + 1700000);       // 1,204,224 int2 (9.6 MB)
  unsigned* recs     = (unsigned*)(wsf + 4108448);   // 1,204,224 u32 (4.8 MB)
  int*      offs     = (int*)(wsf + 5312672);        //    50,176 i
  int*      cnt      = (int*)(wsf + 5362848);        //    50,176 i
  int*      bcursor  = (int*)(wsf + 5413024);        //       196 i
  float*    bmax     = wsf + 5413220;                //       196 f
  float*    bsexp    = wsf + 5413416;                //       196 f
  unsigned short* Wt  = (unsigned short*)(wsf + 5413616);  // 32,768 bf16
  unsigned short* W1t = (unsigned short*)(wsf + 5430000);  // 8,192 bf16 (end ~21.7 MB)

  k_wconv<<<128, 256, 0, stream>>>(W, W1, Wt, W1t, bcursor);
  k_gemm<<<(NN + 31) / 32, 256, 0, stream>>>(x, Wt, a, Whp8, s_src, s_tgt);
  k_score<<<NBLK, 256, 0, stream>>>(ei, s_src, s_tgt, bcursor, recs_mid, bmax, bsexp);
  k_sortB<<<NBLK, 256, 0, stream>>>(bcursor, recs_mid, bmax, bsexp, recs, offs, cnt);
  k_gather<<<NN / 4, 256, 0, stream>>>(offs, cnt, recs, (const unsigned short*)Whp8, xnew);
  k_mlp<<<(NN + 31) / 32, 256, 0, stream>>>(xnew, W1t, b1, W2, b2, evid);
}

// Round 16
// 99.371 us; speedup vs baseline: 8.9857x; 1.0148x over previous
//
#include <hip/hip_runtime.h>
#include <hip/hip_bf16.h>
#include <math.h>

#define NN 50000
#define NE 800000
#define IND 256
#define OUTD 128
#define HIDD 64
#define NBLK 196   // number of 256-target coarse buckets (196*256 = 50176 >= NN)
#define BCAP 6144  // fixed bucket capacity (mean 4082, ~32 sigma headroom)

typedef __attribute__((ext_vector_type(8))) short short8;   // 8 bf16 (4 VGPR)
typedef __attribute__((ext_vector_type(4))) float f32x4;    // MFMA acc
typedef __attribute__((ext_vector_type(2))) float f32x2;    // fp8 cvt result

// ---------- helpers ----------
static __device__ __forceinline__ unsigned short f2bf_hw(float f) {  // HW cvt (RNE)
  __hip_bfloat16 h = __float2bfloat16(f);
  return __hip_bfloat16_raw(h).x;
}
static __device__ __forceinline__ float bf2f(unsigned b) {
  return __uint_as_float(b << 16);
}

// ---------- K0: Wt[n][k]=bf16(W[k][n]), W1t[h][k]=bf16(W1[k][h]), init cursors ----------
__global__ __launch_bounds__(256) void k_wconv(const float* __restrict__ W,
                                               const float* __restrict__ W1,
                                               unsigned short* __restrict__ Wt,
                                               unsigned short* __restrict__ W1t,
                                               int* __restrict__ bcursor) {
  if (blockIdx.x == 0 && threadIdx.x < NBLK)
    bcursor[threadIdx.x] = threadIdx.x * BCAP;       // fixed-capacity bases
  int t = blockIdx.x * 256 + threadIdx.x;     // 128 blocks
  int n = t >> 8, k = t & 255;
  Wt[t] = f2bf_hw(W[k * OUTD + n]);
  if (t < HIDD * OUTD) {                      // 8192: W1 transposed bf16
    int h = t >> 7, kk = t & 127;
    W1t[t] = f2bf_hw(W1[kk * HIDD + h]);
  }
}

// ---------- K1: MFMA GEMM (BM=32, BK=64) -> fp8 Wh + fused s_src/s_tgt ----------
__global__ __launch_bounds__(256) void k_gemm(const float* __restrict__ x,
                                              const unsigned short* __restrict__ Wt,
                                              const float* __restrict__ a,
                                              unsigned* __restrict__ Whp8,
                                              float* __restrict__ s_src,
                                              float* __restrict__ s_tgt) {
  __shared__ float smem[5760];                 // 23040 B
  short* As = (short*)smem;                    // [32][72] bf16
  short* Bs = As + 32 * 72;                    // [128][72] bf16
  float* Cs = smem;                            // [32][132] f32 (epilogue alias)

  const int tid  = threadIdx.x;
  const int bm   = blockIdx.x * 32;
  const int wave = tid >> 6;                   // 0..3 -> col block wave*32
  const int lane = tid & 63;
  const int l15  = lane & 15;
  const int lg   = lane >> 4;                  // 0..3

  f32x4 acc[2][2];
#pragma unroll
  for (int i = 0; i < 2; i++)
#pragma unroll
    for (int j = 0; j < 2; j++) acc[i][j] = (f32x4){0.f, 0.f, 0.f, 0.f};

  const int arow = tid >> 3, aq = tid & 7;
  long arow_g = bm + arow; if (arow_g >= NN) arow_g = NN - 1;   // clamp, writes guarded
  const float* xp = &x[arow_g * IND + aq * 8];
  short* asp = &As[arow * 72 + aq * 8];
  const int bn = tid >> 1, bh = tid & 1;
  const unsigned short* wtp = &Wt[bn * 256 + bh * 32];
  short* bsp = &Bs[bn * 72 + bh * 32];

  for (int k0 = 0; k0 < IND; k0 += 64) {
    float4 va0 = *(const float4*)(xp + k0);
    float4 va1 = *(const float4*)(xp + k0 + 4);
    short8 apk;
    apk[0] = (short)f2bf_hw(va0.x); apk[1] = (short)f2bf_hw(va0.y);
    apk[2] = (short)f2bf_hw(va0.z); apk[3] = (short)f2bf_hw(va0.w);
    apk[4] = (short)f2bf_hw(va1.x); apk[5] = (short)f2bf_hw(va1.y);
    apk[6] = (short)f2bf_hw(va1.z); apk[7] = (short)f2bf_hw(va1.w);
    *(short8*)asp = apk;
#pragma unroll
    for (int q = 0; q < 4; q++)
      *(short8*)(bsp + q * 8) = *(const short8*)(wtp + k0 + q * 8);
    __syncthreads();

    short8 af[2][2], bf[2][2];
#pragma unroll
    for (int mi = 0; mi < 2; mi++)
#pragma unroll
      for (int ks = 0; ks < 2; ks++)
        af[mi][ks] = *(const short8*)&As[(mi * 16 + l15) * 72 + ks * 32 + lg * 8];
#pragma unroll
    for (int ni = 0; ni < 2; ni++)
#pragma unroll
      for (int ks = 0; ks < 2; ks++)
        bf[ni][ks] = *(const short8*)&Bs[(wave * 32 + ni * 16 + l15) * 72 + ks * 32 + lg * 8];
#pragma unroll
    for (int ks = 0; ks < 2; ks++)
#pragma unroll
      for (int mi = 0; mi < 2; mi++)
#pragma unroll
        for (int ni = 0; ni < 2; ni++)
          acc[mi][ni] = __builtin_amdgcn_mfma_f32_16x16x32_bf16(
              af[mi][ks], bf[ni][ks], acc[mi][ni], 0, 0, 0);
    __syncthreads();
  }

  // epilogue: acc -> Cs (f32)
#pragma unroll
  for (int mi = 0; mi < 2; mi++)
#pragma unroll
    for (int ni = 0; ni < 2; ni++)
#pragma unroll
      for (int r = 0; r < 4; r++) {
        int row = mi * 16 + lg * 4 + r;
        int col = wave * 32 + ni * 16 + l15;
        Cs[row * 132 + col] = acc[mi][ni][r];
      }
  __syncthreads();

  // (a) fp8 row store: 512 chunks of 8 f32 -> 8 fp8 bytes (2 per thread)
#pragma unroll
  for (int i = 0; i < 2; i++) {
    int f = tid + i * 256;
    int nd = f >> 4, seg = f & 15;
    long gnode = bm + nd;
    if (gnode < NN) {
      float4 c0 = *(const float4*)&Cs[nd * 132 + seg * 8];
      float4 c1 = *(const float4*)&Cs[nd * 132 + seg * 8 + 4];
      int u0 = __builtin_amdgcn_cvt_pk_fp8_f32(c0.x, c0.y, 0, false);
      u0     = __builtin_amdgcn_cvt_pk_fp8_f32(c0.z, c0.w, u0, true);
      int u1 = __builtin_amdgcn_cvt_pk_fp8_f32(c1.x, c1.y, 0, false);
      u1     = __builtin_amdgcn_cvt_pk_fp8_f32(c1.z, c1.w, u1, true);
      *(uint2*)&Whp8[gnode * 32 + seg * 2] = make_uint2((unsigned)u0, (unsigned)u1);
    }
  }

  // (b) fused s_src/s_tgt: 8 threads per node, 16 cols each, shfl_xor reduce
  {
    const int nd = tid >> 3, p = tid & 7;
    float p1 = 0.f, p2 = 0.f;
    const float* crow = &Cs[nd * 132 + p * 16];
#pragma unroll
    for (int k = 0; k < 16; k++) {
      float c = crow[k];
      p1 = fmaf(c, a[p * 16 + k], p1);
      p2 = fmaf(c, a[128 + p * 16 + k], p2);
    }
    p1 += __shfl_xor(p1, 1); p1 += __shfl_xor(p1, 2); p1 += __shfl_xor(p1, 4);
    p2 += __shfl_xor(p2, 1); p2 += __shfl_xor(p2, 2); p2 += __shfl_xor(p2, 4);
    long gnode = bm + nd;
    if (p == 0 && gnode < NN) { s_src[gnode] = p1; s_tgt[gnode] = p2; }
  }
}

// ---------- K3: scores + DIRECT binning (fixed-capacity buckets) + block stats ----------
__global__ __launch_bounds__(256) void k_score(const int* __restrict__ ei,
                                               const float* __restrict__ s_src,
                                               const float* __restrict__ s_tgt,
                                               int* __restrict__ bcursor,
                                               int2* __restrict__ recs_mid,
                                               float* __restrict__ bmax,
                                               float* __restrict__ bsexp) {
  __shared__ int bh[NBLK];
  __shared__ int gbase[NBLK];
  __shared__ float red[4];
  __shared__ float bmx;
  const int tid = threadIdx.x;
  const long eb = (long)blockIdx.x * 4096;
  if (tid < NBLK) bh[tid] = 0;
  __syncthreads();

  int sv[16]; int tv[16]; float scv[16];
  float mx = -1e30f;
#pragma unroll
  for (int i = 0; i < 16; i++) {
    long e = eb + i * 256 + tid;
    float sc = -1e30f;
    if (e < NE) {
      int s = ei[e];
      int t = ei[NE + e];
      float v = s_src[s] + s_tgt[t];
      sc = v > 0.f ? v : 0.2f * v;              // leaky_relu(0.2)
      sv[i] = s; tv[i] = t;
      atomicAdd(&bh[t >> 8], 1);
    } else {
      tv[i] = -1;
    }
    scv[i] = sc;
    mx = fmaxf(mx, sc);
  }
  __syncthreads();
  if (tid < NBLK) {
    int c = bh[tid];
    gbase[tid] = (c > 0) ? atomicAdd(&bcursor[tid], c) : 0;
    bh[tid] = 0;                               // reuse as local cursor
  }
  __syncthreads();
#pragma unroll
  for (int i = 0; i < 16; i++) {
    if (tv[i] >= 0) {
      int b = tv[i] >> 8;
      int off = atomicAdd(&bh[b], 1);
      recs_mid[gbase[b] + off] = make_int2(sv[i] | ((tv[i] & 255) << 16),
                                           __float_as_int(scv[i]));
    }
  }

  // per-block softmax stats
#pragma unroll
  for (int off = 32; off; off >>= 1) mx = fmaxf(mx, __shfl_down(mx, off));
  int w = tid >> 6, lane = tid & 63;
  if (lane == 0) red[w] = mx;
  __syncthreads();
  if (tid == 0) bmx = fmaxf(fmaxf(red[0], red[1]), fmaxf(red[2], red[3]));
  __syncthreads();
  const float M = bmx;
  float s = 0.f;
#pragma unroll
  for (int i = 0; i < 16; i++) s += __expf(scv[i] - M);   // invalid lanes -> 0
#pragma unroll
  for (int off = 32; off; off >>= 1) s += __shfl_down(s, off);
  if (lane == 0) red[w] = s;
  __syncthreads();
  if (tid == 0) {
    bmax[blockIdx.x] = M;
    bsexp[blockIdx.x] = red[0] + red[1] + red[2] + red[3];
  }
}

// ---------- K6: stats combine (per-block, redundant) + in-bucket LDS sort ----------
// Record out: src(16b) | bf16(alpha)<<16.
__global__ __launch_bounds__(256) void k_sortB(const int* __restrict__ bcursor,
                                               const int2* __restrict__ recs_mid,
                                               const float* __restrict__ bmax,
                                               const float* __restrict__ bsexp,
                                               unsigned* __restrict__ recs,
                                               int* __restrict__ offs,
                                               int* __restrict__ cnt) {
  __shared__ float fred[256];
  __shared__ int h[256], sc[256], cur[256];
  __shared__ unsigned srt[BCAP];
  const int tid = threadIdx.x;
  const int b = blockIdx.x;
  const int base = b * BCAP;
  const int m = bcursor[b] - base;

  // global softmax stats (redundant 196-way reduce; L2-hit reads)
  float mv = (tid < NBLK) ? bmax[tid] : -1e30f;
  fred[tid] = mv;
  __syncthreads();
  for (int off = 128; off; off >>= 1) {
    if (tid < off) fred[tid] = fmaxf(fred[tid], fred[tid + off]);
    __syncthreads();
  }
  const float M = fred[0];
  __syncthreads();
  float se = (tid < NBLK) ? bsexp[tid] * __expf(bmax[tid] - M) : 0.f;
  fred[tid] = se;
  __syncthreads();
  for (int off = 128; off; off >>= 1) {
    if (tid < off) fred[tid] += fred[tid + off];
    __syncthreads();
  }
  const float inv = 1.0f / fred[0];

  h[tid] = 0;
  __syncthreads();
  for (int i = tid; i < m; i += 256) {
    int2 r = recs_mid[base + i];
    atomicAdd(&h[(r.x >> 16) & 255], 1);
  }
  __syncthreads();
  sc[tid] = h[tid];
  __syncthreads();
  for (int off = 1; off < 256; off <<= 1) {
    int t = (tid >= off) ? sc[tid - off] : 0;
    __syncthreads();
    sc[tid] += t;
    __syncthreads();
  }
  int excl = sc[tid] - h[tid];
  cur[tid] = excl;
  offs[b * 256 + tid] = base + excl;           // global per-target offsets
  cnt[b * 256 + tid] = h[tid];
  __syncthreads();
  for (int i = tid; i < m; i += 256) {
    int2 r = recs_mid[base + i];
    int tl = (r.x >> 16) & 255;
    int p = atomicAdd(&cur[tl], 1);
    float al = __expf(__int_as_float(r.y) - M) * inv;
    if (p < BCAP)
      srt[p] = (unsigned)(r.x & 0xffff) | ((unsigned)f2bf_hw(al) << 16);
  }
  __syncthreads();
  for (int i = tid; i < m; i += 256)
    recs[base + i] = srt[i];                   // coalesced 4B records
}

// ---------- K7: gather-sum, half-wave record parallelism (uint row loads) ----------
// One wave per node. Lane half hl=lane>>5 processes even/odd records; lane
// reads a uint = 4 fp8 cols [4*l5 .. 4*l5+3] of its half's record row. One
// 256B wave-load covers 2 records (vs 128B/1 record before) -> half the VMEM
// instruction count. Cross-half combine via shfl_xor(32); float4 store.
__global__ __launch_bounds__(256) void k_gather(const int* __restrict__ offs,
                                                const int* __restrict__ cnt,
                                                const unsigned* __restrict__ recs,
                                                const unsigned* __restrict__ Whu32,
                                                float* __restrict__ xnew) {
  int wid = (blockIdx.x * 256 + threadIdx.x) >> 6;    // 12500*4 = NN waves
  int lane = threadIdx.x & 63;
  const int hl = lane >> 5;                           // record parity
  const int l5 = lane & 31;                           // uint col index
  int start = offs[wid];
  int n = cnt[wid];
  f32x4 acc = (f32x4){0.f, 0.f, 0.f, 0.f};
  for (int base = 0; base < n; base += 64) {
    int m = n - base; if (m > 64) m = 64;
    int li = lane < m ? lane : m - 1;
    unsigned r = recs[start + base + li];             // coalesced chunk load
    for (int i = 0; i < m; i += 8) {                  // 8 records / 4 loads in flight
      unsigned rv[4], v[4];
#pragma unroll
      for (int p = 0; p < 4; p++) rv[p] = __shfl(r, i + 2 * p + hl);
#pragma unroll
      for (int p = 0; p < 4; p++)
        v[p] = Whu32[(long)(rv[p] & 0xffffu) * 32 + l5];
#pragma unroll
      for (int p = 0; p < 4; p++) {
        float al = (i + 2 * p + hl < m) ? bf2f(rv[p] >> 16) : 0.f;
        f32x2 w0 = __builtin_amdgcn_cvt_pk_f32_fp8((int)v[p], false);  // cols 4l5,4l5+1
        f32x2 w1 = __builtin_amdgcn_cvt_pk_f32_fp8((int)v[p], true);   // cols 4l5+2,4l5+3
        acc[0] = fmaf(al, w0[0], acc[0]);
        acc[1] = fmaf(al, w0[1], acc[1]);
        acc[2] = fmaf(al, w1[0], acc[2]);
        acc[3] = fmaf(al, w1[1], acc[3]);
      }
    }
  }
#pragma unroll
  for (int q = 0; q < 4; q++) acc[q] += __shfl_xor(acc[q], 32);
  if (lane < 32)
    *(float4*)&xnew[(long)wid * OUTD + l5 * 4] =
        make_float4(acc[0], acc[1], acc[2], acc[3]);
}

// ---------- K8: MLP head, layer-1 via MFMA bf16 (BM=32) ----------
__global__ __launch_bounds__(256) void k_mlp(const float* __restrict__ xnew,
                                             const unsigned short* __restrict__ W1t,
                                             const float* __restrict__ b1,
                                             const float* __restrict__ W2,
                                             const float* __restrict__ b2,
                                             float* __restrict__ evid) {
  __shared__ short smem[13056];                // 26112 B
  short* As = smem;                            // [32][136] bf16 x-tile
  short* Bs = smem + 32 * 136;                 // [64][136] bf16 W1t (hid-major)
  float* Cs = (float*)smem;                    // [32][68] f32 h (aliases As)

  const int tid = threadIdx.x;
  const int nb = blockIdx.x * 32;
  const int wave = tid >> 6;
  const int lane = tid & 63;
  const int l15 = lane & 15, lg = lane >> 4;

  // stage x -> bf16 (16 elems/thread) and W1t copy (32 shorts/thread)
  {
    int row = tid >> 3, seg = tid & 7;         // 32 rows x 8 segs of 16
    long g = nb + row; if (g >= NN) g = NN - 1;
    const float* xp = &xnew[g * OUTD + seg * 16];
    short* dst = &As[row * 136 + seg * 16];
#pragma unroll
    for (int q = 0; q < 2; q++) {
      float4 v0 = *(const float4*)(xp + q * 8);
      float4 v1 = *(const float4*)(xp + q * 8 + 4);
      short8 pk;
      pk[0] = (short)f2bf_hw(v0.x); pk[1] = (short)f2bf_hw(v0.y);
      pk[2] = (short)f2bf_hw(v0.z); pk[3] = (short)f2bf_hw(v0.w);
      pk[4] = (short)f2bf_hw(v1.x); pk[5] = (short)f2bf_hw(v1.y);
      pk[6] = (short)f2bf_hw(v1.z); pk[7] = (short)f2bf_hw(v1.w);
      *(short8*)(dst + q * 8) = pk;
    }
    int wrow = tid >> 2, wseg = tid & 3;       // 64 rows x 4 segs of 32
    const unsigned short* wp = &W1t[wrow * 128 + wseg * 32];
    short* wdst = &Bs[wrow * 136 + wseg * 32];
#pragma unroll
    for (int q = 0; q < 4; q++)
      *(short8*)(wdst + q * 8) = *(const short8*)(wp + q * 8);
  }
  __syncthreads();

  f32x4 acc[2];
#pragma unroll
  for (int mi = 0; mi < 2; mi++) acc[mi] = (f32x4){0.f, 0.f, 0.f, 0.f};
#pragma unroll
  for (int ks = 0; ks < 4; ks++) {
    short8 bfr = *(const short8*)&Bs[(wave * 16 + l15) * 136 + ks * 32 + lg * 8];
#pragma unroll
    for (int mi = 0; mi < 2; mi++) {
      short8 afr = *(const short8*)&As[(mi * 16 + l15) * 136 + ks * 32 + lg * 8];
      acc[mi] = __builtin_amdgcn_mfma_f32_16x16x32_bf16(afr, bfr, acc[mi], 0, 0, 0);
    }
  }
  __syncthreads();                             // As dead; alias as Cs
#pragma unroll
  for (int mi = 0; mi < 2; mi++)
#pragma unroll
    for (int r = 0; r < 4; r++) {
      int row = mi * 16 + lg * 4 + r;
      int col = wave * 16 + l15;
      Cs[row * 68 + col] = acc[mi][r];
    }
  __syncthreads();

  // layer 2 fused from Cs: 32 nodes, ty covers 2 rows each
  const int ty = tid >> 4, tx = tid & 15;
  float b1r[4], w2r[4][3];
#pragma unroll
  for (int j = 0; j < 4; j++) {
    int jg = tx * 4 + j;
    b1r[j] = b1[jg];
    w2r[j][0] = W2[jg * 3 + 0];
    w2r[j][1] = W2[jg * 3 + 1];
    w2r[j][2] = W2[jg * 3 + 2];
  }
#pragma unroll
  for (int i = 0; i < 2; i++) {
    float p0 = 0.f, p1 = 0.f, p2 = 0.f;
#pragma unroll
    for (int j = 0; j < 4; j++) {
      float h = fmaxf(Cs[(ty * 2 + i) * 68 + tx * 4 + j] + b1r[j], 0.f);
      p0 = fmaf(h, w2r[j][0], p0);
      p1 = fmaf(h, w2r[j][1], p1);
      p2 = fmaf(h, w2r[j][2], p2);
    }
#pragma unroll
    for (int m = 1; m < 16; m <<= 1) {
      p0 += __shfl_xor(p0, m);
      p1 += __shfl_xor(p1, m);
      p2 += __shfl_xor(p2, m);
    }
    if (tx == 0) {
      int n = nb + ty * 2 + i;
      if (n < NN) {
        float e0 = p0 + b2[0], e1 = p1 + b2[1], e2 = p2 + b2[2];
        float s0 = e0 > 20.f ? e0 : log1pf(expf(e0));
        float s1 = e1 > 20.f ? e1 : log1pf(expf(e1));
        float s2 = e2 > 20.f ? e2 : log1pf(expf(e2));
        evid[(long)n * 3 + 0] = s0 + 1.0f;
        evid[(long)n * 3 + 1] = s1 + 1.0f;
        evid[(long)n * 3 + 2] = s2 + 1.0f;
      }
    }
  }
}

extern "C" void kernel_launch(void* const* d_in, const int* in_sizes, int n_in,
                              void* d_out, int out_size, void* d_ws, size_t ws_size,
                              hipStream_t stream) {
  const float* x   = (const float*)d_in[0];
  const int*   ei  = (const int*)d_in[1];
  const float* W   = (const float*)d_in[2];
  const float* a   = (const float*)d_in[3];
  const float* W1  = (const float*)d_in[4];
  const float* b1  = (const float*)d_in[5];
  const float* W2  = (const float*)d_in[6];
  const float* b2  = (const float*)d_in[7];

  float* xnew = (float*)d_out;                       // [NN*OUTD]
  float* evid = (float*)d_out + (size_t)NN * OUTD;   // [NN*3]

  float* wsf = (float*)d_ws;
  unsigned* Whp8     = (unsigned*)wsf;               // 1,600,000 u32 (6.4 MB fp8 Wh)
  float*    s_src    = wsf + 1600000;                //    50,000 f
  float*    s_tgt    = wsf + 1650000;                //    50,000 f
  int2*     recs_mid = (int2*)(wsf + 1700000);       // 1,204,224 int2 (9.6 MB)
  unsigned* recs     = (unsigned*)(wsf + 4108448);   // 1,204,224 u32 (4.8 MB)
  int*      offs     = (int*)(wsf + 5312672);        //    50,176 i
  int*      cnt      = (int*)(wsf + 5362848);        //    50,176 i
  int*      bcursor  = (int*)(wsf + 5413024);        //       196 i
  float*    bmax     = wsf + 5413220;                //       196 f
  float*    bsexp    = wsf + 5413416;                //       196 f
  unsigned short* Wt  = (unsigned short*)(wsf + 5413616);  // 32,768 bf16
  unsigned short* W1t = (unsigned short*)(wsf + 5430000);  // 8,192 bf16 (end ~21.7 MB)

  k_wconv<<<128, 256, 0, stream>>>(W, W1, Wt, W1t, bcursor);
  k_gemm<<<(NN + 31) / 32, 256, 0, stream>>>(x, Wt, a, Whp8, s_src, s_tgt);
  k_score<<<NBLK, 256, 0, stream>>>(ei, s_src, s_tgt, bcursor, recs_mid, bmax, bsexp);
  k_sortB<<<NBLK, 256, 0, stream>>>(bcursor, recs_mid, bmax, bsexp, recs, offs, cnt);
  k_gather<<<NN / 4, 256, 0, stream>>>(offs, cnt, recs, Whp8, xnew);
  k_mlp<<<(NN + 31) / 32, 256, 0, stream>>>(xnew, W1t, b1, W2, b2, evid);
}